// Round 1
// baseline (2323.391 us; speedup 1.0000x reference)
//
#include <hip/hip_runtime.h>
#include <math.h>

#define HEADS 4
#define HID 64

__device__ __forceinline__ float atomicMaxFloat(float* addr, float value) {
    if (value >= 0.f)
        return __int_as_float(atomicMax((int*)addr, __float_as_int(value)));
    else
        return __uint_as_float(atomicMin((unsigned int*)addr, __float_as_uint(value)));
}

__device__ __forceinline__ float lrelu(float x) { return x > 0.f ? x : 0.2f * x; }

// ---- init per-layer accumulators: m=-inf, ssum=0, hacc=0 ----
__global__ void k_init(float* __restrict__ m, float* __restrict__ ss,
                       float* __restrict__ hacc, int N) {
    int tid = blockIdx.x * blockDim.x + threadIdx.x;
    if (tid < N * 4) { m[tid] = -INFINITY; ss[tid] = 0.f; }
    if (tid < N * 64) hacc[tid] = 0.f;
}

// ---- layer 1 transform: xl[n, t] = sum_k x[n,k] * W1[k*256 + t], t in [0,256) ----
__global__ void k_transform1(const float* __restrict__ x, const float* __restrict__ W1,
                             float* __restrict__ xl, int N) {
    int n = blockIdx.x;
    if (n >= N) return;
    int t = threadIdx.x;
    float x0 = x[n * 3 + 0], x1 = x[n * 3 + 1], x2 = x[n * 3 + 2];
    float v = x0 * W1[t] + x1 * W1[256 + t] + x2 * W1[512 + t];
    xl[(size_t)n * 256 + t] = v;
}

// ---- layer 2 transform: xl = h[N,64] @ W2[64,256], 8 nodes per block ----
#define NB 8
__global__ void k_transform2(const float* __restrict__ hin, const float* __restrict__ W,
                             float* __restrict__ xl, int N) {
    int base = blockIdx.x * NB;
    __shared__ float hs[NB * 64];
    int t = threadIdx.x;
    for (int i = t; i < NB * 64; i += 256) {
        int n = base + (i >> 6);
        hs[i] = (n < N) ? hin[(size_t)n * 64 + (i & 63)] : 0.f;
    }
    __syncthreads();
    float acc[NB];
#pragma unroll
    for (int j = 0; j < NB; j++) acc[j] = 0.f;
    for (int k = 0; k < 64; k++) {
        float wv = W[k * 256 + t];
#pragma unroll
        for (int j = 0; j < NB; j++) acc[j] += hs[j * 64 + k] * wv;
    }
#pragma unroll
    for (int j = 0; j < NB; j++) {
        int n = base + j;
        if (n < N) xl[(size_t)n * 256 + t] = acc[j];
    }
}

// ---- attention coefficients: es[n,h] = sum_c xl[n,h,c]*a_src[h,c]; wave per head ----
__global__ void k_attn(const float* __restrict__ xl, const float* __restrict__ a_src,
                       const float* __restrict__ a_dst, float* __restrict__ es,
                       float* __restrict__ ed, int N) {
    int n = blockIdx.x;
    if (n >= N) return;
    int t = threadIdx.x;
    int w = t >> 6, c = t & 63;
    float v = xl[(size_t)n * 256 + t];
    float ps = v * a_src[t];
    float pd = v * a_dst[t];
    for (int o = 32; o > 0; o >>= 1) {
        ps += __shfl_down(ps, o);
        pd += __shfl_down(pd, o);
    }
    if (c == 0) { es[n * 4 + w] = ps; ed[n * 4 + w] = pd; }
}

// ---- edge pass 1: segment max of leaky_relu(es[src]+ed[dst]) over dst ----
__global__ void k_edge_max(const int* __restrict__ srcI, const int* __restrict__ dstI,
                           const float* __restrict__ es, const float* __restrict__ ed,
                           float* __restrict__ m, int N, int E) {
    int e = blockIdx.x * blockDim.x + threadIdx.x;
    if (e >= E) return;
    int s = srcI[e], d = dstI[e];
    if ((unsigned)s >= (unsigned)N || (unsigned)d >= (unsigned)N) return;
    float4 a = *(const float4*)(es + (size_t)s * 4);
    float4 b = *(const float4*)(ed + (size_t)d * 4);
    float e0 = lrelu(a.x + b.x), e1 = lrelu(a.y + b.y);
    float e2 = lrelu(a.z + b.z), e3 = lrelu(a.w + b.w);
    atomicMaxFloat(&m[(size_t)d * 4 + 0], e0);
    atomicMaxFloat(&m[(size_t)d * 4 + 1], e1);
    atomicMaxFloat(&m[(size_t)d * 4 + 2], e2);
    atomicMaxFloat(&m[(size_t)d * 4 + 3], e3);
}

// ---- edge pass 2: ex = exp(e - m[dst]); cache ex; ssum[dst] += ex ----
__global__ void k_edge_sum(const int* __restrict__ srcI, const int* __restrict__ dstI,
                           const float* __restrict__ es, const float* __restrict__ ed,
                           const float* __restrict__ m, float* __restrict__ ss,
                           float* __restrict__ exb, int N, int E) {
    int e = blockIdx.x * blockDim.x + threadIdx.x;
    if (e >= E) return;
    int s = srcI[e], d = dstI[e];
    if ((unsigned)s >= (unsigned)N || (unsigned)d >= (unsigned)N) return;
    float4 a = *(const float4*)(es + (size_t)s * 4);
    float4 b = *(const float4*)(ed + (size_t)d * 4);
    float4 mv = *(const float4*)(m + (size_t)d * 4);
    float x0 = expf(lrelu(a.x + b.x) - mv.x);
    float x1 = expf(lrelu(a.y + b.y) - mv.y);
    float x2 = expf(lrelu(a.z + b.z) - mv.z);
    float x3 = expf(lrelu(a.w + b.w) - mv.w);
    float4 ex; ex.x = x0; ex.y = x1; ex.z = x2; ex.w = x3;
    *(float4*)(exb + (size_t)e * 4) = ex;
    atomicAdd(&ss[(size_t)d * 4 + 0], x0);
    atomicAdd(&ss[(size_t)d * 4 + 1], x1);
    atomicAdd(&ss[(size_t)d * 4 + 2], x2);
    atomicAdd(&ss[(size_t)d * 4 + 3], x3);
}

// ---- edge pass 3: wave per edge; hacc[dst,c] += 0.25 * sum_h alpha_h * xl[src,h,c] ----
__global__ void k_edge_scatter(const int* __restrict__ srcI, const int* __restrict__ dstI,
                               const float* __restrict__ exb, const float* __restrict__ ss,
                               const float* __restrict__ xl, float* __restrict__ hacc,
                               int N, int E) {
    int gid = blockIdx.x * blockDim.x + threadIdx.x;
    int wid = gid >> 6;       // edge index
    int lane = gid & 63;      // channel
    if (wid >= E) return;
    int s = srcI[wid], d = dstI[wid];
    if ((unsigned)s >= (unsigned)N || (unsigned)d >= (unsigned)N) return;
    float4 ex = *(const float4*)(exb + (size_t)wid * 4);
    float4 sv = *(const float4*)(ss + (size_t)d * 4);
    float a0 = ex.x / sv.x, a1 = ex.y / sv.y, a2 = ex.z / sv.z, a3 = ex.w / sv.w;
    const float* xs = xl + (size_t)s * 256;
    float acc = a0 * xs[lane] + a1 * xs[64 + lane] + a2 * xs[128 + lane] + a3 * xs[192 + lane];
    atomicAdd(&hacc[(size_t)d * 64 + lane], 0.25f * acc);
}

// ---- finalize: hout = relu(hacc + b[c]) ----
__global__ void k_finalize(const float* __restrict__ hacc, const float* __restrict__ b,
                           float* __restrict__ hout, int N) {
    int tid = blockIdx.x * blockDim.x + threadIdx.x;
    if (tid >= N * 64) return;
    int c = tid & 63;
    float v = hacc[tid] + b[c];
    hout[tid] = v > 0.f ? v : 0.f;
}

// ---- global add pool: batch_ids sorted; 1 block per graph, binary-search range ----
__global__ void k_pool(const float* __restrict__ h2, const int* __restrict__ batch,
                       float* __restrict__ out, int N, int G) {
    int g = blockIdx.x;
    if (g >= G) return;
    int lo = 0, hi = N;
    while (lo < hi) { int mid = (lo + hi) >> 1; if (batch[mid] < g) lo = mid + 1; else hi = mid; }
    int start = lo;
    lo = start; hi = N;
    while (lo < hi) { int mid = (lo + hi) >> 1; if (batch[mid] < g + 1) lo = mid + 1; else hi = mid; }
    int end = lo;
    int t = threadIdx.x, c = t & 63, j = t >> 6;
    float p = 0.f;
    for (int n = start + j; n < end; n += 4) p += h2[(size_t)n * 64 + c];
    __shared__ float lds[256];
    lds[t] = p;
    __syncthreads();
    if (j == 0) out[g * 64 + c] = lds[c] + lds[64 + c] + lds[128 + c] + lds[192 + c];
}

extern "C" void kernel_launch(void* const* d_in, const int* in_sizes, int n_in,
                              void* d_out, int out_size, void* d_ws, size_t ws_size,
                              hipStream_t stream) {
    const float* x   = (const float*)d_in[0];
    const int*   ei  = (const int*)d_in[1];
    const int*   bat = (const int*)d_in[2];
    const float* W1  = (const float*)d_in[3];
    const float* as1 = (const float*)d_in[4];
    const float* ad1 = (const float*)d_in[5];
    const float* b1  = (const float*)d_in[6];
    const float* W2  = (const float*)d_in[7];
    const float* as2 = (const float*)d_in[8];
    const float* ad2 = (const float*)d_in[9];
    const float* b2  = (const float*)d_in[10];
    float* out = (float*)d_out;

    int N = in_sizes[0] / 3;
    int E = in_sizes[1] / 2;
    int G = out_size / 64;
    const int* srcI = ei;
    const int* dstI = ei + E;

    float* ws = (float*)d_ws;
    size_t off = 0;
    float* xl   = ws + off; off += (size_t)N * 256;
    float* es   = ws + off; off += (size_t)N * 4;
    float* ed   = ws + off; off += (size_t)N * 4;
    float* m    = ws + off; off += (size_t)N * 4;
    float* ss   = ws + off; off += (size_t)N * 4;
    float* hacc = ws + off; off += (size_t)N * 64;
    float* hout = ws + off; off += (size_t)N * 64;
    float* exb  = ws + off; off += (size_t)E * 4;

    int nodeBlk = (N * 64 + 255) / 256;
    int edgeBlk = (E + 255) / 256;
    int scatBlk = (E * 64 + 255) / 256;

    // ---------------- layer 1 ----------------
    k_transform1<<<N, 256, 0, stream>>>(x, W1, xl, N);
    k_attn<<<N, 256, 0, stream>>>(xl, as1, ad1, es, ed, N);
    k_init<<<nodeBlk, 256, 0, stream>>>(m, ss, hacc, N);
    k_edge_max<<<edgeBlk, 256, 0, stream>>>(srcI, dstI, es, ed, m, N, E);
    k_edge_sum<<<edgeBlk, 256, 0, stream>>>(srcI, dstI, es, ed, m, ss, exb, N, E);
    k_edge_scatter<<<scatBlk, 256, 0, stream>>>(srcI, dstI, exb, ss, xl, hacc, N, E);
    k_finalize<<<nodeBlk, 256, 0, stream>>>(hacc, b1, hout, N);

    // ---------------- layer 2 ----------------
    k_transform2<<<(N + NB - 1) / NB, 256, 0, stream>>>(hout, W2, xl, N);
    k_attn<<<N, 256, 0, stream>>>(xl, as2, ad2, es, ed, N);
    k_init<<<nodeBlk, 256, 0, stream>>>(m, ss, hacc, N);
    k_edge_max<<<edgeBlk, 256, 0, stream>>>(srcI, dstI, es, ed, m, N, E);
    k_edge_sum<<<edgeBlk, 256, 0, stream>>>(srcI, dstI, es, ed, m, ss, exb, N, E);
    k_edge_scatter<<<scatBlk, 256, 0, stream>>>(srcI, dstI, exb, ss, xl, hacc, N, E);
    k_finalize<<<nodeBlk, 256, 0, stream>>>(hacc, b2, hout, N);

    // ---------------- pool ----------------
    k_pool<<<G, 256, 0, stream>>>(hout, bat, out, N, G);
}

// Round 2
// 784.136 us; speedup vs baseline: 2.9630x; 2.9630x over previous
//
#include <hip/hip_runtime.h>
#include <math.h>

#define HEADS 4
#define HID 64

__device__ __forceinline__ float lrelu(float x) { return x > 0.f ? x : 0.2f * x; }

__device__ __forceinline__ float wred_sum(float v) {
#pragma unroll
    for (int o = 32; o > 0; o >>= 1) v += __shfl_xor(v, o);
    return v;
}
__device__ __forceinline__ float wred_max(float v) {
#pragma unroll
    for (int o = 32; o > 0; o >>= 1) v = fmaxf(v, __shfl_xor(v, o));
    return v;
}

// ======================= CSR build (dst-sorted) =======================
__global__ void k_zero(int* __restrict__ deg, int N) {
    int i = blockIdx.x * blockDim.x + threadIdx.x;
    if (i < N) deg[i] = 0;
}

__global__ void k_hist(const int* __restrict__ dstI, int* __restrict__ deg, int E) {
    int e = blockIdx.x * blockDim.x + threadIdx.x;
    if (e < E) atomicAdd(&deg[dstI[e]], 1);
}

// chunk = 256 elements per block
__global__ void k_scan1(const int* __restrict__ deg, int* __restrict__ part, int N) {
    __shared__ int lds[256];
    int i = blockIdx.x * 256 + threadIdx.x;
    lds[threadIdx.x] = (i < N) ? deg[i] : 0;
    __syncthreads();
    for (int s = 128; s > 0; s >>= 1) {
        if (threadIdx.x < s) lds[threadIdx.x] += lds[threadIdx.x + s];
        __syncthreads();
    }
    if (threadIdx.x == 0) part[blockIdx.x] = lds[0];
}

// single block of 512 threads: exclusive scan of chunk sums (nch <= 512)
__global__ void k_scan2(int* __restrict__ part, int nch, int* __restrict__ off, int N) {
    __shared__ int lds[512];
    int t = threadIdx.x;
    int orig = (t < nch) ? part[t] : 0;
    lds[t] = orig;
    __syncthreads();
    for (int s = 1; s < 512; s <<= 1) {
        int v = (t >= s) ? lds[t - s] : 0;
        __syncthreads();
        lds[t] += v;
        __syncthreads();
    }
    if (t < nch) part[t] = lds[t] - orig;   // exclusive chunk base
    if (t == 511) off[N] = lds[511];        // total = E
}

__global__ void k_scan3(const int* __restrict__ deg, const int* __restrict__ part,
                        int* __restrict__ off, int* __restrict__ cursor, int N) {
    __shared__ int lds[256];
    int i = blockIdx.x * 256 + threadIdx.x;
    int d = (i < N) ? deg[i] : 0;
    lds[threadIdx.x] = d;
    __syncthreads();
    for (int s = 1; s < 256; s <<= 1) {
        int v = (threadIdx.x >= s) ? lds[threadIdx.x - s] : 0;
        __syncthreads();
        lds[threadIdx.x] += v;
        __syncthreads();
    }
    if (i < N) {
        int o = part[blockIdx.x] + lds[threadIdx.x] - d;
        off[i] = o;
        cursor[i] = o;
    }
}

__global__ void k_fill(const int* __restrict__ srcI, const int* __restrict__ dstI,
                       int* __restrict__ cursor, int* __restrict__ csr, int E) {
    int e = blockIdx.x * blockDim.x + threadIdx.x;
    if (e >= E) return;
    int d = dstI[e];
    int pos = atomicAdd(&cursor[d], 1);
    csr[pos] = srcI[e];
}

// ======================= attention-coefficient precompute =======================
// p_src[h*K+k] = sum_c W[k*256 + h*64 + c] * a_src[h*64 + c]   (one wave per output)
__global__ void k_prep(const float* __restrict__ W, const float* __restrict__ asrc,
                       const float* __restrict__ adst, float* __restrict__ p_src,
                       float* __restrict__ p_dst, int K) {
    int wid = (blockIdx.x * blockDim.x + threadIdx.x) >> 6;
    int lane = threadIdx.x & 63;
    int total = K * 4 * 2;
    if (wid >= total) return;
    int which = wid / (K * 4);
    int hk = wid % (K * 4);
    int h = hk / K, k = hk % K;
    const float* a = which ? adst : asrc;
    float v = W[(size_t)k * 256 + h * 64 + lane] * a[h * 64 + lane];
    v = wred_sum(v);
    if (lane == 0) (which ? p_dst : p_src)[h * K + k] = v;
}

// es[n,h] = sum_k x[n,k] * ps[h*3+k]  (layer 1; 3-dim input)
__global__ void k_esed1(const float* __restrict__ x, const float* __restrict__ ps,
                        const float* __restrict__ pd, float* __restrict__ es,
                        float* __restrict__ ed, int N) {
    int n = blockIdx.x * blockDim.x + threadIdx.x;
    if (n >= N) return;
    float x0 = x[n * 3], x1 = x[n * 3 + 1], x2 = x[n * 3 + 2];
    float4 s, d;
    s.x = x0 * ps[0] + x1 * ps[1] + x2 * ps[2];
    s.y = x0 * ps[3] + x1 * ps[4] + x2 * ps[5];
    s.z = x0 * ps[6] + x1 * ps[7] + x2 * ps[8];
    s.w = x0 * ps[9] + x1 * ps[10] + x2 * ps[11];
    d.x = x0 * pd[0] + x1 * pd[1] + x2 * pd[2];
    d.y = x0 * pd[3] + x1 * pd[4] + x2 * pd[5];
    d.z = x0 * pd[6] + x1 * pd[7] + x2 * pd[8];
    d.w = x0 * pd[9] + x1 * pd[10] + x2 * pd[11];
    ((float4*)es)[n] = s;
    ((float4*)ed)[n] = d;
}

// es[n,h] = sum_k hout[n,k] * qs[h*64+k]  (layer 2; wave per node)
__global__ void k_esed2(const float* __restrict__ hout, const float* __restrict__ qs,
                        const float* __restrict__ qd, float* __restrict__ es,
                        float* __restrict__ ed, int N) {
    int wid = (blockIdx.x * blockDim.x + threadIdx.x) >> 6;
    int lane = threadIdx.x & 63;
    if (wid >= N) return;
    float v = hout[(size_t)wid * 64 + lane];
    float4 s4, d4;
    s4.x = wred_sum(v * qs[lane]);
    s4.y = wred_sum(v * qs[64 + lane]);
    s4.z = wred_sum(v * qs[128 + lane]);
    s4.w = wred_sum(v * qs[192 + lane]);
    d4.x = wred_sum(v * qd[lane]);
    d4.y = wred_sum(v * qd[64 + lane]);
    d4.z = wred_sum(v * qd[128 + lane]);
    d4.w = wred_sum(v * qd[192 + lane]);
    if (lane == 0) {
        ((float4*)es)[wid] = s4;
        ((float4*)ed)[wid] = d4;
    }
}

// ======================= layer 1 fused aggregate =======================
// wave per dst node: softmax over in-edges (registers), aggregate x[src] (3-dim),
// then out[c] = 0.25 * sum_{h,k} agg3[h][k] * W1[k*256+h*64+c] + b1[c], relu.
__global__ void k_agg1(const int* __restrict__ off, const int* __restrict__ csr,
                       const float* __restrict__ es, const float* __restrict__ ed,
                       const float* __restrict__ x, const float* __restrict__ W1,
                       const float* __restrict__ b1, float* __restrict__ hout, int N) {
    int wid = (blockIdx.x * blockDim.x + threadIdx.x) >> 6;
    int lane = threadIdx.x & 63;
    if (wid >= N) return;
    int o0 = off[wid], o1 = off[wid + 1];
    int deg = o1 - o0;
    float4 edv = ((const float4*)ed)[wid];

    // pass 1: per-head max
    float m0 = -INFINITY, m1 = -INFINITY, m2 = -INFINITY, m3 = -INFINITY;
    int s_cache = 0;
    float c0 = 0.f, c1 = 0.f, c2 = 0.f, c3 = 0.f;
    for (int j = lane; j < deg; j += 64) {
        int s = csr[o0 + j];
        float4 ev = ((const float4*)es)[s];
        float e0 = lrelu(ev.x + edv.x), e1 = lrelu(ev.y + edv.y);
        float e2 = lrelu(ev.z + edv.z), e3 = lrelu(ev.w + edv.w);
        if (j < 64) { s_cache = s; c0 = e0; c1 = e1; c2 = e2; c3 = e3; }
        m0 = fmaxf(m0, e0); m1 = fmaxf(m1, e1);
        m2 = fmaxf(m2, e2); m3 = fmaxf(m3, e3);
    }
    m0 = wred_max(m0); m1 = wred_max(m1); m2 = wred_max(m2); m3 = wred_max(m3);

    // pass 2: sum of exp (cache regs become ex)
    float t0 = 0.f, t1 = 0.f, t2 = 0.f, t3 = 0.f;
    for (int j = lane; j < deg; j += 64) {
        float e0, e1, e2, e3;
        if (j < 64) { e0 = c0; e1 = c1; e2 = c2; e3 = c3; }
        else {
            int s = csr[o0 + j];
            float4 ev = ((const float4*)es)[s];
            e0 = lrelu(ev.x + edv.x); e1 = lrelu(ev.y + edv.y);
            e2 = lrelu(ev.z + edv.z); e3 = lrelu(ev.w + edv.w);
        }
        e0 = expf(e0 - m0); e1 = expf(e1 - m1);
        e2 = expf(e2 - m2); e3 = expf(e3 - m3);
        if (j < 64) { c0 = e0; c1 = e1; c2 = e2; c3 = e3; }
        t0 += e0; t1 += e1; t2 += e2; t3 += e3;
    }
    t0 = wred_sum(t0); t1 = wred_sum(t1); t2 = wred_sum(t2); t3 = wred_sum(t3);
    float i0 = t0 > 0.f ? 1.f / t0 : 0.f;
    float i1 = t1 > 0.f ? 1.f / t1 : 0.f;
    float i2 = t2 > 0.f ? 1.f / t2 : 0.f;
    float i3 = t3 > 0.f ? 1.f / t3 : 0.f;

    // pass 3: agg3[h][k] = sum_e alpha_eh * x[src,k]
    float a00 = 0, a01 = 0, a02 = 0, a10 = 0, a11 = 0, a12 = 0;
    float a20 = 0, a21 = 0, a22 = 0, a30 = 0, a31 = 0, a32 = 0;
    for (int j = lane; j < deg; j += 64) {
        float e0, e1, e2, e3; int s;
        if (j < 64) { s = s_cache; e0 = c0; e1 = c1; e2 = c2; e3 = c3; }
        else {
            s = csr[o0 + j];
            float4 ev = ((const float4*)es)[s];
            e0 = expf(lrelu(ev.x + edv.x) - m0);
            e1 = expf(lrelu(ev.y + edv.y) - m1);
            e2 = expf(lrelu(ev.z + edv.z) - m2);
            e3 = expf(lrelu(ev.w + edv.w) - m3);
        }
        float al0 = e0 * i0, al1 = e1 * i1, al2 = e2 * i2, al3 = e3 * i3;
        float xv0 = x[s * 3], xv1 = x[s * 3 + 1], xv2 = x[s * 3 + 2];
        a00 += al0 * xv0; a01 += al0 * xv1; a02 += al0 * xv2;
        a10 += al1 * xv0; a11 += al1 * xv1; a12 += al1 * xv2;
        a20 += al2 * xv0; a21 += al2 * xv1; a22 += al2 * xv2;
        a30 += al3 * xv0; a31 += al3 * xv1; a32 += al3 * xv2;
    }
    a00 = wred_sum(a00); a01 = wred_sum(a01); a02 = wred_sum(a02);
    a10 = wred_sum(a10); a11 = wred_sum(a11); a12 = wred_sum(a12);
    a20 = wred_sum(a20); a21 = wred_sum(a21); a22 = wred_sum(a22);
    a30 = wred_sum(a30); a31 = wred_sum(a31); a32 = wred_sum(a32);

    // epilogue: lane = output channel
    float r = a00 * W1[0 * 256 + 0 + lane]   + a01 * W1[1 * 256 + 0 + lane]   + a02 * W1[2 * 256 + 0 + lane]
            + a10 * W1[0 * 256 + 64 + lane]  + a11 * W1[1 * 256 + 64 + lane]  + a12 * W1[2 * 256 + 64 + lane]
            + a20 * W1[0 * 256 + 128 + lane] + a21 * W1[1 * 256 + 128 + lane] + a22 * W1[2 * 256 + 128 + lane]
            + a30 * W1[0 * 256 + 192 + lane] + a31 * W1[1 * 256 + 192 + lane] + a32 * W1[2 * 256 + 192 + lane];
    r = 0.25f * r + b1[lane];
    hout[(size_t)wid * 64 + lane] = fmaxf(r, 0.f);
}

// ======================= layer 2 aggregate =======================
// wave per dst node: softmax (lane=edge, register-cached), then lane=k accumulation
// of agg64[h][k] = sum_e alpha_eh * hout[src, k]; written to agg[N,4,64].
__global__ void k_agg2(const int* __restrict__ off, const int* __restrict__ csr,
                       const float* __restrict__ es, const float* __restrict__ ed,
                       const float* __restrict__ hout, float* __restrict__ agg, int N) {
    int wid = (blockIdx.x * blockDim.x + threadIdx.x) >> 6;
    int lane = threadIdx.x & 63;
    if (wid >= N) return;
    int o0 = off[wid], o1 = off[wid + 1];
    int deg = o1 - o0;
    float4 edv = ((const float4*)ed)[wid];

    float m0 = -INFINITY, m1 = -INFINITY, m2 = -INFINITY, m3 = -INFINITY;
    int s_cache = 0;
    float c0 = 0.f, c1 = 0.f, c2 = 0.f, c3 = 0.f;
    for (int j = lane; j < deg; j += 64) {
        int s = csr[o0 + j];
        float4 ev = ((const float4*)es)[s];
        float e0 = lrelu(ev.x + edv.x), e1 = lrelu(ev.y + edv.y);
        float e2 = lrelu(ev.z + edv.z), e3 = lrelu(ev.w + edv.w);
        if (j < 64) { s_cache = s; c0 = e0; c1 = e1; c2 = e2; c3 = e3; }
        m0 = fmaxf(m0, e0); m1 = fmaxf(m1, e1);
        m2 = fmaxf(m2, e2); m3 = fmaxf(m3, e3);
    }
    m0 = wred_max(m0); m1 = wred_max(m1); m2 = wred_max(m2); m3 = wred_max(m3);

    float t0 = 0.f, t1 = 0.f, t2 = 0.f, t3 = 0.f;
    for (int j = lane; j < deg; j += 64) {
        float e0, e1, e2, e3;
        if (j < 64) { e0 = c0; e1 = c1; e2 = c2; e3 = c3; }
        else {
            int s = csr[o0 + j];
            float4 ev = ((const float4*)es)[s];
            e0 = lrelu(ev.x + edv.x); e1 = lrelu(ev.y + edv.y);
            e2 = lrelu(ev.z + edv.z); e3 = lrelu(ev.w + edv.w);
        }
        e0 = expf(e0 - m0); e1 = expf(e1 - m1);
        e2 = expf(e2 - m2); e3 = expf(e3 - m3);
        if (j < 64) { c0 = e0; c1 = e1; c2 = e2; c3 = e3; }
        t0 += e0; t1 += e1; t2 += e2; t3 += e3;
    }
    t0 = wred_sum(t0); t1 = wred_sum(t1); t2 = wred_sum(t2); t3 = wred_sum(t3);
    float i0 = t0 > 0.f ? 1.f / t0 : 0.f;
    float i1 = t1 > 0.f ? 1.f / t1 : 0.f;
    float i2 = t2 > 0.f ? 1.f / t2 : 0.f;
    float i3 = t3 > 0.f ? 1.f / t3 : 0.f;

    // pass 3: lane = k (feature dim); alphas fetched from edge-lanes via shuffle
    float acc0 = 0.f, acc1 = 0.f, acc2 = 0.f, acc3 = 0.f;
    int dmain = deg < 64 ? deg : 64;
    for (int j = 0; j < dmain; j++) {
        int s = __shfl(s_cache, j);
        float al0 = __shfl(c0, j) * i0;
        float al1 = __shfl(c1, j) * i1;
        float al2 = __shfl(c2, j) * i2;
        float al3 = __shfl(c3, j) * i3;
        float v = hout[(size_t)s * 64 + lane];
        acc0 += al0 * v; acc1 += al1 * v; acc2 += al2 * v; acc3 += al3 * v;
    }
    for (int j = 64; j < deg; j++) {  // rare tail (deg > 64)
        int s = csr[o0 + j];
        float4 ev = ((const float4*)es)[s];
        float al0 = expf(lrelu(ev.x + edv.x) - m0) * i0;
        float al1 = expf(lrelu(ev.y + edv.y) - m1) * i1;
        float al2 = expf(lrelu(ev.z + edv.z) - m2) * i2;
        float al3 = expf(lrelu(ev.w + edv.w) - m3) * i3;
        float v = hout[(size_t)s * 64 + lane];
        acc0 += al0 * v; acc1 += al1 * v; acc2 += al2 * v; acc3 += al3 * v;
    }
    size_t b = (size_t)wid * 256;
    agg[b + lane] = acc0;
    agg[b + 64 + lane] = acc1;
    agg[b + 128 + lane] = acc2;
    agg[b + 192 + lane] = acc3;
}

// ======================= layer 2 output transform =======================
// hout2[n,c] = relu(0.25 * sum_{h,k} agg[n,h*64+k] * W2[k*256+h*64+c] + b2[c])
#define NB2 32
__global__ void k_out2(const float* __restrict__ agg, const float* __restrict__ W2,
                       const float* __restrict__ b2, float* __restrict__ hout2, int N) {
    __shared__ float lds[NB2 * 256];
    int t = threadIdx.x;
    int base = blockIdx.x * NB2;
    const float4* src = (const float4*)(agg + (size_t)base * 256);
    int limit4 = (N - base < NB2 ? N - base : NB2) * 64;
    for (int i = t; i < NB2 * 64; i += 256) {
        float4 v = (i < limit4) ? src[i] : make_float4(0.f, 0.f, 0.f, 0.f);
        ((float4*)lds)[i] = v;
    }
    __syncthreads();
    int c = t & 63, slot = t >> 6;
    float bv = b2[c];
    float acc[NB2 / 4];
#pragma unroll
    for (int j = 0; j < NB2 / 4; j++) acc[j] = 0.f;
    for (int hk = 0; hk < 256; hk++) {
        int h = hk >> 6, k = hk & 63;
        float w = W2[k * 256 + h * 64 + c];
#pragma unroll
        for (int j = 0; j < NB2 / 4; j++) acc[j] += lds[(slot + j * 4) * 256 + hk] * w;
    }
#pragma unroll
    for (int j = 0; j < NB2 / 4; j++) {
        int n = base + slot + j * 4;
        if (n < N) {
            float r = 0.25f * acc[j] + bv;
            hout2[(size_t)n * 64 + c] = fmaxf(r, 0.f);
        }
    }
}

// ======================= global add pool =======================
__global__ void k_pool(const float* __restrict__ h2, const int* __restrict__ batch,
                       float* __restrict__ out, int N, int G) {
    int g = blockIdx.x;
    if (g >= G) return;
    int lo = 0, hi = N;
    while (lo < hi) { int mid = (lo + hi) >> 1; if (batch[mid] < g) lo = mid + 1; else hi = mid; }
    int start = lo;
    lo = start; hi = N;
    while (lo < hi) { int mid = (lo + hi) >> 1; if (batch[mid] < g + 1) lo = mid + 1; else hi = mid; }
    int end = lo;
    int t = threadIdx.x, c = t & 63, j = t >> 6;
    float p = 0.f;
    for (int n = start + j; n < end; n += 4) p += h2[(size_t)n * 64 + c];
    __shared__ float lds[256];
    lds[t] = p;
    __syncthreads();
    if (j == 0) out[g * 64 + c] = lds[c] + lds[64 + c] + lds[128 + c] + lds[192 + c];
}

extern "C" void kernel_launch(void* const* d_in, const int* in_sizes, int n_in,
                              void* d_out, int out_size, void* d_ws, size_t ws_size,
                              hipStream_t stream) {
    const float* x   = (const float*)d_in[0];
    const int*   ei  = (const int*)d_in[1];
    const int*   bat = (const int*)d_in[2];
    const float* W1  = (const float*)d_in[3];
    const float* as1 = (const float*)d_in[4];
    const float* ad1 = (const float*)d_in[5];
    const float* b1  = (const float*)d_in[6];
    const float* W2  = (const float*)d_in[7];
    const float* as2 = (const float*)d_in[8];
    const float* ad2 = (const float*)d_in[9];
    const float* b2  = (const float*)d_in[10];
    float* out = (float*)d_out;

    int N = in_sizes[0] / 3;
    int E = in_sizes[1] / 2;
    int G = out_size / 64;
    const int* srcI = ei;
    const int* dstI = ei + E;

    // ---- workspace layout (floats first, then ints) ----
    float* fw = (float*)d_ws;
    size_t fo = 0;
    float* agg   = fw + fo; fo += (size_t)N * 256;
    float* hout  = fw + fo; fo += (size_t)N * 64;
    float* hout2 = fw + fo; fo += (size_t)N * 64;
    float* es    = fw + fo; fo += (size_t)N * 4;
    float* ed    = fw + fo; fo += (size_t)N * 4;
    float* p1s   = fw + fo; fo += 64;
    float* p1d   = fw + fo; fo += 64;
    float* qs    = fw + fo; fo += 256;
    float* qd    = fw + fo; fo += 256;
    int* iw = (int*)(fw + fo);
    size_t io = 0;
    int* deg    = iw + io; io += N;
    int* cursor = iw + io; io += N;
    int* off    = iw + io; io += N + 64;
    int* part   = iw + io; io += 512;
    int* csr    = iw + io; io += E;

    int nThrBlk = (N + 255) / 256;
    int eThrBlk = (E + 255) / 256;
    int nWaveBlk = (N + 3) / 4;   // wave per node, 4 waves/block
    int nch = (N + 255) / 256;    // scan chunks (<=512 for N<=131072)

    // ---- CSR build (dst-sorted), reused by both layers ----
    k_zero<<<nThrBlk, 256, 0, stream>>>(deg, N);
    k_hist<<<eThrBlk, 256, 0, stream>>>(dstI, deg, E);
    k_scan1<<<nch, 256, 0, stream>>>(deg, part, N);
    k_scan2<<<1, 512, 0, stream>>>(part, nch, off, N);
    k_scan3<<<nch, 256, 0, stream>>>(deg, part, off, cursor, N);
    k_fill<<<eThrBlk, 256, 0, stream>>>(srcI, dstI, cursor, csr, E);

    // ---- layer 1 ----
    k_prep<<<(3 * 8 * 64 + 255) / 256, 256, 0, stream>>>(W1, as1, ad1, p1s, p1d, 3);
    k_esed1<<<nThrBlk, 256, 0, stream>>>(x, p1s, p1d, es, ed, N);
    k_agg1<<<nWaveBlk, 256, 0, stream>>>(off, csr, es, ed, x, W1, b1, hout, N);

    // ---- layer 2 ----
    k_prep<<<(64 * 8 * 64 + 255) / 256, 256, 0, stream>>>(W2, as2, ad2, qs, qd, 64);
    k_esed2<<<nWaveBlk, 256, 0, stream>>>(hout, qs, qd, es, ed, N);
    k_agg2<<<nWaveBlk, 256, 0, stream>>>(off, csr, es, ed, hout, agg, N);
    k_out2<<<(N + NB2 - 1) / NB2, 256, 0, stream>>>(agg, W2, b2, hout2, N);

    // ---- pool ----
    k_pool<<<G, 256, 0, stream>>>(hout2, bat, out, N, G);
}

// Round 3
// 769.318 us; speedup vs baseline: 3.0201x; 1.0193x over previous
//
#include <hip/hip_runtime.h>
#include <math.h>

#define HEADS 4
#define HID 64

__device__ __forceinline__ float lrelu(float x) { return x > 0.f ? x : 0.2f * x; }

__device__ __forceinline__ float wred_sum(float v) {
#pragma unroll
    for (int o = 32; o > 0; o >>= 1) v += __shfl_xor(v, o);
    return v;
}
__device__ __forceinline__ float wred_max(float v) {
#pragma unroll
    for (int o = 32; o > 0; o >>= 1) v = fmaxf(v, __shfl_xor(v, o));
    return v;
}

// ======================= CSR build (dst-sorted) =======================
__global__ void k_zero(int* __restrict__ deg, int N) {
    int i = blockIdx.x * blockDim.x + threadIdx.x;
    if (i < N) deg[i] = 0;
}

__global__ void k_hist(const int* __restrict__ dstI, int* __restrict__ deg, int E) {
    int e = blockIdx.x * blockDim.x + threadIdx.x;
    if (e < E) atomicAdd(&deg[dstI[e]], 1);
}

__global__ void k_scan1(const int* __restrict__ deg, int* __restrict__ part, int N) {
    __shared__ int lds[256];
    int i = blockIdx.x * 256 + threadIdx.x;
    lds[threadIdx.x] = (i < N) ? deg[i] : 0;
    __syncthreads();
    for (int s = 128; s > 0; s >>= 1) {
        if (threadIdx.x < s) lds[threadIdx.x] += lds[threadIdx.x + s];
        __syncthreads();
    }
    if (threadIdx.x == 0) part[blockIdx.x] = lds[0];
}

__global__ void k_scan2(int* __restrict__ part, int nch, int* __restrict__ off, int N) {
    __shared__ int lds[512];
    int t = threadIdx.x;
    int orig = (t < nch) ? part[t] : 0;
    lds[t] = orig;
    __syncthreads();
    for (int s = 1; s < 512; s <<= 1) {
        int v = (t >= s) ? lds[t - s] : 0;
        __syncthreads();
        lds[t] += v;
        __syncthreads();
    }
    if (t < nch) part[t] = lds[t] - orig;
    if (t == 511) off[N] = lds[511];
}

__global__ void k_scan3(const int* __restrict__ deg, const int* __restrict__ part,
                        int* __restrict__ off, int* __restrict__ cursor, int N) {
    __shared__ int lds[256];
    int i = blockIdx.x * 256 + threadIdx.x;
    int d = (i < N) ? deg[i] : 0;
    lds[threadIdx.x] = d;
    __syncthreads();
    for (int s = 1; s < 256; s <<= 1) {
        int v = (threadIdx.x >= s) ? lds[threadIdx.x - s] : 0;
        __syncthreads();
        lds[threadIdx.x] += v;
        __syncthreads();
    }
    if (i < N) {
        int o = part[blockIdx.x] + lds[threadIdx.x] - d;
        off[i] = o;
        cursor[i] = o;
    }
}

__global__ void k_fill(const int* __restrict__ srcI, const int* __restrict__ dstI,
                       int* __restrict__ cursor, int* __restrict__ csr, int E) {
    int e = blockIdx.x * blockDim.x + threadIdx.x;
    if (e >= E) return;
    int d = dstI[e];
    int pos = atomicAdd(&cursor[d], 1);
    csr[pos] = srcI[e];
}

// ======================= attention-coefficient precompute =======================
// p_src[h*K+k] = sum_c W[k*256 + h*64 + c] * a_src[h*64 + c]
__global__ void k_prep(const float* __restrict__ W, const float* __restrict__ asrc,
                       const float* __restrict__ adst, float* __restrict__ p_src,
                       float* __restrict__ p_dst, int K) {
    int wid = (blockIdx.x * blockDim.x + threadIdx.x) >> 6;
    int lane = threadIdx.x & 63;
    int total = K * 4 * 2;
    if (wid >= total) return;
    int which = wid / (K * 4);
    int hk = wid % (K * 4);
    int h = hk / K, k = hk % K;
    const float* a = which ? adst : asrc;
    float v = W[(size_t)k * 256 + h * 64 + lane] * a[h * 64 + lane];
    v = wred_sum(v);
    if (lane == 0) (which ? p_dst : p_src)[h * K + k] = v;
}

// es[n,h] = sum_k x[n,k] * ps[h*3+k]  (layer 1)
__global__ void k_esed1(const float* __restrict__ x, const float* __restrict__ ps,
                        const float* __restrict__ pd, float* __restrict__ es,
                        float* __restrict__ ed, int N) {
    int n = blockIdx.x * blockDim.x + threadIdx.x;
    if (n >= N) return;
    float x0 = x[n * 3], x1 = x[n * 3 + 1], x2 = x[n * 3 + 2];
    float4 s, d;
    s.x = x0 * ps[0] + x1 * ps[1] + x2 * ps[2];
    s.y = x0 * ps[3] + x1 * ps[4] + x2 * ps[5];
    s.z = x0 * ps[6] + x1 * ps[7] + x2 * ps[8];
    s.w = x0 * ps[9] + x1 * ps[10] + x2 * ps[11];
    d.x = x0 * pd[0] + x1 * pd[1] + x2 * pd[2];
    d.y = x0 * pd[3] + x1 * pd[4] + x2 * pd[5];
    d.z = x0 * pd[6] + x1 * pd[7] + x2 * pd[8];
    d.w = x0 * pd[9] + x1 * pd[10] + x2 * pd[11];
    ((float4*)es)[n] = s;
    ((float4*)ed)[n] = d;
}

// ======================= layer 1: fused aggregate + hout + layer-2 es/ed =======================
__global__ void k_agg1(const int* __restrict__ off, const int* __restrict__ csr,
                       const float* __restrict__ es, const float* __restrict__ ed,
                       const float* __restrict__ x, const float* __restrict__ W1,
                       const float* __restrict__ b1, const float* __restrict__ qs,
                       const float* __restrict__ qd, float* __restrict__ hout,
                       float* __restrict__ es2, float* __restrict__ ed2, int N) {
    int wid = (blockIdx.x * blockDim.x + threadIdx.x) >> 6;
    int lane = threadIdx.x & 63;
    if (wid >= N) return;
    int o0 = off[wid], o1 = off[wid + 1];
    int deg = o1 - o0;
    float4 edv = ((const float4*)ed)[wid];

    // pass 1: per-head max (cache first-64 edge values)
    float m0 = -INFINITY, m1 = -INFINITY, m2 = -INFINITY, m3 = -INFINITY;
    int s_cache = 0;
    float c0 = 0.f, c1 = 0.f, c2 = 0.f, c3 = 0.f;
    for (int j = lane; j < deg; j += 64) {
        int s = csr[o0 + j];
        float4 ev = ((const float4*)es)[s];
        float e0 = lrelu(ev.x + edv.x), e1 = lrelu(ev.y + edv.y);
        float e2 = lrelu(ev.z + edv.z), e3 = lrelu(ev.w + edv.w);
        if (j < 64) { s_cache = s; c0 = e0; c1 = e1; c2 = e2; c3 = e3; }
        m0 = fmaxf(m0, e0); m1 = fmaxf(m1, e1);
        m2 = fmaxf(m2, e2); m3 = fmaxf(m3, e3);
    }
    m0 = wred_max(m0); m1 = wred_max(m1); m2 = wred_max(m2); m3 = wred_max(m3);

    // pass 2: sum of exp
    float t0 = 0.f, t1 = 0.f, t2 = 0.f, t3 = 0.f;
    for (int j = lane; j < deg; j += 64) {
        float e0, e1, e2, e3;
        if (j < 64) { e0 = c0; e1 = c1; e2 = c2; e3 = c3; }
        else {
            int s = csr[o0 + j];
            float4 ev = ((const float4*)es)[s];
            e0 = lrelu(ev.x + edv.x); e1 = lrelu(ev.y + edv.y);
            e2 = lrelu(ev.z + edv.z); e3 = lrelu(ev.w + edv.w);
        }
        e0 = expf(e0 - m0); e1 = expf(e1 - m1);
        e2 = expf(e2 - m2); e3 = expf(e3 - m3);
        if (j < 64) { c0 = e0; c1 = e1; c2 = e2; c3 = e3; }
        t0 += e0; t1 += e1; t2 += e2; t3 += e3;
    }
    t0 = wred_sum(t0); t1 = wred_sum(t1); t2 = wred_sum(t2); t3 = wred_sum(t3);
    float i0 = t0 > 0.f ? 1.f / t0 : 0.f;
    float i1 = t1 > 0.f ? 1.f / t1 : 0.f;
    float i2 = t2 > 0.f ? 1.f / t2 : 0.f;
    float i3 = t3 > 0.f ? 1.f / t3 : 0.f;

    // pass 3: agg3[h][k] = sum_e alpha_eh * x[src,k]
    float a00 = 0, a01 = 0, a02 = 0, a10 = 0, a11 = 0, a12 = 0;
    float a20 = 0, a21 = 0, a22 = 0, a30 = 0, a31 = 0, a32 = 0;
    for (int j = lane; j < deg; j += 64) {
        float e0, e1, e2, e3; int s;
        if (j < 64) { s = s_cache; e0 = c0; e1 = c1; e2 = c2; e3 = c3; }
        else {
            s = csr[o0 + j];
            float4 ev = ((const float4*)es)[s];
            e0 = expf(lrelu(ev.x + edv.x) - m0);
            e1 = expf(lrelu(ev.y + edv.y) - m1);
            e2 = expf(lrelu(ev.z + edv.z) - m2);
            e3 = expf(lrelu(ev.w + edv.w) - m3);
        }
        float al0 = e0 * i0, al1 = e1 * i1, al2 = e2 * i2, al3 = e3 * i3;
        float xv0 = x[s * 3], xv1 = x[s * 3 + 1], xv2 = x[s * 3 + 2];
        a00 += al0 * xv0; a01 += al0 * xv1; a02 += al0 * xv2;
        a10 += al1 * xv0; a11 += al1 * xv1; a12 += al1 * xv2;
        a20 += al2 * xv0; a21 += al2 * xv1; a22 += al2 * xv2;
        a30 += al3 * xv0; a31 += al3 * xv1; a32 += al3 * xv2;
    }
    a00 = wred_sum(a00); a01 = wred_sum(a01); a02 = wred_sum(a02);
    a10 = wred_sum(a10); a11 = wred_sum(a11); a12 = wred_sum(a12);
    a20 = wred_sum(a20); a21 = wred_sum(a21); a22 = wred_sum(a22);
    a30 = wred_sum(a30); a31 = wred_sum(a31); a32 = wred_sum(a32);

    // epilogue: lane = output channel
    float r = a00 * W1[0 * 256 + 0 + lane]   + a01 * W1[1 * 256 + 0 + lane]   + a02 * W1[2 * 256 + 0 + lane]
            + a10 * W1[0 * 256 + 64 + lane]  + a11 * W1[1 * 256 + 64 + lane]  + a12 * W1[2 * 256 + 64 + lane]
            + a20 * W1[0 * 256 + 128 + lane] + a21 * W1[1 * 256 + 128 + lane] + a22 * W1[2 * 256 + 128 + lane]
            + a30 * W1[0 * 256 + 192 + lane] + a31 * W1[1 * 256 + 192 + lane] + a32 * W1[2 * 256 + 192 + lane];
    float hv = fmaxf(0.25f * r + b1[lane], 0.f);
    hout[(size_t)wid * 64 + lane] = hv;

    // fused layer-2 attention coefficients: es2[n,h] = sum_k hv_k * qs[h*64+k]
    float4 s4, d4;
    s4.x = wred_sum(hv * qs[lane]);
    s4.y = wred_sum(hv * qs[64 + lane]);
    s4.z = wred_sum(hv * qs[128 + lane]);
    s4.w = wred_sum(hv * qs[192 + lane]);
    d4.x = wred_sum(hv * qd[lane]);
    d4.y = wred_sum(hv * qd[64 + lane]);
    d4.z = wred_sum(hv * qd[128 + lane]);
    d4.w = wred_sum(hv * qd[192 + lane]);
    if (lane == 0) {
        ((float4*)es2)[wid] = s4;
        ((float4*)ed2)[wid] = d4;
    }
}

// ======================= layer 2: aggregate + fused W2 transform =======================
// wave per dst node. LDS-staged alpha/src for pass 3 (wave-uniform broadcast reads,
// unroll-4 for load overlap), then in-wave 256x64 matvec with W2 streamed through L1.
__global__ void k_agg2(const int* __restrict__ off, const int* __restrict__ csr,
                       const float* __restrict__ es, const float* __restrict__ ed,
                       const float* __restrict__ hout, const float* __restrict__ W2,
                       const float* __restrict__ b2, float* __restrict__ hout2, int N) {
    __shared__ float alds[4 * 256];   // per-wave: 64 edges x float4 alpha
    __shared__ int   slds[4 * 64];    // per-wave: 64 src indices
    __shared__ float aggl[4 * 256];   // per-wave: agg transposed [k*4+h]
    int w = threadIdx.x >> 6, lane = threadIdx.x & 63;
    int wid = blockIdx.x * 4 + w;
    bool active = wid < N;

    int o0 = 0, deg = 0;
    float4 edv = make_float4(0.f, 0.f, 0.f, 0.f);
    if (active) {
        o0 = off[wid];
        deg = off[wid + 1] - o0;
        edv = ((const float4*)ed)[wid];
    }

    // pass 1: per-head max (cache first-64 edges)
    float m0 = -INFINITY, m1 = -INFINITY, m2 = -INFINITY, m3 = -INFINITY;
    int s_cache = 0;
    float c0 = 0.f, c1 = 0.f, c2 = 0.f, c3 = 0.f;
    for (int j = lane; j < deg; j += 64) {
        int s = csr[o0 + j];
        float4 ev = ((const float4*)es)[s];
        float e0 = lrelu(ev.x + edv.x), e1 = lrelu(ev.y + edv.y);
        float e2 = lrelu(ev.z + edv.z), e3 = lrelu(ev.w + edv.w);
        if (j < 64) { s_cache = s; c0 = e0; c1 = e1; c2 = e2; c3 = e3; }
        m0 = fmaxf(m0, e0); m1 = fmaxf(m1, e1);
        m2 = fmaxf(m2, e2); m3 = fmaxf(m3, e3);
    }
    m0 = wred_max(m0); m1 = wred_max(m1); m2 = wred_max(m2); m3 = wred_max(m3);

    // pass 2: sum of exp
    float t0 = 0.f, t1 = 0.f, t2 = 0.f, t3 = 0.f;
    for (int j = lane; j < deg; j += 64) {
        float e0, e1, e2, e3;
        if (j < 64) { e0 = c0; e1 = c1; e2 = c2; e3 = c3; }
        else {
            int s = csr[o0 + j];
            float4 ev = ((const float4*)es)[s];
            e0 = lrelu(ev.x + edv.x); e1 = lrelu(ev.y + edv.y);
            e2 = lrelu(ev.z + edv.z); e3 = lrelu(ev.w + edv.w);
        }
        e0 = expf(e0 - m0); e1 = expf(e1 - m1);
        e2 = expf(e2 - m2); e3 = expf(e3 - m3);
        if (j < 64) { c0 = e0; c1 = e1; c2 = e2; c3 = e3; }
        t0 += e0; t1 += e1; t2 += e2; t3 += e3;
    }
    t0 = wred_sum(t0); t1 = wred_sum(t1); t2 = wred_sum(t2); t3 = wred_sum(t3);
    float i0 = t0 > 0.f ? 1.f / t0 : 0.f;
    float i1 = t1 > 0.f ? 1.f / t1 : 0.f;
    float i2 = t2 > 0.f ? 1.f / t2 : 0.f;
    float i3 = t3 > 0.f ? 1.f / t3 : 0.f;

    // stage premultiplied alphas + src to LDS (zeros beyond deg)
    bool has = (lane < deg);
    float4 av;
    av.x = has ? c0 * i0 : 0.f;
    av.y = has ? c1 * i1 : 0.f;
    av.z = has ? c2 * i2 : 0.f;
    av.w = has ? c3 * i3 : 0.f;
    ((float4*)(alds + w * 256))[lane] = av;
    slds[w * 64 + lane] = has ? s_cache : 0;
    __syncthreads();

    // pass 3: lane = feature k; alphas via wave-uniform LDS broadcast; unroll 4
    float acc0 = 0.f, acc1 = 0.f, acc2 = 0.f, acc3 = 0.f;
    {
        const float4* A = (const float4*)(alds + w * 256);
        const int* S = slds + w * 64;
        int dmain = deg < 64 ? deg : 64;
        int d4 = (dmain + 3) & ~3;
        for (int j = 0; j < d4; j += 4) {
            float4 a0 = A[j], a1 = A[j + 1], a2 = A[j + 2], a3 = A[j + 3];
            int s0 = S[j], s1 = S[j + 1], s2 = S[j + 2], s3 = S[j + 3];
            float v0 = hout[(size_t)s0 * 64 + lane];
            float v1 = hout[(size_t)s1 * 64 + lane];
            float v2 = hout[(size_t)s2 * 64 + lane];
            float v3 = hout[(size_t)s3 * 64 + lane];
            acc0 += a0.x * v0 + a1.x * v1 + a2.x * v2 + a3.x * v3;
            acc1 += a0.y * v0 + a1.y * v1 + a2.y * v2 + a3.y * v3;
            acc2 += a0.z * v0 + a1.z * v1 + a2.z * v2 + a3.z * v3;
            acc3 += a0.w * v0 + a1.w * v1 + a2.w * v2 + a3.w * v3;
        }
        for (int j = 64; j < deg; j++) {   // rare tail deg>64 (recompute, wave-uniform)
            int s = csr[o0 + j];
            float4 ev = ((const float4*)es)[s];
            float al0 = expf(lrelu(ev.x + edv.x) - m0) * i0;
            float al1 = expf(lrelu(ev.y + edv.y) - m1) * i1;
            float al2 = expf(lrelu(ev.z + edv.z) - m2) * i2;
            float al3 = expf(lrelu(ev.w + edv.w) - m3) * i3;
            float v = hout[(size_t)s * 64 + lane];
            acc0 += al0 * v; acc1 += al1 * v; acc2 += al2 * v; acc3 += al3 * v;
        }
    }

    // stage agg transposed: aggl[k*4+h]
    {
        float4 t;
        t.x = acc0; t.y = acc1; t.z = acc2; t.w = acc3;
        ((float4*)(aggl + w * 256))[lane] = t;
    }
    __syncthreads();

    // fused output transform: out[c] = relu(0.25 * sum_{k,h} agg[h][k]*W2[k*256+h*64+c] + b2[c])
    float oacc = 0.f;
    {
        const float4* G = (const float4*)(aggl + w * 256);
        const float* wl = W2 + lane;
#pragma unroll 4
        for (int k = 0; k < 64; k++) {
            float4 g = G[k];            // (agg[0][k], agg[1][k], agg[2][k], agg[3][k])
            const float* wk = wl + k * 256;
            oacc += g.x * wk[0] + g.y * wk[64] + g.z * wk[128] + g.w * wk[192];
        }
    }
    if (active) {
        float r = 0.25f * oacc + b2[lane];
        hout2[(size_t)wid * 64 + lane] = fmaxf(r, 0.f);
    }
}

// ======================= global add pool =======================
__global__ void k_pool(const float* __restrict__ h2, const int* __restrict__ batch,
                       float* __restrict__ out, int N, int G) {
    int g = blockIdx.x;
    if (g >= G) return;
    int lo = 0, hi = N;
    while (lo < hi) { int mid = (lo + hi) >> 1; if (batch[mid] < g) lo = mid + 1; else hi = mid; }
    int start = lo;
    lo = start; hi = N;
    while (lo < hi) { int mid = (lo + hi) >> 1; if (batch[mid] < g + 1) lo = mid + 1; else hi = mid; }
    int end = lo;
    int t = threadIdx.x, c = t & 63, j = t >> 6;
    float p = 0.f;
    for (int n = start + j; n < end; n += 4) p += h2[(size_t)n * 64 + c];
    __shared__ float lds[256];
    lds[t] = p;
    __syncthreads();
    if (j == 0) out[g * 64 + c] = lds[c] + lds[64 + c] + lds[128 + c] + lds[192 + c];
}

extern "C" void kernel_launch(void* const* d_in, const int* in_sizes, int n_in,
                              void* d_out, int out_size, void* d_ws, size_t ws_size,
                              hipStream_t stream) {
    const float* x   = (const float*)d_in[0];
    const int*   ei  = (const int*)d_in[1];
    const int*   bat = (const int*)d_in[2];
    const float* W1  = (const float*)d_in[3];
    const float* as1 = (const float*)d_in[4];
    const float* ad1 = (const float*)d_in[5];
    const float* b1  = (const float*)d_in[6];
    const float* W2  = (const float*)d_in[7];
    const float* as2 = (const float*)d_in[8];
    const float* ad2 = (const float*)d_in[9];
    const float* b2  = (const float*)d_in[10];
    float* out = (float*)d_out;

    int N = in_sizes[0] / 3;
    int E = in_sizes[1] / 2;
    int G = out_size / 64;
    const int* srcI = ei;
    const int* dstI = ei + E;

    // ---- workspace layout ----
    float* fw = (float*)d_ws;
    size_t fo = 0;
    float* hout  = fw + fo; fo += (size_t)N * 64;
    float* hout2 = fw + fo; fo += (size_t)N * 64;
    float* esA   = fw + fo; fo += (size_t)N * 4;
    float* edA   = fw + fo; fo += (size_t)N * 4;
    float* esB   = fw + fo; fo += (size_t)N * 4;
    float* edB   = fw + fo; fo += (size_t)N * 4;
    float* p1s   = fw + fo; fo += 64;
    float* p1d   = fw + fo; fo += 64;
    float* qs    = fw + fo; fo += 256;
    float* qd    = fw + fo; fo += 256;
    int* iw = (int*)(fw + fo);
    size_t io = 0;
    int* deg    = iw + io; io += N;
    int* cursor = iw + io; io += N;
    int* off    = iw + io; io += N + 64;
    int* part   = iw + io; io += 512;
    int* csr    = iw + io; io += E;

    int nThrBlk = (N + 255) / 256;
    int eThrBlk = (E + 255) / 256;
    int nWaveBlk = (N + 3) / 4;
    int nch = (N + 255) / 256;

    // ---- CSR build (dst-sorted) ----
    k_zero<<<nThrBlk, 256, 0, stream>>>(deg, N);
    k_hist<<<eThrBlk, 256, 0, stream>>>(dstI, deg, E);
    k_scan1<<<nch, 256, 0, stream>>>(deg, part, N);
    k_scan2<<<1, 512, 0, stream>>>(part, nch, off, N);
    k_scan3<<<nch, 256, 0, stream>>>(deg, part, off, cursor, N);
    k_fill<<<eThrBlk, 256, 0, stream>>>(srcI, dstI, cursor, csr, E);

    // ---- precompute attention projections (both layers) ----
    k_prep<<<(3 * 8 * 64 + 255) / 256, 256, 0, stream>>>(W1, as1, ad1, p1s, p1d, 3);
    k_prep<<<(64 * 8 * 64 + 255) / 256, 256, 0, stream>>>(W2, as2, ad2, qs, qd, 64);

    // ---- layer 1 (writes hout + layer-2 es/ed) ----
    k_esed1<<<nThrBlk, 256, 0, stream>>>(x, p1s, p1d, esA, edA, N);
    k_agg1<<<nWaveBlk, 256, 0, stream>>>(off, csr, esA, edA, x, W1, b1, qs, qd,
                                         hout, esB, edB, N);

    // ---- layer 2 (aggregate + fused W2 transform) ----
    k_agg2<<<nWaveBlk, 256, 0, stream>>>(off, csr, esB, edB, hout, W2, b2, hout2, N);

    // ---- pool ----
    k_pool<<<G, 256, 0, stream>>>(hout2, bat, out, N, G);
}

// Round 4
// 724.801 us; speedup vs baseline: 3.2056x; 1.0614x over previous
//
#include <hip/hip_runtime.h>
#include <math.h>

#define HEADS 4
#define HID 64

__device__ __forceinline__ float lrelu(float x) { return x > 0.f ? x : 0.2f * x; }

__device__ __forceinline__ float wred_sum(float v) {
#pragma unroll
    for (int o = 32; o > 0; o >>= 1) v += __shfl_xor(v, o);
    return v;
}
__device__ __forceinline__ float wred_max(float v) {
#pragma unroll
    for (int o = 32; o > 0; o >>= 1) v = fmaxf(v, __shfl_xor(v, o));
    return v;
}

// ======================= CSR build (dst-sorted) =======================
__global__ void k_zero(int* __restrict__ deg, int N) {
    int i = blockIdx.x * blockDim.x + threadIdx.x;
    if (i < N) deg[i] = 0;
}

__global__ void k_hist(const int* __restrict__ dstI, int* __restrict__ deg, int E) {
    int e = blockIdx.x * blockDim.x + threadIdx.x;
    if (e < E) atomicAdd(&deg[dstI[e]], 1);
}

__global__ void k_scan1(const int* __restrict__ deg, int* __restrict__ part, int N) {
    __shared__ int lds[256];
    int i = blockIdx.x * 256 + threadIdx.x;
    lds[threadIdx.x] = (i < N) ? deg[i] : 0;
    __syncthreads();
    for (int s = 128; s > 0; s >>= 1) {
        if (threadIdx.x < s) lds[threadIdx.x] += lds[threadIdx.x + s];
        __syncthreads();
    }
    if (threadIdx.x == 0) part[blockIdx.x] = lds[0];
}

__global__ void k_scan2(int* __restrict__ part, int nch, int* __restrict__ off, int N) {
    __shared__ int lds[512];
    int t = threadIdx.x;
    int orig = (t < nch) ? part[t] : 0;
    lds[t] = orig;
    __syncthreads();
    for (int s = 1; s < 512; s <<= 1) {
        int v = (t >= s) ? lds[t - s] : 0;
        __syncthreads();
        lds[t] += v;
        __syncthreads();
    }
    if (t < nch) part[t] = lds[t] - orig;
    if (t == 511) off[N] = lds[511];
}

__global__ void k_scan3(const int* __restrict__ deg, const int* __restrict__ part,
                        int* __restrict__ off, int* __restrict__ cursor, int N) {
    __shared__ int lds[256];
    int i = blockIdx.x * 256 + threadIdx.x;
    int d = (i < N) ? deg[i] : 0;
    lds[threadIdx.x] = d;
    __syncthreads();
    for (int s = 1; s < 256; s <<= 1) {
        int v = (threadIdx.x >= s) ? lds[threadIdx.x - s] : 0;
        __syncthreads();
        lds[threadIdx.x] += v;
        __syncthreads();
    }
    if (i < N) {
        int o = part[blockIdx.x] + lds[threadIdx.x] - d;
        off[i] = o;
        cursor[i] = o;
    }
}

__global__ void k_fill(const int* __restrict__ srcI, const int* __restrict__ dstI,
                       int* __restrict__ cursor, int* __restrict__ csr, int E) {
    int e = blockIdx.x * blockDim.x + threadIdx.x;
    if (e >= E) return;
    int d = dstI[e];
    int pos = atomicAdd(&cursor[d], 1);
    csr[pos] = srcI[e];
}

// ======================= attention-coefficient precompute =======================
__global__ void k_prep(const float* __restrict__ W, const float* __restrict__ asrc,
                       const float* __restrict__ adst, float* __restrict__ p_src,
                       float* __restrict__ p_dst, int K) {
    int wid = (blockIdx.x * blockDim.x + threadIdx.x) >> 6;
    int lane = threadIdx.x & 63;
    int total = K * 4 * 2;
    if (wid >= total) return;
    int which = wid / (K * 4);
    int hk = wid % (K * 4);
    int h = hk / K, k = hk % K;
    const float* a = which ? adst : asrc;
    float v = W[(size_t)k * 256 + h * 64 + lane] * a[h * 64 + lane];
    v = wred_sum(v);
    if (lane == 0) (which ? p_dst : p_src)[h * K + k] = v;
}

// es[n,h] = sum_k x[n,k] * ps[h*3+k]  (layer 1)
__global__ void k_esed1(const float* __restrict__ x, const float* __restrict__ ps,
                        const float* __restrict__ pd, float* __restrict__ es,
                        float* __restrict__ ed, int N) {
    int n = blockIdx.x * blockDim.x + threadIdx.x;
    if (n >= N) return;
    float x0 = x[n * 3], x1 = x[n * 3 + 1], x2 = x[n * 3 + 2];
    float4 s, d;
    s.x = x0 * ps[0] + x1 * ps[1] + x2 * ps[2];
    s.y = x0 * ps[3] + x1 * ps[4] + x2 * ps[5];
    s.z = x0 * ps[6] + x1 * ps[7] + x2 * ps[8];
    s.w = x0 * ps[9] + x1 * ps[10] + x2 * ps[11];
    d.x = x0 * pd[0] + x1 * pd[1] + x2 * pd[2];
    d.y = x0 * pd[3] + x1 * pd[4] + x2 * pd[5];
    d.z = x0 * pd[6] + x1 * pd[7] + x2 * pd[8];
    d.w = x0 * pd[9] + x1 * pd[10] + x2 * pd[11];
    ((float4*)es)[n] = s;
    ((float4*)ed)[n] = d;
}

// ======================= layer 1: fused aggregate + hout + layer-2 es/ed =======================
__global__ void k_agg1(const int* __restrict__ off, const int* __restrict__ csr,
                       const float* __restrict__ es, const float* __restrict__ ed,
                       const float* __restrict__ x, const float* __restrict__ W1,
                       const float* __restrict__ b1, const float* __restrict__ qs,
                       const float* __restrict__ qd, float* __restrict__ hout,
                       float* __restrict__ es2, float* __restrict__ ed2, int N) {
    int wid = (blockIdx.x * blockDim.x + threadIdx.x) >> 6;
    int lane = threadIdx.x & 63;
    if (wid >= N) return;
    int o0 = off[wid], o1 = off[wid + 1];
    int deg = o1 - o0;
    float4 edv = ((const float4*)ed)[wid];

    // pass 1: per-head max (cache first-64 edge values)
    float m0 = -INFINITY, m1 = -INFINITY, m2 = -INFINITY, m3 = -INFINITY;
    int s_cache = 0;
    float c0 = 0.f, c1 = 0.f, c2 = 0.f, c3 = 0.f;
    for (int j = lane; j < deg; j += 64) {
        int s = csr[o0 + j];
        float4 ev = ((const float4*)es)[s];
        float e0 = lrelu(ev.x + edv.x), e1 = lrelu(ev.y + edv.y);
        float e2 = lrelu(ev.z + edv.z), e3 = lrelu(ev.w + edv.w);
        if (j < 64) { s_cache = s; c0 = e0; c1 = e1; c2 = e2; c3 = e3; }
        m0 = fmaxf(m0, e0); m1 = fmaxf(m1, e1);
        m2 = fmaxf(m2, e2); m3 = fmaxf(m3, e3);
    }
    m0 = wred_max(m0); m1 = wred_max(m1); m2 = wred_max(m2); m3 = wred_max(m3);

    // pass 2: sum of exp
    float t0 = 0.f, t1 = 0.f, t2 = 0.f, t3 = 0.f;
    for (int j = lane; j < deg; j += 64) {
        float e0, e1, e2, e3;
        if (j < 64) { e0 = c0; e1 = c1; e2 = c2; e3 = c3; }
        else {
            int s = csr[o0 + j];
            float4 ev = ((const float4*)es)[s];
            e0 = lrelu(ev.x + edv.x); e1 = lrelu(ev.y + edv.y);
            e2 = lrelu(ev.z + edv.z); e3 = lrelu(ev.w + edv.w);
        }
        e0 = __expf(e0 - m0); e1 = __expf(e1 - m1);
        e2 = __expf(e2 - m2); e3 = __expf(e3 - m3);
        if (j < 64) { c0 = e0; c1 = e1; c2 = e2; c3 = e3; }
        t0 += e0; t1 += e1; t2 += e2; t3 += e3;
    }
    t0 = wred_sum(t0); t1 = wred_sum(t1); t2 = wred_sum(t2); t3 = wred_sum(t3);
    float i0 = t0 > 0.f ? 1.f / t0 : 0.f;
    float i1 = t1 > 0.f ? 1.f / t1 : 0.f;
    float i2 = t2 > 0.f ? 1.f / t2 : 0.f;
    float i3 = t3 > 0.f ? 1.f / t3 : 0.f;

    // pass 3: agg3[h][k] = sum_e alpha_eh * x[src,k]
    float a00 = 0, a01 = 0, a02 = 0, a10 = 0, a11 = 0, a12 = 0;
    float a20 = 0, a21 = 0, a22 = 0, a30 = 0, a31 = 0, a32 = 0;
    for (int j = lane; j < deg; j += 64) {
        float e0, e1, e2, e3; int s;
        if (j < 64) { s = s_cache; e0 = c0; e1 = c1; e2 = c2; e3 = c3; }
        else {
            s = csr[o0 + j];
            float4 ev = ((const float4*)es)[s];
            e0 = __expf(lrelu(ev.x + edv.x) - m0);
            e1 = __expf(lrelu(ev.y + edv.y) - m1);
            e2 = __expf(lrelu(ev.z + edv.z) - m2);
            e3 = __expf(lrelu(ev.w + edv.w) - m3);
        }
        float al0 = e0 * i0, al1 = e1 * i1, al2 = e2 * i2, al3 = e3 * i3;
        float xv0 = x[s * 3], xv1 = x[s * 3 + 1], xv2 = x[s * 3 + 2];
        a00 += al0 * xv0; a01 += al0 * xv1; a02 += al0 * xv2;
        a10 += al1 * xv0; a11 += al1 * xv1; a12 += al1 * xv2;
        a20 += al2 * xv0; a21 += al2 * xv1; a22 += al2 * xv2;
        a30 += al3 * xv0; a31 += al3 * xv1; a32 += al3 * xv2;
    }
    a00 = wred_sum(a00); a01 = wred_sum(a01); a02 = wred_sum(a02);
    a10 = wred_sum(a10); a11 = wred_sum(a11); a12 = wred_sum(a12);
    a20 = wred_sum(a20); a21 = wred_sum(a21); a22 = wred_sum(a22);
    a30 = wred_sum(a30); a31 = wred_sum(a31); a32 = wred_sum(a32);

    // epilogue: lane = output channel
    float r = a00 * W1[0 * 256 + 0 + lane]   + a01 * W1[1 * 256 + 0 + lane]   + a02 * W1[2 * 256 + 0 + lane]
            + a10 * W1[0 * 256 + 64 + lane]  + a11 * W1[1 * 256 + 64 + lane]  + a12 * W1[2 * 256 + 64 + lane]
            + a20 * W1[0 * 256 + 128 + lane] + a21 * W1[1 * 256 + 128 + lane] + a22 * W1[2 * 256 + 128 + lane]
            + a30 * W1[0 * 256 + 192 + lane] + a31 * W1[1 * 256 + 192 + lane] + a32 * W1[2 * 256 + 192 + lane];
    float hv = fmaxf(0.25f * r + b1[lane], 0.f);
    hout[(size_t)wid * 64 + lane] = hv;

    // fused layer-2 attention coefficients
    float4 s4, d4;
    s4.x = wred_sum(hv * qs[lane]);
    s4.y = wred_sum(hv * qs[64 + lane]);
    s4.z = wred_sum(hv * qs[128 + lane]);
    s4.w = wred_sum(hv * qs[192 + lane]);
    d4.x = wred_sum(hv * qd[lane]);
    d4.y = wred_sum(hv * qd[64 + lane]);
    d4.z = wred_sum(hv * qd[128 + lane]);
    d4.w = wred_sum(hv * qd[192 + lane]);
    if (lane == 0) {
        ((float4*)es2)[wid] = s4;
        ((float4*)ed2)[wid] = d4;
    }
}

// ======================= layer 2: aggregate (LDS-staged alpha, writes agg) =======================
__global__ void k_agg2(const int* __restrict__ off, const int* __restrict__ csr,
                       const float* __restrict__ es, const float* __restrict__ ed,
                       const float* __restrict__ hout, float* __restrict__ agg, int N) {
    __shared__ float alds[4 * 256];   // per-wave: 64 edges x float4 alpha
    __shared__ int   slds[4 * 64];    // per-wave: 64 src indices
    int w = threadIdx.x >> 6, lane = threadIdx.x & 63;
    int wid = blockIdx.x * 4 + w;
    bool active = wid < N;

    int o0 = 0, deg = 0;
    float4 edv = make_float4(0.f, 0.f, 0.f, 0.f);
    if (active) {
        o0 = off[wid];
        deg = off[wid + 1] - o0;
        edv = ((const float4*)ed)[wid];
    }

    // pass 1: per-head max (cache first-64 edges)
    float m0 = -INFINITY, m1 = -INFINITY, m2 = -INFINITY, m3 = -INFINITY;
    int s_cache = 0;
    float c0 = 0.f, c1 = 0.f, c2 = 0.f, c3 = 0.f;
    for (int j = lane; j < deg; j += 64) {
        int s = csr[o0 + j];
        float4 ev = ((const float4*)es)[s];
        float e0 = lrelu(ev.x + edv.x), e1 = lrelu(ev.y + edv.y);
        float e2 = lrelu(ev.z + edv.z), e3 = lrelu(ev.w + edv.w);
        if (j < 64) { s_cache = s; c0 = e0; c1 = e1; c2 = e2; c3 = e3; }
        m0 = fmaxf(m0, e0); m1 = fmaxf(m1, e1);
        m2 = fmaxf(m2, e2); m3 = fmaxf(m3, e3);
    }
    m0 = wred_max(m0); m1 = wred_max(m1); m2 = wred_max(m2); m3 = wred_max(m3);

    // pass 2: sum of exp
    float t0 = 0.f, t1 = 0.f, t2 = 0.f, t3 = 0.f;
    for (int j = lane; j < deg; j += 64) {
        float e0, e1, e2, e3;
        if (j < 64) { e0 = c0; e1 = c1; e2 = c2; e3 = c3; }
        else {
            int s = csr[o0 + j];
            float4 ev = ((const float4*)es)[s];
            e0 = lrelu(ev.x + edv.x); e1 = lrelu(ev.y + edv.y);
            e2 = lrelu(ev.z + edv.z); e3 = lrelu(ev.w + edv.w);
        }
        e0 = __expf(e0 - m0); e1 = __expf(e1 - m1);
        e2 = __expf(e2 - m2); e3 = __expf(e3 - m3);
        if (j < 64) { c0 = e0; c1 = e1; c2 = e2; c3 = e3; }
        t0 += e0; t1 += e1; t2 += e2; t3 += e3;
    }
    t0 = wred_sum(t0); t1 = wred_sum(t1); t2 = wred_sum(t2); t3 = wred_sum(t3);
    float i0 = t0 > 0.f ? 1.f / t0 : 0.f;
    float i1 = t1 > 0.f ? 1.f / t1 : 0.f;
    float i2 = t2 > 0.f ? 1.f / t2 : 0.f;
    float i3 = t3 > 0.f ? 1.f / t3 : 0.f;

    // stage premultiplied alphas + src to LDS (zeros beyond deg)
    bool has = (lane < deg);
    float4 av;
    av.x = has ? c0 * i0 : 0.f;
    av.y = has ? c1 * i1 : 0.f;
    av.z = has ? c2 * i2 : 0.f;
    av.w = has ? c3 * i3 : 0.f;
    ((float4*)(alds + w * 256))[lane] = av;
    slds[w * 64 + lane] = has ? s_cache : 0;
    __syncthreads();

    // pass 3: lane = feature k; alphas via wave-uniform LDS broadcast; unroll 4
    float acc0 = 0.f, acc1 = 0.f, acc2 = 0.f, acc3 = 0.f;
    {
        const float4* A = (const float4*)(alds + w * 256);
        const int* S = slds + w * 64;
        int dmain = deg < 64 ? deg : 64;
        int d4 = (dmain + 3) & ~3;
        for (int j = 0; j < d4; j += 4) {
            float4 a0 = A[j], a1 = A[j + 1], a2 = A[j + 2], a3 = A[j + 3];
            int s0 = S[j], s1 = S[j + 1], s2 = S[j + 2], s3 = S[j + 3];
            float v0 = hout[(size_t)s0 * 64 + lane];
            float v1 = hout[(size_t)s1 * 64 + lane];
            float v2 = hout[(size_t)s2 * 64 + lane];
            float v3 = hout[(size_t)s3 * 64 + lane];
            acc0 += a0.x * v0 + a1.x * v1 + a2.x * v2 + a3.x * v3;
            acc1 += a0.y * v0 + a1.y * v1 + a2.y * v2 + a3.y * v3;
            acc2 += a0.z * v0 + a1.z * v1 + a2.z * v2 + a3.z * v3;
            acc3 += a0.w * v0 + a1.w * v1 + a2.w * v2 + a3.w * v3;
        }
        for (int j = 64; j < deg; j++) {   // rare tail deg>64
            int s = csr[o0 + j];
            float4 ev = ((const float4*)es)[s];
            float al0 = __expf(lrelu(ev.x + edv.x) - m0) * i0;
            float al1 = __expf(lrelu(ev.y + edv.y) - m1) * i1;
            float al2 = __expf(lrelu(ev.z + edv.z) - m2) * i2;
            float al3 = __expf(lrelu(ev.w + edv.w) - m3) * i3;
            float v = hout[(size_t)s * 64 + lane];
            acc0 += al0 * v; acc1 += al1 * v; acc2 += al2 * v; acc3 += al3 * v;
        }
    }

    if (active) {
        size_t b = (size_t)wid * 256;
        agg[b + lane] = acc0;
        agg[b + 64 + lane] = acc1;
        agg[b + 128 + lane] = acc2;
        agg[b + 192 + lane] = acc3;
    }
}

// ======================= layer 2 output transform (W2 amortized over 32 nodes) =======================
#define NB2 32
__global__ void k_out2(const float* __restrict__ agg, const float* __restrict__ W2,
                       const float* __restrict__ b2, float* __restrict__ hout2, int N) {
    __shared__ float lds[NB2 * 256];
    int t = threadIdx.x;
    int base = blockIdx.x * NB2;
    const float4* src = (const float4*)(agg + (size_t)base * 256);
    int limit4 = (N - base < NB2 ? N - base : NB2) * 64;
    for (int i = t; i < NB2 * 64; i += 256) {
        float4 v = (i < limit4) ? src[i] : make_float4(0.f, 0.f, 0.f, 0.f);
        ((float4*)lds)[i] = v;
    }
    __syncthreads();
    int c = t & 63, slot = t >> 6;
    float bv = b2[c];
    float acc[NB2 / 4];
#pragma unroll
    for (int j = 0; j < NB2 / 4; j++) acc[j] = 0.f;
    for (int hk = 0; hk < 256; hk++) {
        int h = hk >> 6, k = hk & 63;
        float w = W2[k * 256 + h * 64 + c];
#pragma unroll
        for (int j = 0; j < NB2 / 4; j++) acc[j] += lds[(slot + j * 4) * 256 + hk] * w;
    }
#pragma unroll
    for (int j = 0; j < NB2 / 4; j++) {
        int n = base + slot + j * 4;
        if (n < N) {
            float r = 0.25f * acc[j] + bv;
            hout2[(size_t)n * 64 + c] = fmaxf(r, 0.f);
        }
    }
}

// ======================= global add pool =======================
__global__ void k_pool(const float* __restrict__ h2, const int* __restrict__ batch,
                       float* __restrict__ out, int N, int G) {
    int g = blockIdx.x;
    if (g >= G) return;
    int lo = 0, hi = N;
    while (lo < hi) { int mid = (lo + hi) >> 1; if (batch[mid] < g) lo = mid + 1; else hi = mid; }
    int start = lo;
    lo = start; hi = N;
    while (lo < hi) { int mid = (lo + hi) >> 1; if (batch[mid] < g + 1) lo = mid + 1; else hi = mid; }
    int end = lo;
    int t = threadIdx.x, c = t & 63, j = t >> 6;
    float p = 0.f;
    for (int n = start + j; n < end; n += 4) p += h2[(size_t)n * 64 + c];
    __shared__ float lds[256];
    lds[t] = p;
    __syncthreads();
    if (j == 0) out[g * 64 + c] = lds[c] + lds[64 + c] + lds[128 + c] + lds[192 + c];
}

extern "C" void kernel_launch(void* const* d_in, const int* in_sizes, int n_in,
                              void* d_out, int out_size, void* d_ws, size_t ws_size,
                              hipStream_t stream) {
    const float* x   = (const float*)d_in[0];
    const int*   ei  = (const int*)d_in[1];
    const int*   bat = (const int*)d_in[2];
    const float* W1  = (const float*)d_in[3];
    const float* as1 = (const float*)d_in[4];
    const float* ad1 = (const float*)d_in[5];
    const float* b1  = (const float*)d_in[6];
    const float* W2  = (const float*)d_in[7];
    const float* as2 = (const float*)d_in[8];
    const float* ad2 = (const float*)d_in[9];
    const float* b2  = (const float*)d_in[10];
    float* out = (float*)d_out;

    int N = in_sizes[0] / 3;
    int E = in_sizes[1] / 2;
    int G = out_size / 64;
    const int* srcI = ei;
    const int* dstI = ei + E;

    // ---- workspace layout ----
    float* fw = (float*)d_ws;
    size_t fo = 0;
    float* agg   = fw + fo; fo += (size_t)N * 256;
    float* hout  = fw + fo; fo += (size_t)N * 64;
    float* hout2 = fw + fo; fo += (size_t)N * 64;
    float* esA   = fw + fo; fo += (size_t)N * 4;
    float* edA   = fw + fo; fo += (size_t)N * 4;
    float* esB   = fw + fo; fo += (size_t)N * 4;
    float* edB   = fw + fo; fo += (size_t)N * 4;
    float* p1s   = fw + fo; fo += 64;
    float* p1d   = fw + fo; fo += 64;
    float* qs    = fw + fo; fo += 256;
    float* qd    = fw + fo; fo += 256;
    int* iw = (int*)(fw + fo);
    size_t io = 0;
    int* deg    = iw + io; io += N;
    int* cursor = iw + io; io += N;
    int* off    = iw + io; io += N + 64;
    int* part   = iw + io; io += 512;
    int* csr    = iw + io; io += E;

    int nThrBlk = (N + 255) / 256;
    int eThrBlk = (E + 255) / 256;
    int nWaveBlk = (N + 3) / 4;
    int nch = (N + 255) / 256;

    // ---- CSR build (dst-sorted) ----
    k_zero<<<nThrBlk, 256, 0, stream>>>(deg, N);
    k_hist<<<eThrBlk, 256, 0, stream>>>(dstI, deg, E);
    k_scan1<<<nch, 256, 0, stream>>>(deg, part, N);
    k_scan2<<<1, 512, 0, stream>>>(part, nch, off, N);
    k_scan3<<<nch, 256, 0, stream>>>(deg, part, off, cursor, N);
    k_fill<<<eThrBlk, 256, 0, stream>>>(srcI, dstI, cursor, csr, E);

    // ---- precompute attention projections (both layers) ----
    k_prep<<<(3 * 8 * 64 + 255) / 256, 256, 0, stream>>>(W1, as1, ad1, p1s, p1d, 3);
    k_prep<<<(64 * 8 * 64 + 255) / 256, 256, 0, stream>>>(W2, as2, ad2, qs, qd, 64);

    // ---- layer 1 (writes hout + layer-2 es/ed) ----
    k_esed1<<<nThrBlk, 256, 0, stream>>>(x, p1s, p1d, esA, edA, N);
    k_agg1<<<nWaveBlk, 256, 0, stream>>>(off, csr, esA, edA, x, W1, b1, qs, qd,
                                         hout, esB, edB, N);

    // ---- layer 2 ----
    k_agg2<<<nWaveBlk, 256, 0, stream>>>(off, csr, esB, edB, hout, agg, N);
    k_out2<<<(N + NB2 - 1) / NB2, 256, 0, stream>>>(agg, W2, b2, hout2, N);

    // ---- pool ----
    k_pool<<<G, 256, 0, stream>>>(hout2, bat, out, N, G);
}

// Round 5
// 582.238 us; speedup vs baseline: 3.9904x; 1.2449x over previous
//
#include <hip/hip_runtime.h>
#include <math.h>

#define HEADS 4
#define HID 64

__device__ __forceinline__ float lrelu(float x) { return x > 0.f ? x : 0.2f * x; }

__device__ __forceinline__ float wred_sum(float v) {
#pragma unroll
    for (int o = 32; o > 0; o >>= 1) v += __shfl_xor(v, o);
    return v;
}
// 16-lane group reductions (xor offsets stay inside the group)
__device__ __forceinline__ float red16_sum(float v) {
#pragma unroll
    for (int o = 8; o > 0; o >>= 1) v += __shfl_xor(v, o);
    return v;
}
__device__ __forceinline__ float red16_max(float v) {
#pragma unroll
    for (int o = 8; o > 0; o >>= 1) v = fmaxf(v, __shfl_xor(v, o));
    return v;
}

// ======================= CSR build (dst-sorted) =======================
__global__ void k_zero(int* __restrict__ deg, int N) {
    int i = blockIdx.x * blockDim.x + threadIdx.x;
    if (i < N) deg[i] = 0;
}

__global__ void k_hist(const int* __restrict__ dstI, int* __restrict__ deg, int E) {
    int e = blockIdx.x * blockDim.x + threadIdx.x;
    if (e < E) atomicAdd(&deg[dstI[e]], 1);
}

__global__ void k_scan1(const int* __restrict__ deg, int* __restrict__ part, int N) {
    __shared__ int lds[256];
    int i = blockIdx.x * 256 + threadIdx.x;
    lds[threadIdx.x] = (i < N) ? deg[i] : 0;
    __syncthreads();
    for (int s = 128; s > 0; s >>= 1) {
        if (threadIdx.x < s) lds[threadIdx.x] += lds[threadIdx.x + s];
        __syncthreads();
    }
    if (threadIdx.x == 0) part[blockIdx.x] = lds[0];
}

__global__ void k_scan2(int* __restrict__ part, int nch, int* __restrict__ off, int N) {
    __shared__ int lds[512];
    int t = threadIdx.x;
    int orig = (t < nch) ? part[t] : 0;
    lds[t] = orig;
    __syncthreads();
    for (int s = 1; s < 512; s <<= 1) {
        int v = (t >= s) ? lds[t - s] : 0;
        __syncthreads();
        lds[t] += v;
        __syncthreads();
    }
    if (t < nch) part[t] = lds[t] - orig;
    if (t == 511) off[N] = lds[511];
}

__global__ void k_scan3(const int* __restrict__ deg, const int* __restrict__ part,
                        int* __restrict__ off, int* __restrict__ cursor, int N) {
    __shared__ int lds[256];
    int i = blockIdx.x * 256 + threadIdx.x;
    int d = (i < N) ? deg[i] : 0;
    lds[threadIdx.x] = d;
    __syncthreads();
    for (int s = 1; s < 256; s <<= 1) {
        int v = (threadIdx.x >= s) ? lds[threadIdx.x - s] : 0;
        __syncthreads();
        lds[threadIdx.x] += v;
        __syncthreads();
    }
    if (i < N) {
        int o = part[blockIdx.x] + lds[threadIdx.x] - d;
        off[i] = o;
        cursor[i] = o;
    }
}

__global__ void k_fill(const int* __restrict__ srcI, const int* __restrict__ dstI,
                       int* __restrict__ cursor, int* __restrict__ csr, int E) {
    int e = blockIdx.x * blockDim.x + threadIdx.x;
    if (e >= E) return;
    int d = dstI[e];
    int pos = atomicAdd(&cursor[d], 1);
    csr[pos] = srcI[e];
}

// ======================= attention-coefficient precompute =======================
__global__ void k_prep(const float* __restrict__ W, const float* __restrict__ asrc,
                       const float* __restrict__ adst, float* __restrict__ p_src,
                       float* __restrict__ p_dst, int K) {
    int wid = (blockIdx.x * blockDim.x + threadIdx.x) >> 6;
    int lane = threadIdx.x & 63;
    int total = K * 4 * 2;
    if (wid >= total) return;
    int which = wid / (K * 4);
    int hk = wid % (K * 4);
    int h = hk / K, k = hk % K;
    const float* a = which ? adst : asrc;
    float v = W[(size_t)k * 256 + h * 64 + lane] * a[h * 64 + lane];
    v = wred_sum(v);
    if (lane == 0) (which ? p_dst : p_src)[h * K + k] = v;
}

// es[n,h] = sum_k x[n,k] * ps[h*3+k]  (layer 1)
__global__ void k_esed1(const float* __restrict__ x, const float* __restrict__ ps,
                        const float* __restrict__ pd, float* __restrict__ es,
                        float* __restrict__ ed, int N) {
    int n = blockIdx.x * blockDim.x + threadIdx.x;
    if (n >= N) return;
    float x0 = x[n * 3], x1 = x[n * 3 + 1], x2 = x[n * 3 + 2];
    float4 s, d;
    s.x = x0 * ps[0] + x1 * ps[1] + x2 * ps[2];
    s.y = x0 * ps[3] + x1 * ps[4] + x2 * ps[5];
    s.z = x0 * ps[6] + x1 * ps[7] + x2 * ps[8];
    s.w = x0 * ps[9] + x1 * ps[10] + x2 * ps[11];
    d.x = x0 * pd[0] + x1 * pd[1] + x2 * pd[2];
    d.y = x0 * pd[3] + x1 * pd[4] + x2 * pd[5];
    d.z = x0 * pd[6] + x1 * pd[7] + x2 * pd[8];
    d.w = x0 * pd[9] + x1 * pd[10] + x2 * pd[11];
    ((float4*)es)[n] = s;
    ((float4*)ed)[n] = d;
}

// ======================= layer 1: 16-lane group per node =======================
// group (16 lanes) per dst node: softmax + 3-feature aggregation in registers,
// epilogue lane = 4 output channels (float4), fused layer-2 es/ed.
__global__ void k_agg1(const int* __restrict__ off, const int* __restrict__ csr,
                       const float* __restrict__ es, const float* __restrict__ ed,
                       const float* __restrict__ x, const float* __restrict__ W1,
                       const float* __restrict__ b1, const float* __restrict__ qs,
                       const float* __restrict__ qd, float* __restrict__ hout,
                       float* __restrict__ es2, float* __restrict__ ed2, int N) {
    int grp = (blockIdx.x * blockDim.x + threadIdx.x) >> 4;   // global group id = node
    int l = threadIdx.x & 15;
    int wid = grp;
    bool active = wid < N;
    int o0 = 0, deg = 0;
    float4 edv = make_float4(0.f, 0.f, 0.f, 0.f);
    if (active) {
        o0 = off[wid];
        deg = off[wid + 1] - o0;
        edv = ((const float4*)ed)[wid];
    }

    // pass 1: per-head max (cache first 16 edges)
    float m0 = -INFINITY, m1 = -INFINITY, m2 = -INFINITY, m3 = -INFINITY;
    int s_cache = 0;
    float c0 = 0.f, c1 = 0.f, c2 = 0.f, c3 = 0.f;
    for (int j = l; j < deg; j += 16) {
        int s = csr[o0 + j];
        float4 ev = ((const float4*)es)[s];
        float e0 = lrelu(ev.x + edv.x), e1 = lrelu(ev.y + edv.y);
        float e2 = lrelu(ev.z + edv.z), e3 = lrelu(ev.w + edv.w);
        if (j < 16) { s_cache = s; c0 = e0; c1 = e1; c2 = e2; c3 = e3; }
        m0 = fmaxf(m0, e0); m1 = fmaxf(m1, e1);
        m2 = fmaxf(m2, e2); m3 = fmaxf(m3, e3);
    }
    m0 = red16_max(m0); m1 = red16_max(m1); m2 = red16_max(m2); m3 = red16_max(m3);

    // pass 2: sum of exp (cache becomes exp)
    float t0 = 0.f, t1 = 0.f, t2 = 0.f, t3 = 0.f;
    for (int j = l; j < deg; j += 16) {
        float e0, e1, e2, e3;
        if (j < 16) { e0 = c0; e1 = c1; e2 = c2; e3 = c3; }
        else {
            int s = csr[o0 + j];
            float4 ev = ((const float4*)es)[s];
            e0 = lrelu(ev.x + edv.x); e1 = lrelu(ev.y + edv.y);
            e2 = lrelu(ev.z + edv.z); e3 = lrelu(ev.w + edv.w);
        }
        e0 = __expf(e0 - m0); e1 = __expf(e1 - m1);
        e2 = __expf(e2 - m2); e3 = __expf(e3 - m3);
        if (j < 16) { c0 = e0; c1 = e1; c2 = e2; c3 = e3; }
        t0 += e0; t1 += e1; t2 += e2; t3 += e3;
    }
    t0 = red16_sum(t0); t1 = red16_sum(t1); t2 = red16_sum(t2); t3 = red16_sum(t3);
    float i0 = t0 > 0.f ? 1.f / t0 : 0.f;
    float i1 = t1 > 0.f ? 1.f / t1 : 0.f;
    float i2 = t2 > 0.f ? 1.f / t2 : 0.f;
    float i3 = t3 > 0.f ? 1.f / t3 : 0.f;

    // pass 3: agg3[h][k] = sum_e alpha_eh * x[src,k]
    float a00 = 0, a01 = 0, a02 = 0, a10 = 0, a11 = 0, a12 = 0;
    float a20 = 0, a21 = 0, a22 = 0, a30 = 0, a31 = 0, a32 = 0;
    for (int j = l; j < deg; j += 16) {
        float e0, e1, e2, e3; int s;
        if (j < 16) { s = s_cache; e0 = c0; e1 = c1; e2 = c2; e3 = c3; }
        else {
            s = csr[o0 + j];
            float4 ev = ((const float4*)es)[s];
            e0 = __expf(lrelu(ev.x + edv.x) - m0);
            e1 = __expf(lrelu(ev.y + edv.y) - m1);
            e2 = __expf(lrelu(ev.z + edv.z) - m2);
            e3 = __expf(lrelu(ev.w + edv.w) - m3);
        }
        float xv0 = x[s * 3], xv1 = x[s * 3 + 1], xv2 = x[s * 3 + 2];
        a00 += e0 * xv0; a01 += e0 * xv1; a02 += e0 * xv2;
        a10 += e1 * xv0; a11 += e1 * xv1; a12 += e1 * xv2;
        a20 += e2 * xv0; a21 += e2 * xv1; a22 += e2 * xv2;
        a30 += e3 * xv0; a31 += e3 * xv1; a32 += e3 * xv2;
    }
    a00 = red16_sum(a00) * i0; a01 = red16_sum(a01) * i0; a02 = red16_sum(a02) * i0;
    a10 = red16_sum(a10) * i1; a11 = red16_sum(a11) * i1; a12 = red16_sum(a12) * i1;
    a20 = red16_sum(a20) * i2; a21 = red16_sum(a21) * i2; a22 = red16_sum(a22) * i2;
    a30 = red16_sum(a30) * i3; a31 = red16_sum(a31) * i3; a32 = red16_sum(a32) * i3;

    if (!active) return;

    // epilogue: lane handles channels c = l*4 .. l*4+3
    const float4* W1f = (const float4*)W1;   // W1f[k*64 + h*16 + l] = W1[k*256+h*64+l*4 ..]
    float4 r = make_float4(0.f, 0.f, 0.f, 0.f);
    float ah[4][3] = {{a00, a01, a02}, {a10, a11, a12}, {a20, a21, a22}, {a30, a31, a32}};
#pragma unroll
    for (int k = 0; k < 3; k++) {
#pragma unroll
        for (int h = 0; h < 4; h++) {
            float4 wv = W1f[k * 64 + h * 16 + l];
            float a = ah[h][k];
            r.x += a * wv.x; r.y += a * wv.y; r.z += a * wv.z; r.w += a * wv.w;
        }
    }
    float4 bv = ((const float4*)b1)[l];
    float4 hv;
    hv.x = fmaxf(0.25f * r.x + bv.x, 0.f);
    hv.y = fmaxf(0.25f * r.y + bv.y, 0.f);
    hv.z = fmaxf(0.25f * r.z + bv.z, 0.f);
    hv.w = fmaxf(0.25f * r.w + bv.w, 0.f);
    ((float4*)hout)[(size_t)wid * 16 + l] = hv;

    // fused layer-2 es/ed: dot(h, qs[h*64 + ...]) per head
    const float4* qsf = (const float4*)qs;
    const float4* qdf = (const float4*)qd;
    float ps[4], pd[4];
#pragma unroll
    for (int h = 0; h < 4; h++) {
        float4 q = qsf[h * 16 + l];
        ps[h] = red16_sum(hv.x * q.x + hv.y * q.y + hv.z * q.z + hv.w * q.w);
        float4 p = qdf[h * 16 + l];
        pd[h] = red16_sum(hv.x * p.x + hv.y * p.y + hv.z * p.z + hv.w * p.w);
    }
    if (l == 0) {
        ((float4*)es2)[wid] = make_float4(ps[0], ps[1], ps[2], ps[3]);
        ((float4*)ed2)[wid] = make_float4(pd[0], pd[1], pd[2], pd[3]);
    }
}

// ======================= layer 2: phase-A 16-lane softmax -> LDS, phase-B wave gather =======================
#define NS 16   // node slots per 256-thread block
__global__ void k_agg2(const int* __restrict__ off, const int* __restrict__ csr,
                       const float* __restrict__ es, const float* __restrict__ ed,
                       const float* __restrict__ hout, float* __restrict__ agg, int N) {
    __shared__ float exl[NS * 64 * 4];   // raw exp per edge slot (float4/edge), 16 KB
    __shared__ int   sl[NS * 64];        // src indices, 4 KB
    __shared__ float minv[NS * 8];       // m0..3, inv0..3
    __shared__ int   meta[NS * 2];       // o0, deg

    // zero-fill staging
    for (int i = threadIdx.x; i < NS * 64; i += 256) {
        ((float4*)exl)[i] = make_float4(0.f, 0.f, 0.f, 0.f);
        sl[i] = 0;
    }
    __syncthreads();

    int l = threadIdx.x & 15;
    int slot = threadIdx.x >> 4;          // 0..15
    int wid = blockIdx.x * NS + slot;
    bool active = wid < N;
    int o0 = 0, deg = 0;
    float4 edv = make_float4(0.f, 0.f, 0.f, 0.f);
    if (active) {
        o0 = off[wid];
        deg = off[wid + 1] - o0;
        edv = ((const float4*)ed)[wid];
    }

    // pass 1: per-head max (cache first 16)
    float m0 = -INFINITY, m1 = -INFINITY, m2 = -INFINITY, m3 = -INFINITY;
    int s_cache = 0;
    float c0 = 0.f, c1 = 0.f, c2 = 0.f, c3 = 0.f;
    for (int j = l; j < deg; j += 16) {
        int s = csr[o0 + j];
        float4 ev = ((const float4*)es)[s];
        float e0 = lrelu(ev.x + edv.x), e1 = lrelu(ev.y + edv.y);
        float e2 = lrelu(ev.z + edv.z), e3 = lrelu(ev.w + edv.w);
        if (j < 16) { s_cache = s; c0 = e0; c1 = e1; c2 = e2; c3 = e3; }
        m0 = fmaxf(m0, e0); m1 = fmaxf(m1, e1);
        m2 = fmaxf(m2, e2); m3 = fmaxf(m3, e3);
    }
    m0 = red16_max(m0); m1 = red16_max(m1); m2 = red16_max(m2); m3 = red16_max(m3);

    // pass 2: exp -> LDS (first 64 edges), accumulate sums
    float t0 = 0.f, t1 = 0.f, t2 = 0.f, t3 = 0.f;
    for (int j = l; j < deg; j += 16) {
        float e0, e1, e2, e3; int s;
        if (j < 16) { s = s_cache; e0 = c0; e1 = c1; e2 = c2; e3 = c3; }
        else {
            s = csr[o0 + j];
            float4 ev = ((const float4*)es)[s];
            e0 = lrelu(ev.x + edv.x); e1 = lrelu(ev.y + edv.y);
            e2 = lrelu(ev.z + edv.z); e3 = lrelu(ev.w + edv.w);
        }
        e0 = __expf(e0 - m0); e1 = __expf(e1 - m1);
        e2 = __expf(e2 - m2); e3 = __expf(e3 - m3);
        if (j < 64) {
            ((float4*)exl)[slot * 64 + j] = make_float4(e0, e1, e2, e3);
            sl[slot * 64 + j] = s;
        }
        t0 += e0; t1 += e1; t2 += e2; t3 += e3;
    }
    t0 = red16_sum(t0); t1 = red16_sum(t1); t2 = red16_sum(t2); t3 = red16_sum(t3);
    if (l == 0) {
        minv[slot * 8 + 0] = m0; minv[slot * 8 + 1] = m1;
        minv[slot * 8 + 2] = m2; minv[slot * 8 + 3] = m3;
        minv[slot * 8 + 4] = t0 > 0.f ? 1.f / t0 : 0.f;
        minv[slot * 8 + 5] = t1 > 0.f ? 1.f / t1 : 0.f;
        minv[slot * 8 + 6] = t2 > 0.f ? 1.f / t2 : 0.f;
        minv[slot * 8 + 7] = t3 > 0.f ? 1.f / t3 : 0.f;
        meta[slot * 2 + 0] = o0;
        meta[slot * 2 + 1] = deg;
    }
    __syncthreads();

    // phase B: wave per node slot (4 slots per wave), lane = feature
    int lane = threadIdx.x & 63;
    int w = threadIdx.x >> 6;
    for (int sidx = 0; sidx < 4; sidx++) {
        int slot2 = w * 4 + sidx;
        int nd = blockIdx.x * NS + slot2;
        if (nd >= N) continue;
        int o0b = meta[slot2 * 2 + 0], degb = meta[slot2 * 2 + 1];
        float mm0 = minv[slot2 * 8 + 0], mm1 = minv[slot2 * 8 + 1];
        float mm2 = minv[slot2 * 8 + 2], mm3 = minv[slot2 * 8 + 3];
        float iv0 = minv[slot2 * 8 + 4], iv1 = minv[slot2 * 8 + 5];
        float iv2 = minv[slot2 * 8 + 6], iv3 = minv[slot2 * 8 + 7];

        float acc0 = 0.f, acc1 = 0.f, acc2 = 0.f, acc3 = 0.f;
        const float4* EX = ((const float4*)exl) + slot2 * 64;
        const int* S = sl + slot2 * 64;
        int dmain = degb < 64 ? degb : 64;
        int d4 = (dmain + 3) & ~3;
        for (int j = 0; j < d4; j += 4) {
            float4 a0 = EX[j], a1 = EX[j + 1], a2 = EX[j + 2], a3 = EX[j + 3];
            int s0 = S[j], s1 = S[j + 1], s2 = S[j + 2], s3 = S[j + 3];
            float v0 = hout[(size_t)s0 * 64 + lane];
            float v1 = hout[(size_t)s1 * 64 + lane];
            float v2 = hout[(size_t)s2 * 64 + lane];
            float v3 = hout[(size_t)s3 * 64 + lane];
            acc0 += a0.x * v0 + a1.x * v1 + a2.x * v2 + a3.x * v3;
            acc1 += a0.y * v0 + a1.y * v1 + a2.y * v2 + a3.y * v3;
            acc2 += a0.z * v0 + a1.z * v1 + a2.z * v2 + a3.z * v3;
            acc3 += a0.w * v0 + a1.w * v1 + a2.w * v2 + a3.w * v3;
        }
        if (degb > 64) {
            float4 edv2 = ((const float4*)ed)[nd];
            for (int j = 64; j < degb; j++) {
                int s = csr[o0b + j];
                float4 ev = ((const float4*)es)[s];
                float e0 = __expf(lrelu(ev.x + edv2.x) - mm0);
                float e1 = __expf(lrelu(ev.y + edv2.y) - mm1);
                float e2 = __expf(lrelu(ev.z + edv2.z) - mm2);
                float e3 = __expf(lrelu(ev.w + edv2.w) - mm3);
                float v = hout[(size_t)s * 64 + lane];
                acc0 += e0 * v; acc1 += e1 * v; acc2 += e2 * v; acc3 += e3 * v;
            }
        }
        size_t b = (size_t)nd * 256;
        agg[b + lane] = acc0 * iv0;
        agg[b + 64 + lane] = acc1 * iv1;
        agg[b + 128 + lane] = acc2 * iv2;
        agg[b + 192 + lane] = acc3 * iv3;
    }
}

// ======================= layer 2 output transform (W2 amortized over 32 nodes) =======================
#define NB2 32
__global__ void k_out2(const float* __restrict__ agg, const float* __restrict__ W2,
                       const float* __restrict__ b2, float* __restrict__ hout2, int N) {
    __shared__ float lds[NB2 * 256];
    int t = threadIdx.x;
    int base = blockIdx.x * NB2;
    const float4* src = (const float4*)(agg + (size_t)base * 256);
    int limit4 = (N - base < NB2 ? N - base : NB2) * 64;
    for (int i = t; i < NB2 * 64; i += 256) {
        float4 v = (i < limit4) ? src[i] : make_float4(0.f, 0.f, 0.f, 0.f);
        ((float4*)lds)[i] = v;
    }
    __syncthreads();
    int c = t & 63, slot = t >> 6;
    float bv = b2[c];
    float acc[NB2 / 4];
#pragma unroll
    for (int j = 0; j < NB2 / 4; j++) acc[j] = 0.f;
    for (int hk = 0; hk < 256; hk++) {
        int h = hk >> 6, k = hk & 63;
        float w = W2[k * 256 + h * 64 + c];
#pragma unroll
        for (int j = 0; j < NB2 / 4; j++) acc[j] += lds[(slot + j * 4) * 256 + hk] * w;
    }
#pragma unroll
    for (int j = 0; j < NB2 / 4; j++) {
        int n = base + slot + j * 4;
        if (n < N) {
            float r = 0.25f * acc[j] + bv;
            hout2[(size_t)n * 64 + c] = fmaxf(r, 0.f);
        }
    }
}

// ======================= global add pool =======================
__global__ void k_pool(const float* __restrict__ h2, const int* __restrict__ batch,
                       float* __restrict__ out, int N, int G) {
    int g = blockIdx.x;
    if (g >= G) return;
    int lo = 0, hi = N;
    while (lo < hi) { int mid = (lo + hi) >> 1; if (batch[mid] < g) lo = mid + 1; else hi = mid; }
    int start = lo;
    lo = start; hi = N;
    while (lo < hi) { int mid = (lo + hi) >> 1; if (batch[mid] < g + 1) lo = mid + 1; else hi = mid; }
    int end = lo;
    int t = threadIdx.x, c = t & 63, j = t >> 6;
    float p = 0.f;
    for (int n = start + j; n < end; n += 4) p += h2[(size_t)n * 64 + c];
    __shared__ float lds[256];
    lds[t] = p;
    __syncthreads();
    if (j == 0) out[g * 64 + c] = lds[c] + lds[64 + c] + lds[128 + c] + lds[192 + c];
}

extern "C" void kernel_launch(void* const* d_in, const int* in_sizes, int n_in,
                              void* d_out, int out_size, void* d_ws, size_t ws_size,
                              hipStream_t stream) {
    const float* x   = (const float*)d_in[0];
    const int*   ei  = (const int*)d_in[1];
    const int*   bat = (const int*)d_in[2];
    const float* W1  = (const float*)d_in[3];
    const float* as1 = (const float*)d_in[4];
    const float* ad1 = (const float*)d_in[5];
    const float* b1  = (const float*)d_in[6];
    const float* W2  = (const float*)d_in[7];
    const float* as2 = (const float*)d_in[8];
    const float* ad2 = (const float*)d_in[9];
    const float* b2  = (const float*)d_in[10];
    float* out = (float*)d_out;

    int N = in_sizes[0] / 3;
    int E = in_sizes[1] / 2;
    int G = out_size / 64;
    const int* srcI = ei;
    const int* dstI = ei + E;

    // ---- workspace layout ----
    float* fw = (float*)d_ws;
    size_t fo = 0;
    float* agg   = fw + fo; fo += (size_t)N * 256;
    float* hout  = fw + fo; fo += (size_t)N * 64;
    float* hout2 = fw + fo; fo += (size_t)N * 64;
    float* esA   = fw + fo; fo += (size_t)N * 4;
    float* edA   = fw + fo; fo += (size_t)N * 4;
    float* esB   = fw + fo; fo += (size_t)N * 4;
    float* edB   = fw + fo; fo += (size_t)N * 4;
    float* p1s   = fw + fo; fo += 64;
    float* p1d   = fw + fo; fo += 64;
    float* qs    = fw + fo; fo += 256;
    float* qd    = fw + fo; fo += 256;
    int* iw = (int*)(fw + fo);
    size_t io = 0;
    int* deg    = iw + io; io += N;
    int* cursor = iw + io; io += N;
    int* off    = iw + io; io += N + 64;
    int* part   = iw + io; io += 512;
    int* csr    = iw + io; io += E;

    int nThrBlk = (N + 255) / 256;
    int eThrBlk = (E + 255) / 256;
    int nGrpBlk = (N + 15) / 16;    // 16-lane group per node, 16 nodes/block
    int nch = (N + 255) / 256;

    // ---- CSR build (dst-sorted) ----
    k_zero<<<nThrBlk, 256, 0, stream>>>(deg, N);
    k_hist<<<eThrBlk, 256, 0, stream>>>(dstI, deg, E);
    k_scan1<<<nch, 256, 0, stream>>>(deg, part, N);
    k_scan2<<<1, 512, 0, stream>>>(part, nch, off, N);
    k_scan3<<<nch, 256, 0, stream>>>(deg, part, off, cursor, N);
    k_fill<<<eThrBlk, 256, 0, stream>>>(srcI, dstI, cursor, csr, E);

    // ---- precompute attention projections (both layers) ----
    k_prep<<<(3 * 8 * 64 + 255) / 256, 256, 0, stream>>>(W1, as1, ad1, p1s, p1d, 3);
    k_prep<<<(64 * 8 * 64 + 255) / 256, 256, 0, stream>>>(W2, as2, ad2, qs, qd, 64);

    // ---- layer 1 (writes hout + layer-2 es/ed) ----
    k_esed1<<<nThrBlk, 256, 0, stream>>>(x, p1s, p1d, esA, edA, N);
    k_agg1<<<nGrpBlk, 256, 0, stream>>>(off, csr, esA, edA, x, W1, b1, qs, qd,
                                        hout, esB, edB, N);

    // ---- layer 2 ----
    k_agg2<<<nGrpBlk, 256, 0, stream>>>(off, csr, esB, edB, hout, agg, N);
    k_out2<<<(N + NB2 - 1) / NB2, 256, 0, stream>>>(agg, W2, b2, hout2, N);

    // ---- pool ----
    k_pool<<<G, 256, 0, stream>>>(hout2, bat, out, N, G);
}

// Round 6
// 473.430 us; speedup vs baseline: 4.9076x; 1.2298x over previous
//
#include <hip/hip_runtime.h>
#include <math.h>

#define HEADS 4
#define HID 64
#define BSHIFT 7          // 128 nodes per bucket
#define BWIDTH 128
#define CCAP 4096         // LDS csr-staging capacity (edges/bucket mean ~2047)
#define DCHUNK 2048       // edges per k_bdist block (8 per thread)

__device__ __forceinline__ float lrelu(float x) { return x > 0.f ? x : 0.2f * x; }

__device__ __forceinline__ float wred_sum(float v) {
#pragma unroll
    for (int o = 32; o > 0; o >>= 1) v += __shfl_xor(v, o);
    return v;
}
__device__ __forceinline__ float red16_sum(float v) {
#pragma unroll
    for (int o = 8; o > 0; o >>= 1) v += __shfl_xor(v, o);
    return v;
}
__device__ __forceinline__ float red16_max(float v) {
#pragma unroll
    for (int o = 8; o > 0; o >>= 1) v = fmaxf(v, __shfl_xor(v, o));
    return v;
}

// ======================= CSR build: two-level LDS counting sort =======================
__global__ void k_binit(int* __restrict__ bcnt, int NBUCK) {
    int i = threadIdx.x;
    if (i < NBUCK) bcnt[i] = 0;
}

__global__ void k_bhist(const int* __restrict__ dstI, int* __restrict__ bcnt,
                        int E, int NBUCK) {
    __shared__ int h[1024];
    for (int i = threadIdx.x; i < NBUCK; i += 256) h[i] = 0;
    __syncthreads();
    int stride = gridDim.x * 256;
    for (int e = blockIdx.x * 256 + threadIdx.x; e < E; e += stride)
        atomicAdd(&h[dstI[e] >> BSHIFT], 1);
    __syncthreads();
    for (int i = threadIdx.x; i < NBUCK; i += 256)
        if (h[i]) atomicAdd(&bcnt[i], h[i]);
}

// single block, 1024 threads: exclusive scan of bucket counts
__global__ void k_bscan(const int* __restrict__ bcnt, int* __restrict__ bbase,
                        int* __restrict__ gcur, int* __restrict__ off,
                        int NBUCK, int N, int E) {
    __shared__ int lds[1024];
    int t = threadIdx.x;
    int v = (t < NBUCK) ? bcnt[t] : 0;
    lds[t] = v;
    __syncthreads();
    for (int s = 1; s < 1024; s <<= 1) {
        int u = (t >= s) ? lds[t - s] : 0;
        __syncthreads();
        lds[t] += u;
        __syncthreads();
    }
    if (t < NBUCK) {
        int b = lds[t] - v;
        bbase[t] = b;
        gcur[t] = b;
    }
    if (t == 0) { bbase[NBUCK] = E; off[N] = E; }
}

// distribute edges into bucket regions as (src,dst) pairs
__global__ void k_bdist(const int* __restrict__ srcI, const int* __restrict__ dstI,
                        int* __restrict__ gcur, uint2* __restrict__ pairs,
                        int E, int NBUCK) {
    __shared__ int h[1024];
    __shared__ int cur[1024];
    for (int i = threadIdx.x; i < NBUCK; i += 256) h[i] = 0;
    __syncthreads();
    int base = blockIdx.x * DCHUNK;
    int sr[8], dr[8];
#pragma unroll
    for (int k = 0; k < 8; k++) {
        int e = base + threadIdx.x + k * 256;
        if (e < E) {
            sr[k] = srcI[e];
            dr[k] = dstI[e];
            atomicAdd(&h[dr[k] >> BSHIFT], 1);
        } else dr[k] = -1;
    }
    __syncthreads();
    for (int i = threadIdx.x; i < NBUCK; i += 256)
        cur[i] = h[i] ? atomicAdd(&gcur[i], h[i]) : 0;
    __syncthreads();
#pragma unroll
    for (int k = 0; k < 8; k++) {
        if (dr[k] >= 0) {
            int b = dr[k] >> BSHIFT;
            int p = atomicAdd(&cur[b], 1);
            pairs[p] = make_uint2((unsigned)sr[k], (unsigned)dr[k]);
        }
    }
}

// one block per bucket: local degrees -> off[], LDS-cursor distribute -> coalesced csr
__global__ void k_bcsr(const uint2* __restrict__ pairs, const int* __restrict__ bbase,
                       int* __restrict__ off, int* __restrict__ csr, int N) {
    __shared__ int cnt[BWIDTH];
    __shared__ int scan[BWIDTH];
    __shared__ int cur[BWIDTH];
    __shared__ int stage[CCAP];
    int b = blockIdx.x;
    int nodeBase = b << BSHIFT;
    int nNodes = N - nodeBase;
    if (nNodes > BWIDTH) nNodes = BWIDTH;
    int e0 = bbase[b], e1 = bbase[b + 1];
    int ecnt = e1 - e0;
    if (threadIdx.x < BWIDTH) cnt[threadIdx.x] = 0;
    __syncthreads();
    for (int i = threadIdx.x; i < ecnt; i += 256)
        atomicAdd(&cnt[pairs[e0 + i].y - (unsigned)nodeBase], 1);
    __syncthreads();
    if (threadIdx.x < BWIDTH)
        scan[threadIdx.x] = (threadIdx.x < nNodes) ? cnt[threadIdx.x] : 0;
    __syncthreads();
    for (int s = 1; s < BWIDTH; s <<= 1) {
        int u = 0;
        if (threadIdx.x < BWIDTH && threadIdx.x >= s) u = scan[threadIdx.x - s];
        __syncthreads();
        if (threadIdx.x < BWIDTH) scan[threadIdx.x] += u;
        __syncthreads();
    }
    if (threadIdx.x < nNodes) {
        int ex = scan[threadIdx.x] - cnt[threadIdx.x];   // exclusive
        off[nodeBase + threadIdx.x] = e0 + ex;
        cur[threadIdx.x] = ex;
    }
    __syncthreads();
    for (int i = threadIdx.x; i < ecnt; i += 256) {
        uint2 pr = pairs[e0 + i];
        int l = atomicAdd(&cur[pr.y - (unsigned)nodeBase], 1);
        if (l < CCAP) stage[l] = (int)pr.x;
        else csr[e0 + l] = (int)pr.x;   // overflow fallback (never for ~2K/bucket)
    }
    __syncthreads();
    int lim = ecnt < CCAP ? ecnt : CCAP;
    for (int i = threadIdx.x; i < lim; i += 256) csr[e0 + i] = stage[i];
}

// ======================= attention-coefficient precompute =======================
__global__ void k_prep(const float* __restrict__ W, const float* __restrict__ asrc,
                       const float* __restrict__ adst, float* __restrict__ p_src,
                       float* __restrict__ p_dst, int K) {
    int wid = (blockIdx.x * blockDim.x + threadIdx.x) >> 6;
    int lane = threadIdx.x & 63;
    int total = K * 4 * 2;
    if (wid >= total) return;
    int which = wid / (K * 4);
    int hk = wid % (K * 4);
    int h = hk / K, k = hk % K;
    const float* a = which ? adst : asrc;
    float v = W[(size_t)k * 256 + h * 64 + lane] * a[h * 64 + lane];
    v = wred_sum(v);
    if (lane == 0) (which ? p_dst : p_src)[h * K + k] = v;
}

// es[n,h] = sum_k x[n,k] * ps[h*3+k]  (layer 1)
__global__ void k_esed1(const float* __restrict__ x, const float* __restrict__ ps,
                        const float* __restrict__ pd, float* __restrict__ es,
                        float* __restrict__ ed, int N) {
    int n = blockIdx.x * blockDim.x + threadIdx.x;
    if (n >= N) return;
    float x0 = x[n * 3], x1 = x[n * 3 + 1], x2 = x[n * 3 + 2];
    float4 s, d;
    s.x = x0 * ps[0] + x1 * ps[1] + x2 * ps[2];
    s.y = x0 * ps[3] + x1 * ps[4] + x2 * ps[5];
    s.z = x0 * ps[6] + x1 * ps[7] + x2 * ps[8];
    s.w = x0 * ps[9] + x1 * ps[10] + x2 * ps[11];
    d.x = x0 * pd[0] + x1 * pd[1] + x2 * pd[2];
    d.y = x0 * pd[3] + x1 * pd[4] + x2 * pd[5];
    d.z = x0 * pd[6] + x1 * pd[7] + x2 * pd[8];
    d.w = x0 * pd[9] + x1 * pd[10] + x2 * pd[11];
    ((float4*)es)[n] = s;
    ((float4*)ed)[n] = d;
}

// ======================= layer 1: 16-lane group per node =======================
__global__ void k_agg1(const int* __restrict__ off, const int* __restrict__ csr,
                       const float* __restrict__ es, const float* __restrict__ ed,
                       const float* __restrict__ x, const float* __restrict__ W1,
                       const float* __restrict__ b1, const float* __restrict__ qs,
                       const float* __restrict__ qd, float* __restrict__ hout,
                       float* __restrict__ es2, float* __restrict__ ed2, int N) {
    int grp = (blockIdx.x * blockDim.x + threadIdx.x) >> 4;
    int l = threadIdx.x & 15;
    int wid = grp;
    bool active = wid < N;
    int o0 = 0, deg = 0;
    float4 edv = make_float4(0.f, 0.f, 0.f, 0.f);
    if (active) {
        o0 = off[wid];
        deg = off[wid + 1] - o0;
        edv = ((const float4*)ed)[wid];
    }

    float m0 = -INFINITY, m1 = -INFINITY, m2 = -INFINITY, m3 = -INFINITY;
    int s_cache = 0;
    float c0 = 0.f, c1 = 0.f, c2 = 0.f, c3 = 0.f;
    for (int j = l; j < deg; j += 16) {
        int s = csr[o0 + j];
        float4 ev = ((const float4*)es)[s];
        float e0 = lrelu(ev.x + edv.x), e1 = lrelu(ev.y + edv.y);
        float e2 = lrelu(ev.z + edv.z), e3 = lrelu(ev.w + edv.w);
        if (j < 16) { s_cache = s; c0 = e0; c1 = e1; c2 = e2; c3 = e3; }
        m0 = fmaxf(m0, e0); m1 = fmaxf(m1, e1);
        m2 = fmaxf(m2, e2); m3 = fmaxf(m3, e3);
    }
    m0 = red16_max(m0); m1 = red16_max(m1); m2 = red16_max(m2); m3 = red16_max(m3);

    float t0 = 0.f, t1 = 0.f, t2 = 0.f, t3 = 0.f;
    for (int j = l; j < deg; j += 16) {
        float e0, e1, e2, e3;
        if (j < 16) { e0 = c0; e1 = c1; e2 = c2; e3 = c3; }
        else {
            int s = csr[o0 + j];
            float4 ev = ((const float4*)es)[s];
            e0 = lrelu(ev.x + edv.x); e1 = lrelu(ev.y + edv.y);
            e2 = lrelu(ev.z + edv.z); e3 = lrelu(ev.w + edv.w);
        }
        e0 = __expf(e0 - m0); e1 = __expf(e1 - m1);
        e2 = __expf(e2 - m2); e3 = __expf(e3 - m3);
        if (j < 16) { c0 = e0; c1 = e1; c2 = e2; c3 = e3; }
        t0 += e0; t1 += e1; t2 += e2; t3 += e3;
    }
    t0 = red16_sum(t0); t1 = red16_sum(t1); t2 = red16_sum(t2); t3 = red16_sum(t3);
    float i0 = t0 > 0.f ? 1.f / t0 : 0.f;
    float i1 = t1 > 0.f ? 1.f / t1 : 0.f;
    float i2 = t2 > 0.f ? 1.f / t2 : 0.f;
    float i3 = t3 > 0.f ? 1.f / t3 : 0.f;

    float a00 = 0, a01 = 0, a02 = 0, a10 = 0, a11 = 0, a12 = 0;
    float a20 = 0, a21 = 0, a22 = 0, a30 = 0, a31 = 0, a32 = 0;
    for (int j = l; j < deg; j += 16) {
        float e0, e1, e2, e3; int s;
        if (j < 16) { s = s_cache; e0 = c0; e1 = c1; e2 = c2; e3 = c3; }
        else {
            s = csr[o0 + j];
            float4 ev = ((const float4*)es)[s];
            e0 = __expf(lrelu(ev.x + edv.x) - m0);
            e1 = __expf(lrelu(ev.y + edv.y) - m1);
            e2 = __expf(lrelu(ev.z + edv.z) - m2);
            e3 = __expf(lrelu(ev.w + edv.w) - m3);
        }
        float xv0 = x[s * 3], xv1 = x[s * 3 + 1], xv2 = x[s * 3 + 2];
        a00 += e0 * xv0; a01 += e0 * xv1; a02 += e0 * xv2;
        a10 += e1 * xv0; a11 += e1 * xv1; a12 += e1 * xv2;
        a20 += e2 * xv0; a21 += e2 * xv1; a22 += e2 * xv2;
        a30 += e3 * xv0; a31 += e3 * xv1; a32 += e3 * xv2;
    }
    a00 = red16_sum(a00) * i0; a01 = red16_sum(a01) * i0; a02 = red16_sum(a02) * i0;
    a10 = red16_sum(a10) * i1; a11 = red16_sum(a11) * i1; a12 = red16_sum(a12) * i1;
    a20 = red16_sum(a20) * i2; a21 = red16_sum(a21) * i2; a22 = red16_sum(a22) * i2;
    a30 = red16_sum(a30) * i3; a31 = red16_sum(a31) * i3; a32 = red16_sum(a32) * i3;

    if (!active) return;

    const float4* W1f = (const float4*)W1;
    float4 r = make_float4(0.f, 0.f, 0.f, 0.f);
    float ah[4][3] = {{a00, a01, a02}, {a10, a11, a12}, {a20, a21, a22}, {a30, a31, a32}};
#pragma unroll
    for (int k = 0; k < 3; k++) {
#pragma unroll
        for (int h = 0; h < 4; h++) {
            float4 wv = W1f[k * 64 + h * 16 + l];
            float a = ah[h][k];
            r.x += a * wv.x; r.y += a * wv.y; r.z += a * wv.z; r.w += a * wv.w;
        }
    }
    float4 bv = ((const float4*)b1)[l];
    float4 hv;
    hv.x = fmaxf(0.25f * r.x + bv.x, 0.f);
    hv.y = fmaxf(0.25f * r.y + bv.y, 0.f);
    hv.z = fmaxf(0.25f * r.z + bv.z, 0.f);
    hv.w = fmaxf(0.25f * r.w + bv.w, 0.f);
    ((float4*)hout)[(size_t)wid * 16 + l] = hv;

    const float4* qsf = (const float4*)qs;
    const float4* qdf = (const float4*)qd;
    float ps[4], pd[4];
#pragma unroll
    for (int h = 0; h < 4; h++) {
        float4 q = qsf[h * 16 + l];
        ps[h] = red16_sum(hv.x * q.x + hv.y * q.y + hv.z * q.z + hv.w * q.w);
        float4 p = qdf[h * 16 + l];
        pd[h] = red16_sum(hv.x * p.x + hv.y * p.y + hv.z * p.z + hv.w * p.w);
    }
    if (l == 0) {
        ((float4*)es2)[wid] = make_float4(ps[0], ps[1], ps[2], ps[3]);
        ((float4*)ed2)[wid] = make_float4(pd[0], pd[1], pd[2], pd[3]);
    }
}

// ======================= layer 2: phase-A 16-lane softmax -> LDS, phase-B wave gather =======================
#define NS 16
__global__ void k_agg2(const int* __restrict__ off, const int* __restrict__ csr,
                       const float* __restrict__ es, const float* __restrict__ ed,
                       const float* __restrict__ hout, float* __restrict__ agg, int N) {
    __shared__ float exl[NS * 64 * 4];
    __shared__ int   sl[NS * 64];
    __shared__ float minv[NS * 8];
    __shared__ int   meta[NS * 2];

    for (int i = threadIdx.x; i < NS * 64; i += 256) {
        ((float4*)exl)[i] = make_float4(0.f, 0.f, 0.f, 0.f);
        sl[i] = 0;
    }
    __syncthreads();

    int l = threadIdx.x & 15;
    int slot = threadIdx.x >> 4;
    int wid = blockIdx.x * NS + slot;
    bool active = wid < N;
    int o0 = 0, deg = 0;
    float4 edv = make_float4(0.f, 0.f, 0.f, 0.f);
    if (active) {
        o0 = off[wid];
        deg = off[wid + 1] - o0;
        edv = ((const float4*)ed)[wid];
    }

    float m0 = -INFINITY, m1 = -INFINITY, m2 = -INFINITY, m3 = -INFINITY;
    int s_cache = 0;
    float c0 = 0.f, c1 = 0.f, c2 = 0.f, c3 = 0.f;
    for (int j = l; j < deg; j += 16) {
        int s = csr[o0 + j];
        float4 ev = ((const float4*)es)[s];
        float e0 = lrelu(ev.x + edv.x), e1 = lrelu(ev.y + edv.y);
        float e2 = lrelu(ev.z + edv.z), e3 = lrelu(ev.w + edv.w);
        if (j < 16) { s_cache = s; c0 = e0; c1 = e1; c2 = e2; c3 = e3; }
        m0 = fmaxf(m0, e0); m1 = fmaxf(m1, e1);
        m2 = fmaxf(m2, e2); m3 = fmaxf(m3, e3);
    }
    m0 = red16_max(m0); m1 = red16_max(m1); m2 = red16_max(m2); m3 = red16_max(m3);

    float t0 = 0.f, t1 = 0.f, t2 = 0.f, t3 = 0.f;
    for (int j = l; j < deg; j += 16) {
        float e0, e1, e2, e3; int s;
        if (j < 16) { s = s_cache; e0 = c0; e1 = c1; e2 = c2; e3 = c3; }
        else {
            s = csr[o0 + j];
            float4 ev = ((const float4*)es)[s];
            e0 = lrelu(ev.x + edv.x); e1 = lrelu(ev.y + edv.y);
            e2 = lrelu(ev.z + edv.z); e3 = lrelu(ev.w + edv.w);
        }
        e0 = __expf(e0 - m0); e1 = __expf(e1 - m1);
        e2 = __expf(e2 - m2); e3 = __expf(e3 - m3);
        if (j < 64) {
            ((float4*)exl)[slot * 64 + j] = make_float4(e0, e1, e2, e3);
            sl[slot * 64 + j] = s;
        }
        t0 += e0; t1 += e1; t2 += e2; t3 += e3;
    }
    t0 = red16_sum(t0); t1 = red16_sum(t1); t2 = red16_sum(t2); t3 = red16_sum(t3);
    if (l == 0) {
        minv[slot * 8 + 0] = m0; minv[slot * 8 + 1] = m1;
        minv[slot * 8 + 2] = m2; minv[slot * 8 + 3] = m3;
        minv[slot * 8 + 4] = t0 > 0.f ? 1.f / t0 : 0.f;
        minv[slot * 8 + 5] = t1 > 0.f ? 1.f / t1 : 0.f;
        minv[slot * 8 + 6] = t2 > 0.f ? 1.f / t2 : 0.f;
        minv[slot * 8 + 7] = t3 > 0.f ? 1.f / t3 : 0.f;
        meta[slot * 2 + 0] = o0;
        meta[slot * 2 + 1] = deg;
    }
    __syncthreads();

    int lane = threadIdx.x & 63;
    int w = threadIdx.x >> 6;
    for (int sidx = 0; sidx < 4; sidx++) {
        int slot2 = w * 4 + sidx;
        int nd = blockIdx.x * NS + slot2;
        if (nd >= N) continue;
        int o0b = meta[slot2 * 2 + 0], degb = meta[slot2 * 2 + 1];
        float mm0 = minv[slot2 * 8 + 0], mm1 = minv[slot2 * 8 + 1];
        float mm2 = minv[slot2 * 8 + 2], mm3 = minv[slot2 * 8 + 3];
        float iv0 = minv[slot2 * 8 + 4], iv1 = minv[slot2 * 8 + 5];
        float iv2 = minv[slot2 * 8 + 6], iv3 = minv[slot2 * 8 + 7];

        float acc0 = 0.f, acc1 = 0.f, acc2 = 0.f, acc3 = 0.f;
        const float4* EX = ((const float4*)exl) + slot2 * 64;
        const int* S = sl + slot2 * 64;
        int dmain = degb < 64 ? degb : 64;
        int d4 = (dmain + 3) & ~3;
        for (int j = 0; j < d4; j += 4) {
            float4 a0 = EX[j], a1 = EX[j + 1], a2 = EX[j + 2], a3 = EX[j + 3];
            int s0 = S[j], s1 = S[j + 1], s2 = S[j + 2], s3 = S[j + 3];
            float v0 = hout[(size_t)s0 * 64 + lane];
            float v1 = hout[(size_t)s1 * 64 + lane];
            float v2 = hout[(size_t)s2 * 64 + lane];
            float v3 = hout[(size_t)s3 * 64 + lane];
            acc0 += a0.x * v0 + a1.x * v1 + a2.x * v2 + a3.x * v3;
            acc1 += a0.y * v0 + a1.y * v1 + a2.y * v2 + a3.y * v3;
            acc2 += a0.z * v0 + a1.z * v1 + a2.z * v2 + a3.z * v3;
            acc3 += a0.w * v0 + a1.w * v1 + a2.w * v2 + a3.w * v3;
        }
        if (degb > 64) {
            float4 edv2 = ((const float4*)ed)[nd];
            for (int j = 64; j < degb; j++) {
                int s = csr[o0b + j];
                float4 ev = ((const float4*)es)[s];
                float e0 = __expf(lrelu(ev.x + edv2.x) - mm0);
                float e1 = __expf(lrelu(ev.y + edv2.y) - mm1);
                float e2 = __expf(lrelu(ev.z + edv2.z) - mm2);
                float e3 = __expf(lrelu(ev.w + edv2.w) - mm3);
                float v = hout[(size_t)s * 64 + lane];
                acc0 += e0 * v; acc1 += e1 * v; acc2 += e2 * v; acc3 += e3 * v;
            }
        }
        size_t b = (size_t)nd * 256;
        agg[b + lane] = acc0 * iv0;
        agg[b + 64 + lane] = acc1 * iv1;
        agg[b + 128 + lane] = acc2 * iv2;
        agg[b + 192 + lane] = acc3 * iv3;
    }
}

// ======================= layer 2 output transform =======================
#define NB2 32
__global__ void k_out2(const float* __restrict__ agg, const float* __restrict__ W2,
                       const float* __restrict__ b2, float* __restrict__ hout2, int N) {
    __shared__ float lds[NB2 * 256];
    int t = threadIdx.x;
    int base = blockIdx.x * NB2;
    const float4* src = (const float4*)(agg + (size_t)base * 256);
    int limit4 = (N - base < NB2 ? N - base : NB2) * 64;
    for (int i = t; i < NB2 * 64; i += 256) {
        float4 v = (i < limit4) ? src[i] : make_float4(0.f, 0.f, 0.f, 0.f);
        ((float4*)lds)[i] = v;
    }
    __syncthreads();
    int c = t & 63, slot = t >> 6;
    float bv = b2[c];
    float acc[NB2 / 4];
#pragma unroll
    for (int j = 0; j < NB2 / 4; j++) acc[j] = 0.f;
    for (int hk = 0; hk < 256; hk++) {
        int h = hk >> 6, k = hk & 63;
        float w = W2[k * 256 + h * 64 + c];
#pragma unroll
        for (int j = 0; j < NB2 / 4; j++) acc[j] += lds[(slot + j * 4) * 256 + hk] * w;
    }
#pragma unroll
    for (int j = 0; j < NB2 / 4; j++) {
        int n = base + slot + j * 4;
        if (n < N) {
            float r = 0.25f * acc[j] + bv;
            hout2[(size_t)n * 64 + c] = fmaxf(r, 0.f);
        }
    }
}

// ======================= global add pool =======================
__global__ void k_pool(const float* __restrict__ h2, const int* __restrict__ batch,
                       float* __restrict__ out, int N, int G) {
    int g = blockIdx.x;
    if (g >= G) return;
    int lo = 0, hi = N;
    while (lo < hi) { int mid = (lo + hi) >> 1; if (batch[mid] < g) lo = mid + 1; else hi = mid; }
    int start = lo;
    lo = start; hi = N;
    while (lo < hi) { int mid = (lo + hi) >> 1; if (batch[mid] < g + 1) lo = mid + 1; else hi = mid; }
    int end = lo;
    int t = threadIdx.x, c = t & 63, j = t >> 6;
    float p = 0.f;
    for (int n = start + j; n < end; n += 4) p += h2[(size_t)n * 64 + c];
    __shared__ float lds[256];
    lds[t] = p;
    __syncthreads();
    if (j == 0) out[g * 64 + c] = lds[c] + lds[64 + c] + lds[128 + c] + lds[192 + c];
}

extern "C" void kernel_launch(void* const* d_in, const int* in_sizes, int n_in,
                              void* d_out, int out_size, void* d_ws, size_t ws_size,
                              hipStream_t stream) {
    const float* x   = (const float*)d_in[0];
    const int*   ei  = (const int*)d_in[1];
    const int*   bat = (const int*)d_in[2];
    const float* W1  = (const float*)d_in[3];
    const float* as1 = (const float*)d_in[4];
    const float* ad1 = (const float*)d_in[5];
    const float* b1  = (const float*)d_in[6];
    const float* W2  = (const float*)d_in[7];
    const float* as2 = (const float*)d_in[8];
    const float* ad2 = (const float*)d_in[9];
    const float* b2  = (const float*)d_in[10];
    float* out = (float*)d_out;

    int N = in_sizes[0] / 3;
    int E = in_sizes[1] / 2;
    int G = out_size / 64;
    const int* srcI = ei;
    const int* dstI = ei + E;
    int NBUCK = (N + BWIDTH - 1) >> BSHIFT;   // <= 1024 for N <= 131072

    // ---- workspace layout ----
    float* fw = (float*)d_ws;
    size_t fo = 0;
    float* agg   = fw + fo; fo += (size_t)N * 256;
    float* hout  = fw + fo; fo += (size_t)N * 64;
    float* hout2 = fw + fo; fo += (size_t)N * 64;
    float* esA   = fw + fo; fo += (size_t)N * 4;
    float* edA   = fw + fo; fo += (size_t)N * 4;
    float* esB   = fw + fo; fo += (size_t)N * 4;
    float* edB   = fw + fo; fo += (size_t)N * 4;
    float* p1s   = fw + fo; fo += 64;
    float* p1d   = fw + fo; fo += 64;
    float* qs    = fw + fo; fo += 256;
    float* qd    = fw + fo; fo += 256;
    int* iw = (int*)(fw + fo);        // 8B-aligned (fo even)
    size_t io = 0;
    uint2* pairs = (uint2*)iw; io += (size_t)2 * E;
    int* csr    = iw + io; io += E;
    int* off    = iw + io; io += N + 1;
    int* bbase  = iw + io; io += 1025;
    int* gcur   = iw + io; io += 1024;
    int* bcnt   = iw + io; io += 1024;

    int nThrBlk = (N + 255) / 256;
    int nGrpBlk = (N + 15) / 16;

    // ---- CSR build: two-level counting sort ----
    k_binit<<<1, 1024, 0, stream>>>(bcnt, NBUCK);
    k_bhist<<<256, 256, 0, stream>>>(dstI, bcnt, E, NBUCK);
    k_bscan<<<1, 1024, 0, stream>>>(bcnt, bbase, gcur, off, NBUCK, N, E);
    k_bdist<<<(E + DCHUNK - 1) / DCHUNK, 256, 0, stream>>>(srcI, dstI, gcur, pairs, E, NBUCK);
    k_bcsr<<<NBUCK, 256, 0, stream>>>(pairs, bbase, off, csr, N);

    // ---- precompute attention projections (both layers) ----
    k_prep<<<(3 * 8 * 64 + 255) / 256, 256, 0, stream>>>(W1, as1, ad1, p1s, p1d, 3);
    k_prep<<<(64 * 8 * 64 + 255) / 256, 256, 0, stream>>>(W2, as2, ad2, qs, qd, 64);

    // ---- layer 1 (writes hout + layer-2 es/ed) ----
    k_esed1<<<nThrBlk, 256, 0, stream>>>(x, p1s, p1d, esA, edA, N);
    k_agg1<<<nGrpBlk, 256, 0, stream>>>(off, csr, esA, edA, x, W1, b1, qs, qd,
                                        hout, esB, edB, N);

    // ---- layer 2 ----
    k_agg2<<<nGrpBlk, 256, 0, stream>>>(off, csr, esB, edB, hout, agg, N);
    k_out2<<<(N + NB2 - 1) / NB2, 256, 0, stream>>>(agg, W2, b2, hout2, N);

    // ---- pool ----
    k_pool<<<G, 256, 0, stream>>>(hout2, bat, out, N, G);
}

// Round 7
// 391.542 us; speedup vs baseline: 5.9339x; 1.2091x over previous
//
#include <hip/hip_runtime.h>
#include <math.h>

#define HEADS 4
#define HID 64
#define BSHIFT 7          // 128 nodes per bucket
#define BWIDTH 128
#define CCAP 4096         // LDS csr-staging capacity (edges/bucket mean ~2047)
#define DCHUNK 2048       // edges per k_bdist block (8 per thread)

__device__ __forceinline__ float lrelu(float x) { return x > 0.f ? x : 0.2f * x; }

__device__ __forceinline__ float wred_sum(float v) {
#pragma unroll
    for (int o = 32; o > 0; o >>= 1) v += __shfl_xor(v, o);
    return v;
}
__device__ __forceinline__ float red16_sum(float v) {
#pragma unroll
    for (int o = 8; o > 0; o >>= 1) v += __shfl_xor(v, o);
    return v;
}
__device__ __forceinline__ float red16_max(float v) {
#pragma unroll
    for (int o = 8; o > 0; o >>= 1) v = fmaxf(v, __shfl_xor(v, o));
    return v;
}

// ======================= CSR build: two-level LDS counting sort =======================
__global__ void k_binit(int* __restrict__ bcnt, int NBUCK) {
    int i = threadIdx.x;
    if (i < NBUCK) bcnt[i] = 0;
}

__global__ void k_bhist(const int* __restrict__ dstI, int* __restrict__ bcnt,
                        int E, int NBUCK) {
    __shared__ int h[1024];
    for (int i = threadIdx.x; i < NBUCK; i += 256) h[i] = 0;
    __syncthreads();
    int stride = gridDim.x * 256;
    for (int e = blockIdx.x * 256 + threadIdx.x; e < E; e += stride)
        atomicAdd(&h[dstI[e] >> BSHIFT], 1);
    __syncthreads();
    for (int i = threadIdx.x; i < NBUCK; i += 256)
        if (h[i]) atomicAdd(&bcnt[i], h[i]);
}

// single block, 1024 threads: exclusive scan of bucket counts
__global__ void k_bscan(const int* __restrict__ bcnt, int* __restrict__ bbase,
                        int* __restrict__ gcur, int* __restrict__ off,
                        int NBUCK, int N, int E) {
    __shared__ int lds[1024];
    int t = threadIdx.x;
    int v = (t < NBUCK) ? bcnt[t] : 0;
    lds[t] = v;
    __syncthreads();
    for (int s = 1; s < 1024; s <<= 1) {
        int u = (t >= s) ? lds[t - s] : 0;
        __syncthreads();
        lds[t] += u;
        __syncthreads();
    }
    if (t < NBUCK) {
        int b = lds[t] - v;
        bbase[t] = b;
        gcur[t] = b;
    }
    if (t == 0) { bbase[NBUCK] = E; off[N] = E; }
}

// distribute edges into bucket regions as (src,dst) pairs
__global__ void k_bdist(const int* __restrict__ srcI, const int* __restrict__ dstI,
                        int* __restrict__ gcur, uint2* __restrict__ pairs,
                        int E, int NBUCK) {
    __shared__ int h[1024];
    __shared__ int cur[1024];
    for (int i = threadIdx.x; i < NBUCK; i += 256) h[i] = 0;
    __syncthreads();
    int base = blockIdx.x * DCHUNK;
    int sr[8], dr[8];
#pragma unroll
    for (int k = 0; k < 8; k++) {
        int e = base + threadIdx.x + k * 256;
        if (e < E) {
            sr[k] = srcI[e];
            dr[k] = dstI[e];
            atomicAdd(&h[dr[k] >> BSHIFT], 1);
        } else dr[k] = -1;
    }
    __syncthreads();
    for (int i = threadIdx.x; i < NBUCK; i += 256)
        cur[i] = h[i] ? atomicAdd(&gcur[i], h[i]) : 0;
    __syncthreads();
#pragma unroll
    for (int k = 0; k < 8; k++) {
        if (dr[k] >= 0) {
            int b = dr[k] >> BSHIFT;
            int p = atomicAdd(&cur[b], 1);
            pairs[p] = make_uint2((unsigned)sr[k], (unsigned)dr[k]);
        }
    }
}

// one block per bucket: local degrees -> off[], LDS-cursor distribute -> coalesced csr
__global__ void k_bcsr(const uint2* __restrict__ pairs, const int* __restrict__ bbase,
                       int* __restrict__ off, int* __restrict__ csr, int N) {
    __shared__ int cnt[BWIDTH];
    __shared__ int scan[BWIDTH];
    __shared__ int cur[BWIDTH];
    __shared__ int stage[CCAP];
    int b = blockIdx.x;
    int nodeBase = b << BSHIFT;
    int nNodes = N - nodeBase;
    if (nNodes > BWIDTH) nNodes = BWIDTH;
    int e0 = bbase[b], e1 = bbase[b + 1];
    int ecnt = e1 - e0;
    if (threadIdx.x < BWIDTH) cnt[threadIdx.x] = 0;
    __syncthreads();
    for (int i = threadIdx.x; i < ecnt; i += 256)
        atomicAdd(&cnt[pairs[e0 + i].y - (unsigned)nodeBase], 1);
    __syncthreads();
    if (threadIdx.x < BWIDTH)
        scan[threadIdx.x] = (threadIdx.x < nNodes) ? cnt[threadIdx.x] : 0;
    __syncthreads();
    for (int s = 1; s < BWIDTH; s <<= 1) {
        int u = 0;
        if (threadIdx.x < BWIDTH && threadIdx.x >= s) u = scan[threadIdx.x - s];
        __syncthreads();
        if (threadIdx.x < BWIDTH) scan[threadIdx.x] += u;
        __syncthreads();
    }
    if (threadIdx.x < nNodes) {
        int ex = scan[threadIdx.x] - cnt[threadIdx.x];   // exclusive
        off[nodeBase + threadIdx.x] = e0 + ex;
        cur[threadIdx.x] = ex;
    }
    __syncthreads();
    for (int i = threadIdx.x; i < ecnt; i += 256) {
        uint2 pr = pairs[e0 + i];
        int l = atomicAdd(&cur[pr.y - (unsigned)nodeBase], 1);
        if (l < CCAP) stage[l] = (int)pr.x;
        else csr[e0 + l] = (int)pr.x;   // overflow fallback (never for ~2K/bucket)
    }
    __syncthreads();
    int lim = ecnt < CCAP ? ecnt : CCAP;
    for (int i = threadIdx.x; i < lim; i += 256) csr[e0 + i] = stage[i];
}

// ======================= attention-coefficient precompute =======================
__global__ void k_prep(const float* __restrict__ W, const float* __restrict__ asrc,
                       const float* __restrict__ adst, float* __restrict__ p_src,
                       float* __restrict__ p_dst, int K) {
    int wid = (blockIdx.x * blockDim.x + threadIdx.x) >> 6;
    int lane = threadIdx.x & 63;
    int total = K * 4 * 2;
    if (wid >= total) return;
    int which = wid / (K * 4);
    int hk = wid % (K * 4);
    int h = hk / K, k = hk % K;
    const float* a = which ? adst : asrc;
    float v = W[(size_t)k * 256 + h * 64 + lane] * a[h * 64 + lane];
    v = wred_sum(v);
    if (lane == 0) (which ? p_dst : p_src)[h * K + k] = v;
}

// es[n,h] = sum_k x[n,k] * ps[h*3+k]  (layer 1)
__global__ void k_esed1(const float* __restrict__ x, const float* __restrict__ ps,
                        const float* __restrict__ pd, float* __restrict__ es,
                        float* __restrict__ ed, int N) {
    int n = blockIdx.x * blockDim.x + threadIdx.x;
    if (n >= N) return;
    float x0 = x[n * 3], x1 = x[n * 3 + 1], x2 = x[n * 3 + 2];
    float4 s, d;
    s.x = x0 * ps[0] + x1 * ps[1] + x2 * ps[2];
    s.y = x0 * ps[3] + x1 * ps[4] + x2 * ps[5];
    s.z = x0 * ps[6] + x1 * ps[7] + x2 * ps[8];
    s.w = x0 * ps[9] + x1 * ps[10] + x2 * ps[11];
    d.x = x0 * pd[0] + x1 * pd[1] + x2 * pd[2];
    d.y = x0 * pd[3] + x1 * pd[4] + x2 * pd[5];
    d.z = x0 * pd[6] + x1 * pd[7] + x2 * pd[8];
    d.w = x0 * pd[9] + x1 * pd[10] + x2 * pd[11];
    ((float4*)es)[n] = s;
    ((float4*)ed)[n] = d;
}

// ======================= layer 1: 16-lane group per node =======================
__global__ void k_agg1(const int* __restrict__ off, const int* __restrict__ csr,
                       const float* __restrict__ es, const float* __restrict__ ed,
                       const float* __restrict__ x, const float* __restrict__ W1,
                       const float* __restrict__ b1, const float* __restrict__ qs,
                       const float* __restrict__ qd, float* __restrict__ hout,
                       float* __restrict__ es2, float* __restrict__ ed2, int N) {
    int grp = (blockIdx.x * blockDim.x + threadIdx.x) >> 4;
    int l = threadIdx.x & 15;
    int wid = grp;
    bool active = wid < N;
    int o0 = 0, deg = 0;
    float4 edv = make_float4(0.f, 0.f, 0.f, 0.f);
    if (active) {
        o0 = off[wid];
        deg = off[wid + 1] - o0;
        edv = ((const float4*)ed)[wid];
    }

    float m0 = -INFINITY, m1 = -INFINITY, m2 = -INFINITY, m3 = -INFINITY;
    int s_cache = 0;
    float c0 = 0.f, c1 = 0.f, c2 = 0.f, c3 = 0.f;
    for (int j = l; j < deg; j += 16) {
        int s = csr[o0 + j];
        float4 ev = ((const float4*)es)[s];
        float e0 = lrelu(ev.x + edv.x), e1 = lrelu(ev.y + edv.y);
        float e2 = lrelu(ev.z + edv.z), e3 = lrelu(ev.w + edv.w);
        if (j < 16) { s_cache = s; c0 = e0; c1 = e1; c2 = e2; c3 = e3; }
        m0 = fmaxf(m0, e0); m1 = fmaxf(m1, e1);
        m2 = fmaxf(m2, e2); m3 = fmaxf(m3, e3);
    }
    m0 = red16_max(m0); m1 = red16_max(m1); m2 = red16_max(m2); m3 = red16_max(m3);

    float t0 = 0.f, t1 = 0.f, t2 = 0.f, t3 = 0.f;
    for (int j = l; j < deg; j += 16) {
        float e0, e1, e2, e3;
        if (j < 16) { e0 = c0; e1 = c1; e2 = c2; e3 = c3; }
        else {
            int s = csr[o0 + j];
            float4 ev = ((const float4*)es)[s];
            e0 = lrelu(ev.x + edv.x); e1 = lrelu(ev.y + edv.y);
            e2 = lrelu(ev.z + edv.z); e3 = lrelu(ev.w + edv.w);
        }
        e0 = __expf(e0 - m0); e1 = __expf(e1 - m1);
        e2 = __expf(e2 - m2); e3 = __expf(e3 - m3);
        if (j < 16) { c0 = e0; c1 = e1; c2 = e2; c3 = e3; }
        t0 += e0; t1 += e1; t2 += e2; t3 += e3;
    }
    t0 = red16_sum(t0); t1 = red16_sum(t1); t2 = red16_sum(t2); t3 = red16_sum(t3);
    float i0 = t0 > 0.f ? 1.f / t0 : 0.f;
    float i1 = t1 > 0.f ? 1.f / t1 : 0.f;
    float i2 = t2 > 0.f ? 1.f / t2 : 0.f;
    float i3 = t3 > 0.f ? 1.f / t3 : 0.f;

    float a00 = 0, a01 = 0, a02 = 0, a10 = 0, a11 = 0, a12 = 0;
    float a20 = 0, a21 = 0, a22 = 0, a30 = 0, a31 = 0, a32 = 0;
    for (int j = l; j < deg; j += 16) {
        float e0, e1, e2, e3; int s;
        if (j < 16) { s = s_cache; e0 = c0; e1 = c1; e2 = c2; e3 = c3; }
        else {
            s = csr[o0 + j];
            float4 ev = ((const float4*)es)[s];
            e0 = __expf(lrelu(ev.x + edv.x) - m0);
            e1 = __expf(lrelu(ev.y + edv.y) - m1);
            e2 = __expf(lrelu(ev.z + edv.z) - m2);
            e3 = __expf(lrelu(ev.w + edv.w) - m3);
        }
        float xv0 = x[s * 3], xv1 = x[s * 3 + 1], xv2 = x[s * 3 + 2];
        a00 += e0 * xv0; a01 += e0 * xv1; a02 += e0 * xv2;
        a10 += e1 * xv0; a11 += e1 * xv1; a12 += e1 * xv2;
        a20 += e2 * xv0; a21 += e2 * xv1; a22 += e2 * xv2;
        a30 += e3 * xv0; a31 += e3 * xv1; a32 += e3 * xv2;
    }
    a00 = red16_sum(a00) * i0; a01 = red16_sum(a01) * i0; a02 = red16_sum(a02) * i0;
    a10 = red16_sum(a10) * i1; a11 = red16_sum(a11) * i1; a12 = red16_sum(a12) * i1;
    a20 = red16_sum(a20) * i2; a21 = red16_sum(a21) * i2; a22 = red16_sum(a22) * i2;
    a30 = red16_sum(a30) * i3; a31 = red16_sum(a31) * i3; a32 = red16_sum(a32) * i3;

    if (!active) return;

    const float4* W1f = (const float4*)W1;
    float4 r = make_float4(0.f, 0.f, 0.f, 0.f);
    float ah[4][3] = {{a00, a01, a02}, {a10, a11, a12}, {a20, a21, a22}, {a30, a31, a32}};
#pragma unroll
    for (int k = 0; k < 3; k++) {
#pragma unroll
        for (int h = 0; h < 4; h++) {
            float4 wv = W1f[k * 64 + h * 16 + l];
            float a = ah[h][k];
            r.x += a * wv.x; r.y += a * wv.y; r.z += a * wv.z; r.w += a * wv.w;
        }
    }
    float4 bv = ((const float4*)b1)[l];
    float4 hv;
    hv.x = fmaxf(0.25f * r.x + bv.x, 0.f);
    hv.y = fmaxf(0.25f * r.y + bv.y, 0.f);
    hv.z = fmaxf(0.25f * r.z + bv.z, 0.f);
    hv.w = fmaxf(0.25f * r.w + bv.w, 0.f);
    ((float4*)hout)[(size_t)wid * 16 + l] = hv;

    const float4* qsf = (const float4*)qs;
    const float4* qdf = (const float4*)qd;
    float ps[4], pd[4];
#pragma unroll
    for (int h = 0; h < 4; h++) {
        float4 q = qsf[h * 16 + l];
        ps[h] = red16_sum(hv.x * q.x + hv.y * q.y + hv.z * q.z + hv.w * q.w);
        float4 p = qdf[h * 16 + l];
        pd[h] = red16_sum(hv.x * p.x + hv.y * p.y + hv.z * p.z + hv.w * p.w);
    }
    if (l == 0) {
        ((float4*)es2)[wid] = make_float4(ps[0], ps[1], ps[2], ps[3]);
        ((float4*)ed2)[wid] = make_float4(pd[0], pd[1], pd[2], pd[3]);
    }
}

// ======================= layer 2: phase-A 16-lane softmax -> LDS, phase-B wave gather =======================
#define NS 16
__global__ void k_agg2(const int* __restrict__ off, const int* __restrict__ csr,
                       const float* __restrict__ es, const float* __restrict__ ed,
                       const float* __restrict__ hout, float* __restrict__ agg, int N) {
    __shared__ float exl[NS * 64 * 4];
    __shared__ int   sl[NS * 64];
    __shared__ float minv[NS * 8];
    __shared__ int   meta[NS * 2];

    for (int i = threadIdx.x; i < NS * 64; i += 256) {
        ((float4*)exl)[i] = make_float4(0.f, 0.f, 0.f, 0.f);
        sl[i] = 0;
    }
    __syncthreads();

    int l = threadIdx.x & 15;
    int slot = threadIdx.x >> 4;
    int wid = blockIdx.x * NS + slot;
    bool active = wid < N;
    int o0 = 0, deg = 0;
    float4 edv = make_float4(0.f, 0.f, 0.f, 0.f);
    if (active) {
        o0 = off[wid];
        deg = off[wid + 1] - o0;
        edv = ((const float4*)ed)[wid];
    }

    float m0 = -INFINITY, m1 = -INFINITY, m2 = -INFINITY, m3 = -INFINITY;
    int s_cache = 0;
    float c0 = 0.f, c1 = 0.f, c2 = 0.f, c3 = 0.f;
    for (int j = l; j < deg; j += 16) {
        int s = csr[o0 + j];
        float4 ev = ((const float4*)es)[s];
        float e0 = lrelu(ev.x + edv.x), e1 = lrelu(ev.y + edv.y);
        float e2 = lrelu(ev.z + edv.z), e3 = lrelu(ev.w + edv.w);
        if (j < 16) { s_cache = s; c0 = e0; c1 = e1; c2 = e2; c3 = e3; }
        m0 = fmaxf(m0, e0); m1 = fmaxf(m1, e1);
        m2 = fmaxf(m2, e2); m3 = fmaxf(m3, e3);
    }
    m0 = red16_max(m0); m1 = red16_max(m1); m2 = red16_max(m2); m3 = red16_max(m3);

    float t0 = 0.f, t1 = 0.f, t2 = 0.f, t3 = 0.f;
    for (int j = l; j < deg; j += 16) {
        float e0, e1, e2, e3; int s;
        if (j < 16) { s = s_cache; e0 = c0; e1 = c1; e2 = c2; e3 = c3; }
        else {
            s = csr[o0 + j];
            float4 ev = ((const float4*)es)[s];
            e0 = lrelu(ev.x + edv.x); e1 = lrelu(ev.y + edv.y);
            e2 = lrelu(ev.z + edv.z); e3 = lrelu(ev.w + edv.w);
        }
        e0 = __expf(e0 - m0); e1 = __expf(e1 - m1);
        e2 = __expf(e2 - m2); e3 = __expf(e3 - m3);
        if (j < 64) {
            ((float4*)exl)[slot * 64 + j] = make_float4(e0, e1, e2, e3);
            sl[slot * 64 + j] = s;
        }
        t0 += e0; t1 += e1; t2 += e2; t3 += e3;
    }
    t0 = red16_sum(t0); t1 = red16_sum(t1); t2 = red16_sum(t2); t3 = red16_sum(t3);
    if (l == 0) {
        minv[slot * 8 + 0] = m0; minv[slot * 8 + 1] = m1;
        minv[slot * 8 + 2] = m2; minv[slot * 8 + 3] = m3;
        minv[slot * 8 + 4] = t0 > 0.f ? 1.f / t0 : 0.f;
        minv[slot * 8 + 5] = t1 > 0.f ? 1.f / t1 : 0.f;
        minv[slot * 8 + 6] = t2 > 0.f ? 1.f / t2 : 0.f;
        minv[slot * 8 + 7] = t3 > 0.f ? 1.f / t3 : 0.f;
        meta[slot * 2 + 0] = o0;
        meta[slot * 2 + 1] = deg;
    }
    __syncthreads();

    int lane = threadIdx.x & 63;
    int w = threadIdx.x >> 6;
    for (int sidx = 0; sidx < 4; sidx++) {
        int slot2 = w * 4 + sidx;
        int nd = blockIdx.x * NS + slot2;
        if (nd >= N) continue;
        int o0b = meta[slot2 * 2 + 0], degb = meta[slot2 * 2 + 1];
        float mm0 = minv[slot2 * 8 + 0], mm1 = minv[slot2 * 8 + 1];
        float mm2 = minv[slot2 * 8 + 2], mm3 = minv[slot2 * 8 + 3];
        float iv0 = minv[slot2 * 8 + 4], iv1 = minv[slot2 * 8 + 5];
        float iv2 = minv[slot2 * 8 + 6], iv3 = minv[slot2 * 8 + 7];

        float acc0 = 0.f, acc1 = 0.f, acc2 = 0.f, acc3 = 0.f;
        const float4* EX = ((const float4*)exl) + slot2 * 64;
        const int* S = sl + slot2 * 64;
        int dmain = degb < 64 ? degb : 64;
        int d4 = (dmain + 3) & ~3;
        for (int j = 0; j < d4; j += 4) {
            float4 a0 = EX[j], a1 = EX[j + 1], a2 = EX[j + 2], a3 = EX[j + 3];
            int s0 = S[j], s1 = S[j + 1], s2 = S[j + 2], s3 = S[j + 3];
            float v0 = hout[(size_t)s0 * 64 + lane];
            float v1 = hout[(size_t)s1 * 64 + lane];
            float v2 = hout[(size_t)s2 * 64 + lane];
            float v3 = hout[(size_t)s3 * 64 + lane];
            acc0 += a0.x * v0 + a1.x * v1 + a2.x * v2 + a3.x * v3;
            acc1 += a0.y * v0 + a1.y * v1 + a2.y * v2 + a3.y * v3;
            acc2 += a0.z * v0 + a1.z * v1 + a2.z * v2 + a3.z * v3;
            acc3 += a0.w * v0 + a1.w * v1 + a2.w * v2 + a3.w * v3;
        }
        if (degb > 64) {
            float4 edv2 = ((const float4*)ed)[nd];
            for (int j = 64; j < degb; j++) {
                int s = csr[o0b + j];
                float4 ev = ((const float4*)es)[s];
                float e0 = __expf(lrelu(ev.x + edv2.x) - mm0);
                float e1 = __expf(lrelu(ev.y + edv2.y) - mm1);
                float e2 = __expf(lrelu(ev.z + edv2.z) - mm2);
                float e3 = __expf(lrelu(ev.w + edv2.w) - mm3);
                float v = hout[(size_t)s * 64 + lane];
                acc0 += e0 * v; acc1 += e1 * v; acc2 += e2 * v; acc3 += e3 * v;
            }
        }
        size_t b = (size_t)nd * 256;
        agg[b + lane] = acc0 * iv0;
        agg[b + 64 + lane] = acc1 * iv1;
        agg[b + 128 + lane] = acc2 * iv2;
        agg[b + 192 + lane] = acc3 * iv3;
    }
}

// ======================= layer 2 output transform =======================
#define NB2 32
__global__ void k_out2(const float* __restrict__ agg, const float* __restrict__ W2,
                       const float* __restrict__ b2, float* __restrict__ hout2, int N) {
    __shared__ float lds[NB2 * 256];
    int t = threadIdx.x;
    int base = blockIdx.x * NB2;
    const float4* src = (const float4*)(agg + (size_t)base * 256);
    int limit4 = (N - base < NB2 ? N - base : NB2) * 64;
    for (int i = t; i < NB2 * 64; i += 256) {
        float4 v = (i < limit4) ? src[i] : make_float4(0.f, 0.f, 0.f, 0.f);
        ((float4*)lds)[i] = v;
    }
    __syncthreads();
    int c = t & 63, slot = t >> 6;
    float bv = b2[c];
    float acc[NB2 / 4];
#pragma unroll
    for (int j = 0; j < NB2 / 4; j++) acc[j] = 0.f;
    for (int hk = 0; hk < 256; hk++) {
        int h = hk >> 6, k = hk & 63;
        float w = W2[k * 256 + h * 64 + c];
#pragma unroll
        for (int j = 0; j < NB2 / 4; j++) acc[j] += lds[(slot + j * 4) * 256 + hk] * w;
    }
#pragma unroll
    for (int j = 0; j < NB2 / 4; j++) {
        int n = base + slot + j * 4;
        if (n < N) {
            float r = 0.25f * acc[j] + bv;
            hout2[(size_t)n * 64 + c] = fmaxf(r, 0.f);
        }
    }
}

// ======================= global add pool (wide) =======================
__global__ void k_pzero(float* __restrict__ out, int total) {
    int i = blockIdx.x * blockDim.x + threadIdx.x;
    if (i < total) out[i] = 0.f;
}

// 16-lane slices: slice owns float4 channel-slot c4 and a contiguous node chunk.
// batch sorted -> few graph-boundary crossings per chunk; flush via atomicAdd.
__global__ void k_pool(const float* __restrict__ h2, const int* __restrict__ batch,
                       float* __restrict__ out, int N, int G) {
    int tid = blockIdx.x * blockDim.x + threadIdx.x;
    int c4 = tid & 15;
    int grp = tid >> 4;                       // 0 .. ngroups-1
    int ngroups = (gridDim.x * blockDim.x) >> 4;
    int chunk = (N + ngroups - 1) / ngroups;
    int n0 = grp * chunk;
    int n1 = n0 + chunk; if (n1 > N) n1 = N;
    if (n0 >= N) return;

    int curg = -1;
    float4 acc = make_float4(0.f, 0.f, 0.f, 0.f);
    for (int n = n0; n < n1; n++) {
        int g = batch[n];
        if (g != curg) {
            if (curg >= 0) {
                float* o = out + curg * 64 + c4 * 4;
                atomicAdd(o + 0, acc.x); atomicAdd(o + 1, acc.y);
                atomicAdd(o + 2, acc.z); atomicAdd(o + 3, acc.w);
            }
            curg = g;
            acc = make_float4(0.f, 0.f, 0.f, 0.f);
        }
        float4 v = ((const float4*)h2)[(size_t)n * 16 + c4];
        acc.x += v.x; acc.y += v.y; acc.z += v.z; acc.w += v.w;
    }
    if (curg >= 0) {
        float* o = out + curg * 64 + c4 * 4;
        atomicAdd(o + 0, acc.x); atomicAdd(o + 1, acc.y);
        atomicAdd(o + 2, acc.z); atomicAdd(o + 3, acc.w);
    }
}

extern "C" void kernel_launch(void* const* d_in, const int* in_sizes, int n_in,
                              void* d_out, int out_size, void* d_ws, size_t ws_size,
                              hipStream_t stream) {
    const float* x   = (const float*)d_in[0];
    const int*   ei  = (const int*)d_in[1];
    const int*   bat = (const int*)d_in[2];
    const float* W1  = (const float*)d_in[3];
    const float* as1 = (const float*)d_in[4];
    const float* ad1 = (const float*)d_in[5];
    const float* b1  = (const float*)d_in[6];
    const float* W2  = (const float*)d_in[7];
    const float* as2 = (const float*)d_in[8];
    const float* ad2 = (const float*)d_in[9];
    const float* b2  = (const float*)d_in[10];
    float* out = (float*)d_out;

    int N = in_sizes[0] / 3;
    int E = in_sizes[1] / 2;
    int G = out_size / 64;
    const int* srcI = ei;
    const int* dstI = ei + E;
    int NBUCK = (N + BWIDTH - 1) >> BSHIFT;   // <= 1024 for N <= 131072

    // ---- workspace layout ----
    float* fw = (float*)d_ws;
    size_t fo = 0;
    float* agg   = fw + fo; fo += (size_t)N * 256;
    float* hout  = fw + fo; fo += (size_t)N * 64;
    float* hout2 = fw + fo; fo += (size_t)N * 64;
    float* esA   = fw + fo; fo += (size_t)N * 4;
    float* edA   = fw + fo; fo += (size_t)N * 4;
    float* esB   = fw + fo; fo += (size_t)N * 4;
    float* edB   = fw + fo; fo += (size_t)N * 4;
    float* p1s   = fw + fo; fo += 64;
    float* p1d   = fw + fo; fo += 64;
    float* qs    = fw + fo; fo += 256;
    float* qd    = fw + fo; fo += 256;
    int* iw = (int*)(fw + fo);        // 8B-aligned (fo even)
    size_t io = 0;
    uint2* pairs = (uint2*)iw; io += (size_t)2 * E;
    int* csr    = iw + io; io += E;
    int* off    = iw + io; io += N + 1;
    int* bbase  = iw + io; io += 1025;
    int* gcur   = iw + io; io += 1024;
    int* bcnt   = iw + io; io += 1024;

    int nThrBlk = (N + 255) / 256;
    int nGrpBlk = (N + 15) / 16;

    // ---- CSR build: two-level counting sort ----
    k_binit<<<1, 1024, 0, stream>>>(bcnt, NBUCK);
    k_bhist<<<256, 256, 0, stream>>>(dstI, bcnt, E, NBUCK);
    k_bscan<<<1, 1024, 0, stream>>>(bcnt, bbase, gcur, off, NBUCK, N, E);
    k_bdist<<<(E + DCHUNK - 1) / DCHUNK, 256, 0, stream>>>(srcI, dstI, gcur, pairs, E, NBUCK);
    k_bcsr<<<NBUCK, 256, 0, stream>>>(pairs, bbase, off, csr, N);

    // ---- precompute attention projections (both layers) ----
    k_prep<<<(3 * 8 * 64 + 255) / 256, 256, 0, stream>>>(W1, as1, ad1, p1s, p1d, 3);
    k_prep<<<(64 * 8 * 64 + 255) / 256, 256, 0, stream>>>(W2, as2, ad2, qs, qd, 64);

    // ---- layer 1 (writes hout + layer-2 es/ed) ----
    k_esed1<<<nThrBlk, 256, 0, stream>>>(x, p1s, p1d, esA, edA, N);
    k_agg1<<<nGrpBlk, 256, 0, stream>>>(off, csr, esA, edA, x, W1, b1, qs, qd,
                                        hout, esB, edB, N);

    // ---- layer 2 ----
    k_agg2<<<nGrpBlk, 256, 0, stream>>>(off, csr, esB, edB, hout, agg, N);
    k_out2<<<(N + NB2 - 1) / NB2, 256, 0, stream>>>(agg, W2, b2, hout2, N);

    // ---- pool ----
    k_pzero<<<(G * 64 + 255) / 256, 256, 0, stream>>>(out, G * 64);
    k_pool<<<512, 256, 0, stream>>>(hout2, bat, out, N, G);
}

// Round 8
// 339.472 us; speedup vs baseline: 6.8441x; 1.1534x over previous
//
#include <hip/hip_runtime.h>
#include <math.h>

#define HEADS 4
#define HID 64
#define BSHIFT 7          // 128 nodes per bucket
#define BWIDTH 128
#define CCAP 4096         // LDS csr-staging capacity (edges/bucket mean ~2047)
#define DCHUNK 2048       // edges per k_bdist block (8 per thread)

typedef __attribute__((ext_vector_type(8))) short short8;
typedef __attribute__((ext_vector_type(4))) float f32x4;

__device__ __forceinline__ float lrelu(float x) { return x > 0.f ? x : 0.2f * x; }

__device__ __forceinline__ unsigned short bf16r(float f) {
    unsigned u = __float_as_uint(f);
    unsigned r = (u + 0x7FFFu + ((u >> 16) & 1u)) >> 16;
    return (unsigned short)r;
}

__device__ __forceinline__ float wred_sum(float v) {
#pragma unroll
    for (int o = 32; o > 0; o >>= 1) v += __shfl_xor(v, o);
    return v;
}
__device__ __forceinline__ float red16_sum(float v) {
#pragma unroll
    for (int o = 8; o > 0; o >>= 1) v += __shfl_xor(v, o);
    return v;
}
__device__ __forceinline__ float red16_max(float v) {
#pragma unroll
    for (int o = 8; o > 0; o >>= 1) v = fmaxf(v, __shfl_xor(v, o));
    return v;
}

// ======================= CSR build: two-level LDS counting sort =======================
__global__ void k_binit(int* __restrict__ bcnt, int NBUCK) {
    int i = threadIdx.x;
    if (i < NBUCK) bcnt[i] = 0;
}

__global__ void k_bhist(const int* __restrict__ dstI, int* __restrict__ bcnt,
                        int E, int NBUCK) {
    __shared__ int h[1024];
    for (int i = threadIdx.x; i < NBUCK; i += 256) h[i] = 0;
    __syncthreads();
    int stride = gridDim.x * 256;
    for (int e = blockIdx.x * 256 + threadIdx.x; e < E; e += stride)
        atomicAdd(&h[dstI[e] >> BSHIFT], 1);
    __syncthreads();
    for (int i = threadIdx.x; i < NBUCK; i += 256)
        if (h[i]) atomicAdd(&bcnt[i], h[i]);
}

// single block, 1024 threads: exclusive scan of bucket counts
__global__ void k_bscan(const int* __restrict__ bcnt, int* __restrict__ bbase,
                        int* __restrict__ gcur, int* __restrict__ off,
                        int NBUCK, int N, int E) {
    __shared__ int lds[1024];
    int t = threadIdx.x;
    int v = (t < NBUCK) ? bcnt[t] : 0;
    lds[t] = v;
    __syncthreads();
    for (int s = 1; s < 1024; s <<= 1) {
        int u = (t >= s) ? lds[t - s] : 0;
        __syncthreads();
        lds[t] += u;
        __syncthreads();
    }
    if (t < NBUCK) {
        int b = lds[t] - v;
        bbase[t] = b;
        gcur[t] = b;
    }
    if (t == 0) { bbase[NBUCK] = E; off[N] = E; }
}

// distribute edges into bucket regions as (src,dst) pairs
__global__ void k_bdist(const int* __restrict__ srcI, const int* __restrict__ dstI,
                        int* __restrict__ gcur, uint2* __restrict__ pairs,
                        int E, int NBUCK) {
    __shared__ int h[1024];
    __shared__ int cur[1024];
    for (int i = threadIdx.x; i < NBUCK; i += 256) h[i] = 0;
    __syncthreads();
    int base = blockIdx.x * DCHUNK;
    int sr[8], dr[8];
#pragma unroll
    for (int k = 0; k < 8; k++) {
        int e = base + threadIdx.x + k * 256;
        if (e < E) {
            sr[k] = srcI[e];
            dr[k] = dstI[e];
            atomicAdd(&h[dr[k] >> BSHIFT], 1);
        } else dr[k] = -1;
    }
    __syncthreads();
    for (int i = threadIdx.x; i < NBUCK; i += 256)
        cur[i] = h[i] ? atomicAdd(&gcur[i], h[i]) : 0;
    __syncthreads();
#pragma unroll
    for (int k = 0; k < 8; k++) {
        if (dr[k] >= 0) {
            int b = dr[k] >> BSHIFT;
            int p = atomicAdd(&cur[b], 1);
            pairs[p] = make_uint2((unsigned)sr[k], (unsigned)dr[k]);
        }
    }
}

// one block per bucket: local degrees -> off[], LDS-cursor distribute -> coalesced csr
__global__ void k_bcsr(const uint2* __restrict__ pairs, const int* __restrict__ bbase,
                       int* __restrict__ off, int* __restrict__ csr, int N) {
    __shared__ int cnt[BWIDTH];
    __shared__ int scan[BWIDTH];
    __shared__ int cur[BWIDTH];
    __shared__ int stage[CCAP];
    int b = blockIdx.x;
    int nodeBase = b << BSHIFT;
    int nNodes = N - nodeBase;
    if (nNodes > BWIDTH) nNodes = BWIDTH;
    int e0 = bbase[b], e1 = bbase[b + 1];
    int ecnt = e1 - e0;
    if (threadIdx.x < BWIDTH) cnt[threadIdx.x] = 0;
    __syncthreads();
    for (int i = threadIdx.x; i < ecnt; i += 256)
        atomicAdd(&cnt[pairs[e0 + i].y - (unsigned)nodeBase], 1);
    __syncthreads();
    if (threadIdx.x < BWIDTH)
        scan[threadIdx.x] = (threadIdx.x < nNodes) ? cnt[threadIdx.x] : 0;
    __syncthreads();
    for (int s = 1; s < BWIDTH; s <<= 1) {
        int u = 0;
        if (threadIdx.x < BWIDTH && threadIdx.x >= s) u = scan[threadIdx.x - s];
        __syncthreads();
        if (threadIdx.x < BWIDTH) scan[threadIdx.x] += u;
        __syncthreads();
    }
    if (threadIdx.x < nNodes) {
        int ex = scan[threadIdx.x] - cnt[threadIdx.x];   // exclusive
        off[nodeBase + threadIdx.x] = e0 + ex;
        cur[threadIdx.x] = ex;
    }
    __syncthreads();
    for (int i = threadIdx.x; i < ecnt; i += 256) {
        uint2 pr = pairs[e0 + i];
        int l = atomicAdd(&cur[pr.y - (unsigned)nodeBase], 1);
        if (l < CCAP) stage[l] = (int)pr.x;
        else csr[e0 + l] = (int)pr.x;   // overflow fallback
    }
    __syncthreads();
    int lim = ecnt < CCAP ? ecnt : CCAP;
    for (int i = threadIdx.x; i < lim; i += 256) csr[e0 + i] = stage[i];
}

// ======================= attention-coefficient precompute =======================
__global__ void k_prep(const float* __restrict__ W, const float* __restrict__ asrc,
                       const float* __restrict__ adst, float* __restrict__ p_src,
                       float* __restrict__ p_dst, int K) {
    int wid = (blockIdx.x * blockDim.x + threadIdx.x) >> 6;
    int lane = threadIdx.x & 63;
    int total = K * 4 * 2;
    if (wid >= total) return;
    int which = wid / (K * 4);
    int hk = wid % (K * 4);
    int h = hk / K, k = hk % K;
    const float* a = which ? adst : asrc;
    float v = W[(size_t)k * 256 + h * 64 + lane] * a[h * 64 + lane];
    v = wred_sum(v);
    if (lane == 0) (which ? p_dst : p_src)[h * K + k] = v;
}

// W2 -> bf16, transposed: W2bt[c*256 + h*64 + kf] = bf16(W2[kf*256 + h*64 + c])
__global__ void k_w2bt(const float* __restrict__ W2, unsigned short* __restrict__ W2bt) {
    int i = blockIdx.x * 256 + threadIdx.x;   // i = c*256 + kh
    int c = i >> 8, kh = i & 255;
    int h = kh >> 6, kf = kh & 63;
    W2bt[i] = bf16r(W2[kf * 256 + h * 64 + c]);
}

// es[n,h] = sum_k x[n,k] * ps[h*3+k]  (layer 1)
__global__ void k_esed1(const float* __restrict__ x, const float* __restrict__ ps,
                        const float* __restrict__ pd, float* __restrict__ es,
                        float* __restrict__ ed, int N) {
    int n = blockIdx.x * blockDim.x + threadIdx.x;
    if (n >= N) return;
    float x0 = x[n * 3], x1 = x[n * 3 + 1], x2 = x[n * 3 + 2];
    float4 s, d;
    s.x = x0 * ps[0] + x1 * ps[1] + x2 * ps[2];
    s.y = x0 * ps[3] + x1 * ps[4] + x2 * ps[5];
    s.z = x0 * ps[6] + x1 * ps[7] + x2 * ps[8];
    s.w = x0 * ps[9] + x1 * ps[10] + x2 * ps[11];
    d.x = x0 * pd[0] + x1 * pd[1] + x2 * pd[2];
    d.y = x0 * pd[3] + x1 * pd[4] + x2 * pd[5];
    d.z = x0 * pd[6] + x1 * pd[7] + x2 * pd[8];
    d.w = x0 * pd[9] + x1 * pd[10] + x2 * pd[11];
    ((float4*)es)[n] = s;
    ((float4*)ed)[n] = d;
}

// ======================= layer 1: 16-lane group per node =======================
__global__ void k_agg1(const int* __restrict__ off, const int* __restrict__ csr,
                       const float* __restrict__ es, const float* __restrict__ ed,
                       const float* __restrict__ x, const float* __restrict__ W1,
                       const float* __restrict__ b1, const float* __restrict__ qs,
                       const float* __restrict__ qd, float* __restrict__ hout,
                       float* __restrict__ es2, float* __restrict__ ed2, int N) {
    int grp = (blockIdx.x * blockDim.x + threadIdx.x) >> 4;
    int l = threadIdx.x & 15;
    int wid = grp;
    bool active = wid < N;
    int o0 = 0, deg = 0;
    float4 edv = make_float4(0.f, 0.f, 0.f, 0.f);
    if (active) {
        o0 = off[wid];
        deg = off[wid + 1] - o0;
        edv = ((const float4*)ed)[wid];
    }

    float m0 = -INFINITY, m1 = -INFINITY, m2 = -INFINITY, m3 = -INFINITY;
    int s_cache = 0;
    float c0 = 0.f, c1 = 0.f, c2 = 0.f, c3 = 0.f;
    for (int j = l; j < deg; j += 16) {
        int s = csr[o0 + j];
        float4 ev = ((const float4*)es)[s];
        float e0 = lrelu(ev.x + edv.x), e1 = lrelu(ev.y + edv.y);
        float e2 = lrelu(ev.z + edv.z), e3 = lrelu(ev.w + edv.w);
        if (j < 16) { s_cache = s; c0 = e0; c1 = e1; c2 = e2; c3 = e3; }
        m0 = fmaxf(m0, e0); m1 = fmaxf(m1, e1);
        m2 = fmaxf(m2, e2); m3 = fmaxf(m3, e3);
    }
    m0 = red16_max(m0); m1 = red16_max(m1); m2 = red16_max(m2); m3 = red16_max(m3);

    float t0 = 0.f, t1 = 0.f, t2 = 0.f, t3 = 0.f;
    for (int j = l; j < deg; j += 16) {
        float e0, e1, e2, e3;
        if (j < 16) { e0 = c0; e1 = c1; e2 = c2; e3 = c3; }
        else {
            int s = csr[o0 + j];
            float4 ev = ((const float4*)es)[s];
            e0 = lrelu(ev.x + edv.x); e1 = lrelu(ev.y + edv.y);
            e2 = lrelu(ev.z + edv.z); e3 = lrelu(ev.w + edv.w);
        }
        e0 = __expf(e0 - m0); e1 = __expf(e1 - m1);
        e2 = __expf(e2 - m2); e3 = __expf(e3 - m3);
        if (j < 16) { c0 = e0; c1 = e1; c2 = e2; c3 = e3; }
        t0 += e0; t1 += e1; t2 += e2; t3 += e3;
    }
    t0 = red16_sum(t0); t1 = red16_sum(t1); t2 = red16_sum(t2); t3 = red16_sum(t3);
    float i0 = t0 > 0.f ? 1.f / t0 : 0.f;
    float i1 = t1 > 0.f ? 1.f / t1 : 0.f;
    float i2 = t2 > 0.f ? 1.f / t2 : 0.f;
    float i3 = t3 > 0.f ? 1.f / t3 : 0.f;

    float a00 = 0, a01 = 0, a02 = 0, a10 = 0, a11 = 0, a12 = 0;
    float a20 = 0, a21 = 0, a22 = 0, a30 = 0, a31 = 0, a32 = 0;
    for (int j = l; j < deg; j += 16) {
        float e0, e1, e2, e3; int s;
        if (j < 16) { s = s_cache; e0 = c0; e1 = c1; e2 = c2; e3 = c3; }
        else {
            s = csr[o0 + j];
            float4 ev = ((const float4*)es)[s];
            e0 = __expf(lrelu(ev.x + edv.x) - m0);
            e1 = __expf(lrelu(ev.y + edv.y) - m1);
            e2 = __expf(lrelu(ev.z + edv.z) - m2);
            e3 = __expf(lrelu(ev.w + edv.w) - m3);
        }
        float xv0 = x[s * 3], xv1 = x[s * 3 + 1], xv2 = x[s * 3 + 2];
        a00 += e0 * xv0; a01 += e0 * xv1; a02 += e0 * xv2;
        a10 += e1 * xv0; a11 += e1 * xv1; a12 += e1 * xv2;
        a20 += e2 * xv0; a21 += e2 * xv1; a22 += e2 * xv2;
        a30 += e3 * xv0; a31 += e3 * xv1; a32 += e3 * xv2;
    }
    a00 = red16_sum(a00) * i0; a01 = red16_sum(a01) * i0; a02 = red16_sum(a02) * i0;
    a10 = red16_sum(a10) * i1; a11 = red16_sum(a11) * i1; a12 = red16_sum(a12) * i1;
    a20 = red16_sum(a20) * i2; a21 = red16_sum(a21) * i2; a22 = red16_sum(a22) * i2;
    a30 = red16_sum(a30) * i3; a31 = red16_sum(a31) * i3; a32 = red16_sum(a32) * i3;

    if (!active) return;

    const float4* W1f = (const float4*)W1;
    float4 r = make_float4(0.f, 0.f, 0.f, 0.f);
    float ah[4][3] = {{a00, a01, a02}, {a10, a11, a12}, {a20, a21, a22}, {a30, a31, a32}};
#pragma unroll
    for (int k = 0; k < 3; k++) {
#pragma unroll
        for (int h = 0; h < 4; h++) {
            float4 wv = W1f[k * 64 + h * 16 + l];
            float a = ah[h][k];
            r.x += a * wv.x; r.y += a * wv.y; r.z += a * wv.z; r.w += a * wv.w;
        }
    }
    float4 bv = ((const float4*)b1)[l];
    float4 hv;
    hv.x = fmaxf(0.25f * r.x + bv.x, 0.f);
    hv.y = fmaxf(0.25f * r.y + bv.y, 0.f);
    hv.z = fmaxf(0.25f * r.z + bv.z, 0.f);
    hv.w = fmaxf(0.25f * r.w + bv.w, 0.f);
    ((float4*)hout)[(size_t)wid * 16 + l] = hv;

    const float4* qsf = (const float4*)qs;
    const float4* qdf = (const float4*)qd;
    float ps[4], pd[4];
#pragma unroll
    for (int h = 0; h < 4; h++) {
        float4 q = qsf[h * 16 + l];
        ps[h] = red16_sum(hv.x * q.x + hv.y * q.y + hv.z * q.z + hv.w * q.w);
        float4 p = qdf[h * 16 + l];
        pd[h] = red16_sum(hv.x * p.x + hv.y * p.y + hv.z * p.z + hv.w * p.w);
    }
    if (l == 0) {
        ((float4*)es2)[wid] = make_float4(ps[0], ps[1], ps[2], ps[3]);
        ((float4*)ed2)[wid] = make_float4(pd[0], pd[1], pd[2], pd[3]);
    }
}

// ======================= layer 2: phase-A 16-lane softmax -> LDS, phase-B wave gather =======================
// writes agg in bf16 (consumed by MFMA k_out2)
#define NS 16
__global__ void k_agg2(const int* __restrict__ off, const int* __restrict__ csr,
                       const float* __restrict__ es, const float* __restrict__ ed,
                       const float* __restrict__ hout, unsigned short* __restrict__ aggb,
                       int N) {
    __shared__ float exl[NS * 64 * 4];
    __shared__ int   sl[NS * 64];
    __shared__ float minv[NS * 8];
    __shared__ int   meta[NS * 2];

    for (int i = threadIdx.x; i < NS * 64; i += 256) {
        ((float4*)exl)[i] = make_float4(0.f, 0.f, 0.f, 0.f);
        sl[i] = 0;
    }
    __syncthreads();

    int l = threadIdx.x & 15;
    int slot = threadIdx.x >> 4;
    int wid = blockIdx.x * NS + slot;
    bool active = wid < N;
    int o0 = 0, deg = 0;
    float4 edv = make_float4(0.f, 0.f, 0.f, 0.f);
    if (active) {
        o0 = off[wid];
        deg = off[wid + 1] - o0;
        edv = ((const float4*)ed)[wid];
    }

    float m0 = -INFINITY, m1 = -INFINITY, m2 = -INFINITY, m3 = -INFINITY;
    int s_cache = 0;
    float c0 = 0.f, c1 = 0.f, c2 = 0.f, c3 = 0.f;
    for (int j = l; j < deg; j += 16) {
        int s = csr[o0 + j];
        float4 ev = ((const float4*)es)[s];
        float e0 = lrelu(ev.x + edv.x), e1 = lrelu(ev.y + edv.y);
        float e2 = lrelu(ev.z + edv.z), e3 = lrelu(ev.w + edv.w);
        if (j < 16) { s_cache = s; c0 = e0; c1 = e1; c2 = e2; c3 = e3; }
        m0 = fmaxf(m0, e0); m1 = fmaxf(m1, e1);
        m2 = fmaxf(m2, e2); m3 = fmaxf(m3, e3);
    }
    m0 = red16_max(m0); m1 = red16_max(m1); m2 = red16_max(m2); m3 = red16_max(m3);

    float t0 = 0.f, t1 = 0.f, t2 = 0.f, t3 = 0.f;
    for (int j = l; j < deg; j += 16) {
        float e0, e1, e2, e3; int s;
        if (j < 16) { s = s_cache; e0 = c0; e1 = c1; e2 = c2; e3 = c3; }
        else {
            s = csr[o0 + j];
            float4 ev = ((const float4*)es)[s];
            e0 = lrelu(ev.x + edv.x); e1 = lrelu(ev.y + edv.y);
            e2 = lrelu(ev.z + edv.z); e3 = lrelu(ev.w + edv.w);
        }
        e0 = __expf(e0 - m0); e1 = __expf(e1 - m1);
        e2 = __expf(e2 - m2); e3 = __expf(e3 - m3);
        if (j < 64) {
            ((float4*)exl)[slot * 64 + j] = make_float4(e0, e1, e2, e3);
            sl[slot * 64 + j] = s;
        }
        t0 += e0; t1 += e1; t2 += e2; t3 += e3;
    }
    t0 = red16_sum(t0); t1 = red16_sum(t1); t2 = red16_sum(t2); t3 = red16_sum(t3);
    if (l == 0) {
        minv[slot * 8 + 0] = m0; minv[slot * 8 + 1] = m1;
        minv[slot * 8 + 2] = m2; minv[slot * 8 + 3] = m3;
        minv[slot * 8 + 4] = t0 > 0.f ? 1.f / t0 : 0.f;
        minv[slot * 8 + 5] = t1 > 0.f ? 1.f / t1 : 0.f;
        minv[slot * 8 + 6] = t2 > 0.f ? 1.f / t2 : 0.f;
        minv[slot * 8 + 7] = t3 > 0.f ? 1.f / t3 : 0.f;
        meta[slot * 2 + 0] = o0;
        meta[slot * 2 + 1] = deg;
    }
    __syncthreads();

    int lane = threadIdx.x & 63;
    int w = threadIdx.x >> 6;
    for (int sidx = 0; sidx < 4; sidx++) {
        int slot2 = w * 4 + sidx;
        int nd = blockIdx.x * NS + slot2;
        if (nd >= N) continue;
        int o0b = meta[slot2 * 2 + 0], degb = meta[slot2 * 2 + 1];
        float mm0 = minv[slot2 * 8 + 0], mm1 = minv[slot2 * 8 + 1];
        float mm2 = minv[slot2 * 8 + 2], mm3 = minv[slot2 * 8 + 3];
        float iv0 = minv[slot2 * 8 + 4], iv1 = minv[slot2 * 8 + 5];
        float iv2 = minv[slot2 * 8 + 6], iv3 = minv[slot2 * 8 + 7];

        float acc0 = 0.f, acc1 = 0.f, acc2 = 0.f, acc3 = 0.f;
        const float4* EX = ((const float4*)exl) + slot2 * 64;
        const int* S = sl + slot2 * 64;
        int dmain = degb < 64 ? degb : 64;
        int d4 = (dmain + 3) & ~3;
        for (int j = 0; j < d4; j += 4) {
            float4 a0 = EX[j], a1 = EX[j + 1], a2 = EX[j + 2], a3 = EX[j + 3];
            int s0 = S[j], s1 = S[j + 1], s2 = S[j + 2], s3 = S[j + 3];
            float v0 = hout[(size_t)s0 * 64 + lane];
            float v1 = hout[(size_t)s1 * 64 + lane];
            float v2 = hout[(size_t)s2 * 64 + lane];
            float v3 = hout[(size_t)s3 * 64 + lane];
            acc0 += a0.x * v0 + a1.x * v1 + a2.x * v2 + a3.x * v3;
            acc1 += a0.y * v0 + a1.y * v1 + a2.y * v2 + a3.y * v3;
            acc2 += a0.z * v0 + a1.z * v1 + a2.z * v2 + a3.z * v3;
            acc3 += a0.w * v0 + a1.w * v1 + a2.w * v2 + a3.w * v3;
        }
        if (degb > 64) {
            float4 edv2 = ((const float4*)ed)[nd];
            for (int j = 64; j < degb; j++) {
                int s = csr[o0b + j];
                float4 ev = ((const float4*)es)[s];
                float e0 = __expf(lrelu(ev.x + edv2.x) - mm0);
                float e1 = __expf(lrelu(ev.y + edv2.y) - mm1);
                float e2 = __expf(lrelu(ev.z + edv2.z) - mm2);
                float e3 = __expf(lrelu(ev.w + edv2.w) - mm3);
                float v = hout[(size_t)s * 64 + lane];
                acc0 += e0 * v; acc1 += e1 * v; acc2 += e2 * v; acc3 += e3 * v;
            }
        }
        size_t b = (size_t)nd * 256;
        aggb[b + lane]        = bf16r(acc0 * iv0);
        aggb[b + 64 + lane]   = bf16r(acc1 * iv1);
        aggb[b + 128 + lane]  = bf16r(acc2 * iv2);
        aggb[b + 192 + lane]  = bf16r(acc3 * iv3);
    }
}

// ======================= layer 2 output transform: bf16 MFMA =======================
// out[n,c] = relu(0.25 * sum_kh A[n][kh]*B[kh][c] + b2[c]); A=aggb[N,256], B=W2bt^T.
// Wave = 16 nodes x 64 channels; block = 4 waves = 64 nodes. 8 K-chunks x 4 col-tiles.
__global__ void k_out2(const unsigned short* __restrict__ aggb,
                       const unsigned short* __restrict__ W2bt,
                       const float* __restrict__ b2, float* __restrict__ hout2, int N) {
    int w = threadIdx.x >> 6, lane = threadIdx.x & 63;
    int nodeBase = blockIdx.x * 64 + w * 16;
    int m = lane & 15;        // A row (node) / B-D col (channel)
    int quad = lane >> 4;     // k-subblock selector; D row = quad*4+reg
    const short* A = (const short*)aggb + (size_t)(nodeBase + m) * 256 + quad * 8;
    const short* B = (const short*)W2bt;

    f32x4 acc0 = {0.f, 0.f, 0.f, 0.f}, acc1 = {0.f, 0.f, 0.f, 0.f};
    f32x4 acc2 = {0.f, 0.f, 0.f, 0.f}, acc3 = {0.f, 0.f, 0.f, 0.f};
#pragma unroll
    for (int kk = 0; kk < 8; kk++) {
        short8 af = *(const short8*)(A + kk * 32);
        short8 b0 = *(const short8*)(B + (size_t)(0 * 16 + m) * 256 + kk * 32 + quad * 8);
        short8 b1v = *(const short8*)(B + (size_t)(1 * 16 + m) * 256 + kk * 32 + quad * 8);
        short8 b2v = *(const short8*)(B + (size_t)(2 * 16 + m) * 256 + kk * 32 + quad * 8);
        short8 b3v = *(const short8*)(B + (size_t)(3 * 16 + m) * 256 + kk * 32 + quad * 8);
        acc0 = __builtin_amdgcn_mfma_f32_16x16x32_bf16(af, b0, acc0, 0, 0, 0);
        acc1 = __builtin_amdgcn_mfma_f32_16x16x32_bf16(af, b1v, acc1, 0, 0, 0);
        acc2 = __builtin_amdgcn_mfma_f32_16x16x32_bf16(af, b2v, acc2, 0, 0, 0);
        acc3 = __builtin_amdgcn_mfma_f32_16x16x32_bf16(af, b3v, acc3, 0, 0, 0);
    }
    f32x4 accs[4] = {acc0, acc1, acc2, acc3};
#pragma unroll
    for (int cb = 0; cb < 4; cb++) {
        int c = cb * 16 + m;
        float bv = b2[c];
#pragma unroll
        for (int r = 0; r < 4; r++) {
            int node = nodeBase + quad * 4 + r;
            if (node < N) {
                float v = 0.25f * accs[cb][r] + bv;
                hout2[(size_t)node * 64 + c] = fmaxf(v, 0.f);
            }
        }
    }
}

// ======================= global add pool (wide) =======================
__global__ void k_pzero(float* __restrict__ out, int total) {
    int i = blockIdx.x * blockDim.x + threadIdx.x;
    if (i < total) out[i] = 0.f;
}

__global__ void k_pool(const float* __restrict__ h2, const int* __restrict__ batch,
                       float* __restrict__ out, int N, int G) {
    int tid = blockIdx.x * blockDim.x + threadIdx.x;
    int c4 = tid & 15;
    int grp = tid >> 4;
    int ngroups = (gridDim.x * blockDim.x) >> 4;
    int chunk = (N + ngroups - 1) / ngroups;
    int n0 = grp * chunk;
    int n1 = n0 + chunk; if (n1 > N) n1 = N;
    if (n0 >= N) return;

    int curg = -1;
    float4 acc = make_float4(0.f, 0.f, 0.f, 0.f);
    for (int n = n0; n < n1; n++) {
        int g = batch[n];
        if (g != curg) {
            if (curg >= 0) {
                float* o = out + curg * 64 + c4 * 4;
                atomicAdd(o + 0, acc.x); atomicAdd(o + 1, acc.y);
                atomicAdd(o + 2, acc.z); atomicAdd(o + 3, acc.w);
            }
            curg = g;
            acc = make_float4(0.f, 0.f, 0.f, 0.f);
        }
        float4 v = ((const float4*)h2)[(size_t)n * 16 + c4];
        acc.x += v.x; acc.y += v.y; acc.z += v.z; acc.w += v.w;
    }
    if (curg >= 0) {
        float* o = out + curg * 64 + c4 * 4;
        atomicAdd(o + 0, acc.x); atomicAdd(o + 1, acc.y);
        atomicAdd(o + 2, acc.z); atomicAdd(o + 3, acc.w);
    }
}

extern "C" void kernel_launch(void* const* d_in, const int* in_sizes, int n_in,
                              void* d_out, int out_size, void* d_ws, size_t ws_size,
                              hipStream_t stream) {
    const float* x   = (const float*)d_in[0];
    const int*   ei  = (const int*)d_in[1];
    const int*   bat = (const int*)d_in[2];
    const float* W1  = (const float*)d_in[3];
    const float* as1 = (const float*)d_in[4];
    const float* ad1 = (const float*)d_in[5];
    const float* b1  = (const float*)d_in[6];
    const float* W2  = (const float*)d_in[7];
    const float* as2 = (const float*)d_in[8];
    const float* ad2 = (const float*)d_in[9];
    const float* b2  = (const float*)d_in[10];
    float* out = (float*)d_out;

    int N = in_sizes[0] / 3;
    int E = in_sizes[1] / 2;
    int G = out_size / 64;
    const int* srcI = ei;
    const int* dstI = ei + E;
    int NBUCK = (N + BWIDTH - 1) >> BSHIFT;

    // ---- workspace layout ----
    float* fw = (float*)d_ws;
    size_t fo = 0;
    unsigned short* aggb = (unsigned short*)fw; fo += (size_t)N * 128;  // N*256 bf16
    float* hout  = fw + fo; fo += (size_t)N * 64;
    float* hout2 = fw + fo; fo += (size_t)N * 64;
    float* esA   = fw + fo; fo += (size_t)N * 4;
    float* edA   = fw + fo; fo += (size_t)N * 4;
    float* esB   = fw + fo; fo += (size_t)N * 4;
    float* edB   = fw + fo; fo += (size_t)N * 4;
    float* p1s   = fw + fo; fo += 64;
    float* p1d   = fw + fo; fo += 64;
    float* qs    = fw + fo; fo += 256;
    float* qd    = fw + fo; fo += 256;
    unsigned short* W2bt = (unsigned short*)(fw + fo); fo += 64 * 256 / 2;  // 16384 bf16
    int* iw = (int*)(fw + fo);
    size_t io = 0;
    uint2* pairs = (uint2*)iw; io += (size_t)2 * E;
    int* csr    = iw + io; io += E;
    int* off    = iw + io; io += N + 1;
    int* bbase  = iw + io; io += 1025;
    int* gcur   = iw + io; io += 1024;
    int* bcnt   = iw + io; io += 1024;

    int nThrBlk = (N + 255) / 256;
    int nGrpBlk = (N + 15) / 16;

    // ---- CSR build: two-level counting sort ----
    k_binit<<<1, 1024, 0, stream>>>(bcnt, NBUCK);
    k_bhist<<<256, 256, 0, stream>>>(dstI, bcnt, E, NBUCK);
    k_bscan<<<1, 1024, 0, stream>>>(bcnt, bbase, gcur, off, NBUCK, N, E);
    k_bdist<<<(E + DCHUNK - 1) / DCHUNK, 256, 0, stream>>>(srcI, dstI, gcur, pairs, E, NBUCK);
    k_bcsr<<<NBUCK, 256, 0, stream>>>(pairs, bbase, off, csr, N);

    // ---- precompute attention projections + bf16 W2 ----
    k_prep<<<(3 * 8 * 64 + 255) / 256, 256, 0, stream>>>(W1, as1, ad1, p1s, p1d, 3);
    k_prep<<<(64 * 8 * 64 + 255) / 256, 256, 0, stream>>>(W2, as2, ad2, qs, qd, 64);
    k_w2bt<<<64, 256, 0, stream>>>(W2, W2bt);

    // ---- layer 1 (writes hout + layer-2 es/ed) ----
    k_esed1<<<nThrBlk, 256, 0, stream>>>(x, p1s, p1d, esA, edA, N);
    k_agg1<<<nGrpBlk, 256, 0, stream>>>(off, csr, esA, edA, x, W1, b1, qs, qd,
                                        hout, esB, edB, N);

    // ---- layer 2 ----
    k_agg2<<<nGrpBlk, 256, 0, stream>>>(off, csr, esB, edB, hout, aggb, N);
    k_out2<<<(N + 63) / 64, 256, 0, stream>>>(aggb, W2bt, b2, hout2, N);

    // ---- pool ----
    k_pzero<<<(G * 64 + 255) / 256, 256, 0, stream>>>(out, G * 64);
    k_pool<<<512, 256, 0, stream>>>(hout2, bat, out, N, G);
}

// Round 9
// 265.949 us; speedup vs baseline: 8.7362x; 1.2765x over previous
//
#include <hip/hip_runtime.h>
#include <math.h>

#define HEADS 4
#define HID 64
#define BSHIFT 7          // 128 nodes per bucket
#define BWIDTH 128
#define CCAP 4096         // LDS csr-staging capacity (edges/bucket mean ~2047)
#define DCHUNK 8192       // edges per k_bdist block (8 per thread, 1024 threads)

typedef __attribute__((ext_vector_type(8))) short short8;
typedef __attribute__((ext_vector_type(4))) float f32x4;

__device__ __forceinline__ float lrelu(float x) { return x > 0.f ? x : 0.2f * x; }

__device__ __forceinline__ unsigned short bf16r(float f) {
    unsigned u = __float_as_uint(f);
    unsigned r = (u + 0x7FFFu + ((u >> 16) & 1u)) >> 16;
    return (unsigned short)r;
}
__device__ __forceinline__ float bf2f(unsigned short u) {
    return __uint_as_float(((unsigned)u) << 16);
}

__device__ __forceinline__ float wred_sum(float v) {
#pragma unroll
    for (int o = 32; o > 0; o >>= 1) v += __shfl_xor(v, o);
    return v;
}
__device__ __forceinline__ float red16_sum(float v) {
#pragma unroll
    for (int o = 8; o > 0; o >>= 1) v += __shfl_xor(v, o);
    return v;
}
__device__ __forceinline__ float red16_max(float v) {
#pragma unroll
    for (int o = 8; o > 0; o >>= 1) v = fmaxf(v, __shfl_xor(v, o));
    return v;
}

// ======================= CSR build: two-level LDS counting sort =======================
__global__ void k_binit(int* __restrict__ bcnt, int NBUCK) {
    int i = threadIdx.x;
    if (i < NBUCK) bcnt[i] = 0;
}

__global__ void k_bhist(const int* __restrict__ dstI, int* __restrict__ bcnt,
                        int E, int NBUCK) {
    __shared__ int h[1024];
    for (int i = threadIdx.x; i < NBUCK; i += 256) h[i] = 0;
    __syncthreads();
    int stride = gridDim.x * 256;
    for (int e = blockIdx.x * 256 + threadIdx.x; e < E; e += stride)
        atomicAdd(&h[dstI[e] >> BSHIFT], 1);
    __syncthreads();
    for (int i = threadIdx.x; i < NBUCK; i += 256)
        if (h[i]) atomicAdd(&bcnt[i], h[i]);
}

// single block, 1024 threads: exclusive scan of bucket counts
__global__ void k_bscan(const int* __restrict__ bcnt, int* __restrict__ bbase,
                        int* __restrict__ gcur, int* __restrict__ off,
                        int NBUCK, int N, int E) {
    __shared__ int lds[1024];
    int t = threadIdx.x;
    int v = (t < NBUCK) ? bcnt[t] : 0;
    lds[t] = v;
    __syncthreads();
    for (int s = 1; s < 1024; s <<= 1) {
        int u = (t >= s) ? lds[t - s] : 0;
        __syncthreads();
        lds[t] += u;
        __syncthreads();
    }
    if (t < NBUCK) {
        int b = lds[t] - v;
        bbase[t] = b;
        gcur[t] = b;
    }
    if (t == 0) { bbase[NBUCK] = E; off[N] = E; }
}

// distribute edges into bucket regions as (src,dst) pairs; 1024 threads/block
__global__ void k_bdist(const int* __restrict__ srcI, const int* __restrict__ dstI,
                        int* __restrict__ gcur, uint2* __restrict__ pairs,
                        int E, int NBUCK) {
    __shared__ int h[1024];
    __shared__ int cur[1024];
    for (int i = threadIdx.x; i < NBUCK; i += 1024) h[i] = 0;
    __syncthreads();
    int base = blockIdx.x * DCHUNK;
    int sr[8], dr[8];
#pragma unroll
    for (int k = 0; k < 8; k++) {
        int e = base + threadIdx.x + k * 1024;
        if (e < E) {
            sr[k] = srcI[e];
            dr[k] = dstI[e];
            atomicAdd(&h[dr[k] >> BSHIFT], 1);
        } else dr[k] = -1;
    }
    __syncthreads();
    for (int i = threadIdx.x; i < NBUCK; i += 1024)
        cur[i] = h[i] ? atomicAdd(&gcur[i], h[i]) : 0;
    __syncthreads();
#pragma unroll
    for (int k = 0; k < 8; k++) {
        if (dr[k] >= 0) {
            int b = dr[k] >> BSHIFT;
            int p = atomicAdd(&cur[b], 1);
            pairs[p] = make_uint2((unsigned)sr[k], (unsigned)dr[k]);
        }
    }
}

// one block per bucket: local degrees -> off[], LDS-cursor distribute -> coalesced csr
__global__ void k_bcsr(const uint2* __restrict__ pairs, const int* __restrict__ bbase,
                       int* __restrict__ off, int* __restrict__ csr, int N) {
    __shared__ int cnt[BWIDTH];
    __shared__ int scan[BWIDTH];
    __shared__ int cur[BWIDTH];
    __shared__ int stage[CCAP];
    int b = blockIdx.x;
    int nodeBase = b << BSHIFT;
    int nNodes = N - nodeBase;
    if (nNodes > BWIDTH) nNodes = BWIDTH;
    int e0 = bbase[b], e1 = bbase[b + 1];
    int ecnt = e1 - e0;
    if (threadIdx.x < BWIDTH) cnt[threadIdx.x] = 0;
    __syncthreads();
    for (int i = threadIdx.x; i < ecnt; i += 256)
        atomicAdd(&cnt[pairs[e0 + i].y - (unsigned)nodeBase], 1);
    __syncthreads();
    if (threadIdx.x < BWIDTH)
        scan[threadIdx.x] = (threadIdx.x < nNodes) ? cnt[threadIdx.x] : 0;
    __syncthreads();
    for (int s = 1; s < BWIDTH; s <<= 1) {
        int u = 0;
        if (threadIdx.x < BWIDTH && threadIdx.x >= s) u = scan[threadIdx.x - s];
        __syncthreads();
        if (threadIdx.x < BWIDTH) scan[threadIdx.x] += u;
        __syncthreads();
    }
    if (threadIdx.x < nNodes) {
        int ex = scan[threadIdx.x] - cnt[threadIdx.x];   // exclusive
        off[nodeBase + threadIdx.x] = e0 + ex;
        cur[threadIdx.x] = ex;
    }
    __syncthreads();
    for (int i = threadIdx.x; i < ecnt; i += 256) {
        uint2 pr = pairs[e0 + i];
        int l = atomicAdd(&cur[pr.y - (unsigned)nodeBase], 1);
        if (l < CCAP) stage[l] = (int)pr.x;
        else csr[e0 + l] = (int)pr.x;   // overflow fallback
    }
    __syncthreads();
    int lim = ecnt < CCAP ? ecnt : CCAP;
    for (int i = threadIdx.x; i < lim; i += 256) csr[e0 + i] = stage[i];
}

// ======================= attention-coefficient precompute =======================
__global__ void k_prep(const float* __restrict__ W, const float* __restrict__ asrc,
                       const float* __restrict__ adst, float* __restrict__ p_src,
                       float* __restrict__ p_dst, int K) {
    int wid = (blockIdx.x * blockDim.x + threadIdx.x) >> 6;
    int lane = threadIdx.x & 63;
    int total = K * 4 * 2;
    if (wid >= total) return;
    int which = wid / (K * 4);
    int hk = wid % (K * 4);
    int h = hk / K, k = hk % K;
    const float* a = which ? adst : asrc;
    float v = W[(size_t)k * 256 + h * 64 + lane] * a[h * 64 + lane];
    v = wred_sum(v);
    if (lane == 0) (which ? p_dst : p_src)[h * K + k] = v;
}

// W2 -> bf16, transposed: W2bt[c*256 + h*64 + kf] = bf16(W2[kf*256 + h*64 + c])
__global__ void k_w2bt(const float* __restrict__ W2, unsigned short* __restrict__ W2bt) {
    int i = blockIdx.x * 256 + threadIdx.x;   // i = c*256 + kh
    int c = i >> 8, kh = i & 255;
    int h = kh >> 6, kf = kh & 63;
    W2bt[i] = bf16r(W2[kf * 256 + h * 64 + c]);
}

// es[n,h] = sum_k x[n,k] * ps[h*3+k]  (layer 1)
__global__ void k_esed1(const float* __restrict__ x, const float* __restrict__ ps,
                        const float* __restrict__ pd, float* __restrict__ es,
                        float* __restrict__ ed, int N) {
    int n = blockIdx.x * blockDim.x + threadIdx.x;
    if (n >= N) return;
    float x0 = x[n * 3], x1 = x[n * 3 + 1], x2 = x[n * 3 + 2];
    float4 s, d;
    s.x = x0 * ps[0] + x1 * ps[1] + x2 * ps[2];
    s.y = x0 * ps[3] + x1 * ps[4] + x2 * ps[5];
    s.z = x0 * ps[6] + x1 * ps[7] + x2 * ps[8];
    s.w = x0 * ps[9] + x1 * ps[10] + x2 * ps[11];
    d.x = x0 * pd[0] + x1 * pd[1] + x2 * pd[2];
    d.y = x0 * pd[3] + x1 * pd[4] + x2 * pd[5];
    d.z = x0 * pd[6] + x1 * pd[7] + x2 * pd[8];
    d.w = x0 * pd[9] + x1 * pd[10] + x2 * pd[11];
    ((float4*)es)[n] = s;
    ((float4*)ed)[n] = d;
}

// ======================= layer 1: 16-lane group per node (bf16 hout) =======================
__global__ void k_agg1(const int* __restrict__ off, const int* __restrict__ csr,
                       const float* __restrict__ es, const float* __restrict__ ed,
                       const float* __restrict__ x, const float* __restrict__ W1,
                       const float* __restrict__ b1, const float* __restrict__ qs,
                       const float* __restrict__ qd, unsigned short* __restrict__ houtb,
                       float* __restrict__ es2, float* __restrict__ ed2, int N) {
    int grp = (blockIdx.x * blockDim.x + threadIdx.x) >> 4;
    int l = threadIdx.x & 15;
    int wid = grp;
    bool active = wid < N;
    int o0 = 0, deg = 0;
    float4 edv = make_float4(0.f, 0.f, 0.f, 0.f);
    if (active) {
        o0 = off[wid];
        deg = off[wid + 1] - o0;
        edv = ((const float4*)ed)[wid];
    }

    float m0 = -INFINITY, m1 = -INFINITY, m2 = -INFINITY, m3 = -INFINITY;
    int s_cache = 0;
    float c0 = 0.f, c1 = 0.f, c2 = 0.f, c3 = 0.f;
    for (int j = l; j < deg; j += 16) {
        int s = csr[o0 + j];
        float4 ev = ((const float4*)es)[s];
        float e0 = lrelu(ev.x + edv.x), e1 = lrelu(ev.y + edv.y);
        float e2 = lrelu(ev.z + edv.z), e3 = lrelu(ev.w + edv.w);
        if (j < 16) { s_cache = s; c0 = e0; c1 = e1; c2 = e2; c3 = e3; }
        m0 = fmaxf(m0, e0); m1 = fmaxf(m1, e1);
        m2 = fmaxf(m2, e2); m3 = fmaxf(m3, e3);
    }
    m0 = red16_max(m0); m1 = red16_max(m1); m2 = red16_max(m2); m3 = red16_max(m3);

    float t0 = 0.f, t1 = 0.f, t2 = 0.f, t3 = 0.f;
    for (int j = l; j < deg; j += 16) {
        float e0, e1, e2, e3;
        if (j < 16) { e0 = c0; e1 = c1; e2 = c2; e3 = c3; }
        else {
            int s = csr[o0 + j];
            float4 ev = ((const float4*)es)[s];
            e0 = lrelu(ev.x + edv.x); e1 = lrelu(ev.y + edv.y);
            e2 = lrelu(ev.z + edv.z); e3 = lrelu(ev.w + edv.w);
        }
        e0 = __expf(e0 - m0); e1 = __expf(e1 - m1);
        e2 = __expf(e2 - m2); e3 = __expf(e3 - m3);
        if (j < 16) { c0 = e0; c1 = e1; c2 = e2; c3 = e3; }
        t0 += e0; t1 += e1; t2 += e2; t3 += e3;
    }
    t0 = red16_sum(t0); t1 = red16_sum(t1); t2 = red16_sum(t2); t3 = red16_sum(t3);
    float i0 = t0 > 0.f ? 1.f / t0 : 0.f;
    float i1 = t1 > 0.f ? 1.f / t1 : 0.f;
    float i2 = t2 > 0.f ? 1.f / t2 : 0.f;
    float i3 = t3 > 0.f ? 1.f / t3 : 0.f;

    float a00 = 0, a01 = 0, a02 = 0, a10 = 0, a11 = 0, a12 = 0;
    float a20 = 0, a21 = 0, a22 = 0, a30 = 0, a31 = 0, a32 = 0;
    for (int j = l; j < deg; j += 16) {
        float e0, e1, e2, e3; int s;
        if (j < 16) { s = s_cache; e0 = c0; e1 = c1; e2 = c2; e3 = c3; }
        else {
            s = csr[o0 + j];
            float4 ev = ((const float4*)es)[s];
            e0 = __expf(lrelu(ev.x + edv.x) - m0);
            e1 = __expf(lrelu(ev.y + edv.y) - m1);
            e2 = __expf(lrelu(ev.z + edv.z) - m2);
            e3 = __expf(lrelu(ev.w + edv.w) - m3);
        }
        float xv0 = x[s * 3], xv1 = x[s * 3 + 1], xv2 = x[s * 3 + 2];
        a00 += e0 * xv0; a01 += e0 * xv1; a02 += e0 * xv2;
        a10 += e1 * xv0; a11 += e1 * xv1; a12 += e1 * xv2;
        a20 += e2 * xv0; a21 += e2 * xv1; a22 += e2 * xv2;
        a30 += e3 * xv0; a31 += e3 * xv1; a32 += e3 * xv2;
    }
    a00 = red16_sum(a00) * i0; a01 = red16_sum(a01) * i0; a02 = red16_sum(a02) * i0;
    a10 = red16_sum(a10) * i1; a11 = red16_sum(a11) * i1; a12 = red16_sum(a12) * i1;
    a20 = red16_sum(a20) * i2; a21 = red16_sum(a21) * i2; a22 = red16_sum(a22) * i2;
    a30 = red16_sum(a30) * i3; a31 = red16_sum(a31) * i3; a32 = red16_sum(a32) * i3;

    if (!active) return;

    const float4* W1f = (const float4*)W1;
    float4 r = make_float4(0.f, 0.f, 0.f, 0.f);
    float ah[4][3] = {{a00, a01, a02}, {a10, a11, a12}, {a20, a21, a22}, {a30, a31, a32}};
#pragma unroll
    for (int k = 0; k < 3; k++) {
#pragma unroll
        for (int h = 0; h < 4; h++) {
            float4 wv = W1f[k * 64 + h * 16 + l];
            float a = ah[h][k];
            r.x += a * wv.x; r.y += a * wv.y; r.z += a * wv.z; r.w += a * wv.w;
        }
    }
    float4 bv = ((const float4*)b1)[l];
    float4 hv;
    hv.x = fmaxf(0.25f * r.x + bv.x, 0.f);
    hv.y = fmaxf(0.25f * r.y + bv.y, 0.f);
    hv.z = fmaxf(0.25f * r.z + bv.z, 0.f);
    hv.w = fmaxf(0.25f * r.w + bv.w, 0.f);
    ((ushort4*)houtb)[(size_t)wid * 16 + l] =
        make_ushort4(bf16r(hv.x), bf16r(hv.y), bf16r(hv.z), bf16r(hv.w));

    const float4* qsf = (const float4*)qs;
    const float4* qdf = (const float4*)qd;
    float ps[4], pd[4];
#pragma unroll
    for (int h = 0; h < 4; h++) {
        float4 q = qsf[h * 16 + l];
        ps[h] = red16_sum(hv.x * q.x + hv.y * q.y + hv.z * q.z + hv.w * q.w);
        float4 p = qdf[h * 16 + l];
        pd[h] = red16_sum(hv.x * p.x + hv.y * p.y + hv.z * p.z + hv.w * p.w);
    }
    if (l == 0) {
        ((float4*)es2)[wid] = make_float4(ps[0], ps[1], ps[2], ps[3]);
        ((float4*)ed2)[wid] = make_float4(pd[0], pd[1], pd[2], pd[3]);
    }
}

// ======================= layer 2: phase-A 16-lane softmax -> LDS, phase-B wave gather =======================
// gathers bf16 hout; writes agg in bf16 (consumed by MFMA k_out2)
#define NS 16
__global__ void k_agg2(const int* __restrict__ off, const int* __restrict__ csr,
                       const float* __restrict__ es, const float* __restrict__ ed,
                       const unsigned short* __restrict__ houtb,
                       unsigned short* __restrict__ aggb, int N) {
    __shared__ float exl[NS * 64 * 4];
    __shared__ int   sl[NS * 64];
    __shared__ float minv[NS * 8];
    __shared__ int   meta[NS * 2];

    for (int i = threadIdx.x; i < NS * 64; i += 256) {
        ((float4*)exl)[i] = make_float4(0.f, 0.f, 0.f, 0.f);
        sl[i] = 0;
    }
    __syncthreads();

    int l = threadIdx.x & 15;
    int slot = threadIdx.x >> 4;
    int wid = blockIdx.x * NS + slot;
    bool active = wid < N;
    int o0 = 0, deg = 0;
    float4 edv = make_float4(0.f, 0.f, 0.f, 0.f);
    if (active) {
        o0 = off[wid];
        deg = off[wid + 1] - o0;
        edv = ((const float4*)ed)[wid];
    }

    float m0 = -INFINITY, m1 = -INFINITY, m2 = -INFINITY, m3 = -INFINITY;
    int s_cache = 0;
    float c0 = 0.f, c1 = 0.f, c2 = 0.f, c3 = 0.f;
    for (int j = l; j < deg; j += 16) {
        int s = csr[o0 + j];
        float4 ev = ((const float4*)es)[s];
        float e0 = lrelu(ev.x + edv.x), e1 = lrelu(ev.y + edv.y);
        float e2 = lrelu(ev.z + edv.z), e3 = lrelu(ev.w + edv.w);
        if (j < 16) { s_cache = s; c0 = e0; c1 = e1; c2 = e2; c3 = e3; }
        m0 = fmaxf(m0, e0); m1 = fmaxf(m1, e1);
        m2 = fmaxf(m2, e2); m3 = fmaxf(m3, e3);
    }
    m0 = red16_max(m0); m1 = red16_max(m1); m2 = red16_max(m2); m3 = red16_max(m3);

    float t0 = 0.f, t1 = 0.f, t2 = 0.f, t3 = 0.f;
    for (int j = l; j < deg; j += 16) {
        float e0, e1, e2, e3; int s;
        if (j < 16) { s = s_cache; e0 = c0; e1 = c1; e2 = c2; e3 = c3; }
        else {
            s = csr[o0 + j];
            float4 ev = ((const float4*)es)[s];
            e0 = lrelu(ev.x + edv.x); e1 = lrelu(ev.y + edv.y);
            e2 = lrelu(ev.z + edv.z); e3 = lrelu(ev.w + edv.w);
        }
        e0 = __expf(e0 - m0); e1 = __expf(e1 - m1);
        e2 = __expf(e2 - m2); e3 = __expf(e3 - m3);
        if (j < 64) {
            ((float4*)exl)[slot * 64 + j] = make_float4(e0, e1, e2, e3);
            sl[slot * 64 + j] = s;
        }
        t0 += e0; t1 += e1; t2 += e2; t3 += e3;
    }
    t0 = red16_sum(t0); t1 = red16_sum(t1); t2 = red16_sum(t2); t3 = red16_sum(t3);
    if (l == 0) {
        minv[slot * 8 + 0] = m0; minv[slot * 8 + 1] = m1;
        minv[slot * 8 + 2] = m2; minv[slot * 8 + 3] = m3;
        minv[slot * 8 + 4] = t0 > 0.f ? 1.f / t0 : 0.f;
        minv[slot * 8 + 5] = t1 > 0.f ? 1.f / t1 : 0.f;
        minv[slot * 8 + 6] = t2 > 0.f ? 1.f / t2 : 0.f;
        minv[slot * 8 + 7] = t3 > 0.f ? 1.f / t3 : 0.f;
        meta[slot * 2 + 0] = o0;
        meta[slot * 2 + 1] = deg;
    }
    __syncthreads();

    int lane = threadIdx.x & 63;
    int w = threadIdx.x >> 6;
    for (int sidx = 0; sidx < 4; sidx++) {
        int slot2 = w * 4 + sidx;
        int nd = blockIdx.x * NS + slot2;
        if (nd >= N) continue;
        int o0b = meta[slot2 * 2 + 0], degb = meta[slot2 * 2 + 1];
        float mm0 = minv[slot2 * 8 + 0], mm1 = minv[slot2 * 8 + 1];
        float mm2 = minv[slot2 * 8 + 2], mm3 = minv[slot2 * 8 + 3];
        float iv0 = minv[slot2 * 8 + 4], iv1 = minv[slot2 * 8 + 5];
        float iv2 = minv[slot2 * 8 + 6], iv3 = minv[slot2 * 8 + 7];

        float acc0 = 0.f, acc1 = 0.f, acc2 = 0.f, acc3 = 0.f;
        const float4* EX = ((const float4*)exl) + slot2 * 64;
        const int* S = sl + slot2 * 64;
        int dmain = degb < 64 ? degb : 64;
        int d4 = (dmain + 3) & ~3;
        for (int j = 0; j < d4; j += 4) {
            float4 a0 = EX[j], a1 = EX[j + 1], a2 = EX[j + 2], a3 = EX[j + 3];
            int s0 = S[j], s1 = S[j + 1], s2 = S[j + 2], s3 = S[j + 3];
            float v0 = bf2f(houtb[(size_t)s0 * 64 + lane]);
            float v1 = bf2f(houtb[(size_t)s1 * 64 + lane]);
            float v2 = bf2f(houtb[(size_t)s2 * 64 + lane]);
            float v3 = bf2f(houtb[(size_t)s3 * 64 + lane]);
            acc0 += a0.x * v0 + a1.x * v1 + a2.x * v2 + a3.x * v3;
            acc1 += a0.y * v0 + a1.y * v1 + a2.y * v2 + a3.y * v3;
            acc2 += a0.z * v0 + a1.z * v1 + a2.z * v2 + a3.z * v3;
            acc3 += a0.w * v0 + a1.w * v1 + a2.w * v2 + a3.w * v3;
        }
        if (degb > 64) {
            float4 edv2 = ((const float4*)ed)[nd];
            for (int j = 64; j < degb; j++) {
                int s = csr[o0b + j];
                float4 ev = ((const float4*)es)[s];
                float e0 = __expf(lrelu(ev.x + edv2.x) - mm0);
                float e1 = __expf(lrelu(ev.y + edv2.y) - mm1);
                float e2 = __expf(lrelu(ev.z + edv2.z) - mm2);
                float e3 = __expf(lrelu(ev.w + edv2.w) - mm3);
                float v = bf2f(houtb[(size_t)s * 64 + lane]);
                acc0 += e0 * v; acc1 += e1 * v; acc2 += e2 * v; acc3 += e3 * v;
            }
        }
        size_t b = (size_t)nd * 256;
        aggb[b + lane]        = bf16r(acc0 * iv0);
        aggb[b + 64 + lane]   = bf16r(acc1 * iv1);
        aggb[b + 128 + lane]  = bf16r(acc2 * iv2);
        aggb[b + 192 + lane]  = bf16r(acc3 * iv3);
    }
}

// ======================= layer 2 output transform (MFMA) + fused global-add-pool =======================
// Wave = 16 nodes x 64 channels; block = 4 waves = 64 nodes. Pool fused:
// batch sorted -> most waves see one graph (shuffle-reduce + 64 atomics/wave).
__global__ void k_out2(const unsigned short* __restrict__ aggb,
                       const unsigned short* __restrict__ W2bt,
                       const float* __restrict__ b2, const int* __restrict__ batch,
                       float* __restrict__ out, int N) {
    int w = threadIdx.x >> 6, lane = threadIdx.x & 63;
    int nodeBase = blockIdx.x * 64 + w * 16;
    int m = lane & 15;        // A row (node) / B-D col (channel)
    int quad = lane >> 4;     // k-subblock selector; D row = quad*4+reg
    const short* A = (const short*)aggb + (size_t)(nodeBase + m) * 256 + quad * 8;
    const short* B = (const short*)W2bt;

    f32x4 acc0 = {0.f, 0.f, 0.f, 0.f}, acc1 = {0.f, 0.f, 0.f, 0.f};
    f32x4 acc2 = {0.f, 0.f, 0.f, 0.f}, acc3 = {0.f, 0.f, 0.f, 0.f};
#pragma unroll
    for (int kk = 0; kk < 8; kk++) {
        short8 af = *(const short8*)(A + kk * 32);
        short8 b0 = *(const short8*)(B + (size_t)(0 * 16 + m) * 256 + kk * 32 + quad * 8);
        short8 b1v = *(const short8*)(B + (size_t)(1 * 16 + m) * 256 + kk * 32 + quad * 8);
        short8 b2v = *(const short8*)(B + (size_t)(2 * 16 + m) * 256 + kk * 32 + quad * 8);
        short8 b3v = *(const short8*)(B + (size_t)(3 * 16 + m) * 256 + kk * 32 + quad * 8);
        acc0 = __builtin_amdgcn_mfma_f32_16x16x32_bf16(af, b0, acc0, 0, 0, 0);
        acc1 = __builtin_amdgcn_mfma_f32_16x16x32_bf16(af, b1v, acc1, 0, 0, 0);
        acc2 = __builtin_amdgcn_mfma_f32_16x16x32_bf16(af, b2v, acc2, 0, 0, 0);
        acc3 = __builtin_amdgcn_mfma_f32_16x16x32_bf16(af, b3v, acc3, 0, 0, 0);
    }
    f32x4 accs[4] = {acc0, acc1, acc2, acc3};

    // relu(0.25*acc + b2) per element, then pool
    float vals[4][4];
#pragma unroll
    for (int cb = 0; cb < 4; cb++) {
        float bv = b2[cb * 16 + m];
#pragma unroll
        for (int r = 0; r < 4; r++)
            vals[cb][r] = fmaxf(0.25f * accs[cb][r] + bv, 0.f);
    }

    bool fast = (nodeBase + 15 < N);
    int g0 = 0;
    if (fast) {
        g0 = batch[nodeBase];
        int g1 = batch[nodeBase + 15];
        fast = (g0 == g1);
    }
    if (fast) {
#pragma unroll
        for (int cb = 0; cb < 4; cb++) {
            float s = vals[cb][0] + vals[cb][1] + vals[cb][2] + vals[cb][3];
            s += __shfl_xor(s, 16);
            s += __shfl_xor(s, 32);
            if (quad == 0) atomicAdd(&out[g0 * 64 + cb * 16 + m], s);
        }
    } else {
#pragma unroll
        for (int r = 0; r < 4; r++) {
            int node = nodeBase + quad * 4 + r;
            if (node < N) {
                int g = batch[node];
#pragma unroll
                for (int cb = 0; cb < 4; cb++)
                    atomicAdd(&out[g * 64 + cb * 16 + m], vals[cb][r]);
            }
        }
    }
}

__global__ void k_pzero(float* __restrict__ out, int total) {
    int i = blockIdx.x * blockDim.x + threadIdx.x;
    if (i < total) out[i] = 0.f;
}

extern "C" void kernel_launch(void* const* d_in, const int* in_sizes, int n_in,
                              void* d_out, int out_size, void* d_ws, size_t ws_size,
                              hipStream_t stream) {
    const float* x   = (const float*)d_in[0];
    const int*   ei  = (const int*)d_in[1];
    const int*   bat = (const int*)d_in[2];
    const float* W1  = (const float*)d_in[3];
    const float* as1 = (const float*)d_in[4];
    const float* ad1 = (const float*)d_in[5];
    const float* b1  = (const float*)d_in[6];
    const float* W2  = (const float*)d_in[7];
    const float* as2 = (const float*)d_in[8];
    const float* ad2 = (const float*)d_in[9];
    const float* b2  = (const float*)d_in[10];
    float* out = (float*)d_out;

    int N = in_sizes[0] / 3;
    int E = in_sizes[1] / 2;
    int G = out_size / 64;
    const int* srcI = ei;
    const int* dstI = ei + E;
    int NBUCK = (N + BWIDTH - 1) >> BSHIFT;

    // ---- workspace layout ----
    float* fw = (float*)d_ws;
    size_t fo = 0;
    unsigned short* aggb = (unsigned short*)fw; fo += (size_t)N * 128;   // N*256 bf16
    unsigned short* houtb = (unsigned short*)(fw + fo); fo += (size_t)N * 32;  // N*64 bf16
    float* esA   = fw + fo; fo += (size_t)N * 4;
    float* edA   = fw + fo; fo += (size_t)N * 4;
    float* esB   = fw + fo; fo += (size_t)N * 4;
    float* edB   = fw + fo; fo += (size_t)N * 4;
    float* p1s   = fw + fo; fo += 64;
    float* p1d   = fw + fo; fo += 64;
    float* qs    = fw + fo; fo += 256;
    float* qd    = fw + fo; fo += 256;
    unsigned short* W2bt = (unsigned short*)(fw + fo); fo += 64 * 256 / 2;
    int* iw = (int*)(fw + fo);
    size_t io = 0;
    uint2* pairs = (uint2*)iw; io += (size_t)2 * E;
    int* csr    = iw + io; io += E;
    int* off    = iw + io; io += N + 1;
    int* bbase  = iw + io; io += 1025;
    int* gcur   = iw + io; io += 1024;
    int* bcnt   = iw + io; io += 1024;

    int nThrBlk = (N + 255) / 256;
    int nGrpBlk = (N + 15) / 16;

    // ---- CSR build: two-level counting sort ----
    k_binit<<<1, 1024, 0, stream>>>(bcnt, NBUCK);
    k_bhist<<<256, 256, 0, stream>>>(dstI, bcnt, E, NBUCK);
    k_bscan<<<1, 1024, 0, stream>>>(bcnt, bbase, gcur, off, NBUCK, N, E);
    k_bdist<<<(E + DCHUNK - 1) / DCHUNK, 1024, 0, stream>>>(srcI, dstI, gcur, pairs, E, NBUCK);
    k_bcsr<<<NBUCK, 256, 0, stream>>>(pairs, bbase, off, csr, N);

    // ---- precompute attention projections + bf16 W2; zero out ----
    k_prep<<<(3 * 8 * 64 + 255) / 256, 256, 0, stream>>>(W1, as1, ad1, p1s, p1d, 3);
    k_prep<<<(64 * 8 * 64 + 255) / 256, 256, 0, stream>>>(W2, as2, ad2, qs, qd, 64);
    k_w2bt<<<64, 256, 0, stream>>>(W2, W2bt);
    k_pzero<<<(G * 64 + 255) / 256, 256, 0, stream>>>(out, G * 64);

    // ---- layer 1 (writes bf16 hout + layer-2 es/ed) ----
    k_esed1<<<nThrBlk, 256, 0, stream>>>(x, p1s, p1d, esA, edA, N);
    k_agg1<<<nGrpBlk, 256, 0, stream>>>(off, csr, esA, edA, x, W1, b1, qs, qd,
                                        houtb, esB, edB, N);

    // ---- layer 2 (aggregate -> bf16 agg -> MFMA transform + fused pool) ----
    k_agg2<<<nGrpBlk, 256, 0, stream>>>(off, csr, esB, edB, houtb, aggb, N);
    k_out2<<<(N + 63) / 64, 256, 0, stream>>>(aggb, W2bt, b2, bat, out, N);
}

// Round 10
// 257.257 us; speedup vs baseline: 9.0314x; 1.0338x over previous
//
#include <hip/hip_runtime.h>
#include <math.h>

#define HEADS 4
#define HID 64
#define BSHIFT 7          // 128 nodes per bucket
#define BWIDTH 128
#define CCAP 4096         // LDS csr-staging capacity (edges/bucket mean ~2047)
#define DCHUNK 8192       // edges per k_bdist block (8 per thread, 1024 threads)

typedef __attribute__((ext_vector_type(8))) short short8;
typedef __attribute__((ext_vector_type(4))) float f32x4;

__device__ __forceinline__ float lrelu(float x) { return x > 0.f ? x : 0.2f * x; }

__device__ __forceinline__ unsigned short bf16r(float f) {
    unsigned u = __float_as_uint(f);
    unsigned r = (u + 0x7FFFu + ((u >> 16) & 1u)) >> 16;
    return (unsigned short)r;
}
__device__ __forceinline__ float bf2f(unsigned short u) {
    return __uint_as_float(((unsigned)u) << 16);
}

__device__ __forceinline__ float wred_sum(float v) {
#pragma unroll
    for (int o = 32; o > 0; o >>= 1) v += __shfl_xor(v, o);
    return v;
}
__device__ __forceinline__ float red16_sum(float v) {
#pragma unroll
    for (int o = 8; o > 0; o >>= 1) v += __shfl_xor(v, o);
    return v;
}

// ======================= CSR build: two-level LDS counting sort =======================
__global__ void k_binit(int* __restrict__ bcnt, int NBUCK) {
    int i = threadIdx.x;
    if (i < NBUCK) bcnt[i] = 0;
}

__global__ void k_bhist(const int* __restrict__ dstI, int* __restrict__ bcnt,
                        int E, int NBUCK) {
    __shared__ int h[1024];
    for (int i = threadIdx.x; i < NBUCK; i += 256) h[i] = 0;
    __syncthreads();
    int stride = gridDim.x * 256;
    for (int e = blockIdx.x * 256 + threadIdx.x; e < E; e += stride)
        atomicAdd(&h[dstI[e] >> BSHIFT], 1);
    __syncthreads();
    for (int i = threadIdx.x; i < NBUCK; i += 256)
        if (h[i]) atomicAdd(&bcnt[i], h[i]);
}

// single block, 1024 threads: exclusive scan of bucket counts
__global__ void k_bscan(const int* __restrict__ bcnt, int* __restrict__ bbase,
                        int* __restrict__ gcur, int* __restrict__ off,
                        int NBUCK, int N, int E) {
    __shared__ int lds[1024];
    int t = threadIdx.x;
    int v = (t < NBUCK) ? bcnt[t] : 0;
    lds[t] = v;
    __syncthreads();
    for (int s = 1; s < 1024; s <<= 1) {
        int u = (t >= s) ? lds[t - s] : 0;
        __syncthreads();
        lds[t] += u;
        __syncthreads();
    }
    if (t < NBUCK) {
        int b = lds[t] - v;
        bbase[t] = b;
        gcur[t] = b;
    }
    if (t == 0) { bbase[NBUCK] = E; off[N] = E; }
}

// distribute edges into bucket regions as packed (src<<BSHIFT | dst&(BWIDTH-1))
__global__ void k_bdist(const int* __restrict__ srcI, const int* __restrict__ dstI,
                        int* __restrict__ gcur, unsigned* __restrict__ pairs,
                        int E, int NBUCK) {
    __shared__ int h[1024];
    __shared__ int cur[1024];
    for (int i = threadIdx.x; i < NBUCK; i += 1024) h[i] = 0;
    __syncthreads();
    int base = blockIdx.x * DCHUNK;
    int sr[8], dr[8];
#pragma unroll
    for (int k = 0; k < 8; k++) {
        int e = base + threadIdx.x + k * 1024;
        if (e < E) {
            sr[k] = srcI[e];
            dr[k] = dstI[e];
            atomicAdd(&h[dr[k] >> BSHIFT], 1);
        } else dr[k] = -1;
    }
    __syncthreads();
    for (int i = threadIdx.x; i < NBUCK; i += 1024)
        cur[i] = h[i] ? atomicAdd(&gcur[i], h[i]) : 0;
    __syncthreads();
#pragma unroll
    for (int k = 0; k < 8; k++) {
        if (dr[k] >= 0) {
            int b = dr[k] >> BSHIFT;
            int p = atomicAdd(&cur[b], 1);
            pairs[p] = ((unsigned)sr[k] << BSHIFT) | ((unsigned)dr[k] & (BWIDTH - 1));
        }
    }
}

// one block per bucket: local degrees -> off[], LDS-cursor distribute -> coalesced csr
__global__ void k_bcsr(const unsigned* __restrict__ pairs, const int* __restrict__ bbase,
                       int* __restrict__ off, int* __restrict__ csr, int N) {
    __shared__ int cnt[BWIDTH];
    __shared__ int scan[BWIDTH];
    __shared__ int cur[BWIDTH];
    __shared__ int stage[CCAP];
    int b = blockIdx.x;
    int nodeBase = b << BSHIFT;
    int nNodes = N - nodeBase;
    if (nNodes > BWIDTH) nNodes = BWIDTH;
    int e0 = bbase[b], e1 = bbase[b + 1];
    int ecnt = e1 - e0;
    if (threadIdx.x < BWIDTH) cnt[threadIdx.x] = 0;
    __syncthreads();
    for (int i = threadIdx.x; i < ecnt; i += 256)
        atomicAdd(&cnt[pairs[e0 + i] & (BWIDTH - 1)], 1);
    __syncthreads();
    if (threadIdx.x < BWIDTH)
        scan[threadIdx.x] = (threadIdx.x < nNodes) ? cnt[threadIdx.x] : 0;
    __syncthreads();
    for (int s = 1; s < BWIDTH; s <<= 1) {
        int u = 0;
        if (threadIdx.x < BWIDTH && threadIdx.x >= s) u = scan[threadIdx.x - s];
        __syncthreads();
        if (threadIdx.x < BWIDTH) scan[threadIdx.x] += u;
        __syncthreads();
    }
    if (threadIdx.x < nNodes) {
        int ex = scan[threadIdx.x] - cnt[threadIdx.x];   // exclusive
        off[nodeBase + threadIdx.x] = e0 + ex;
        cur[threadIdx.x] = ex;
    }
    __syncthreads();
    for (int i = threadIdx.x; i < ecnt; i += 256) {
        unsigned pr = pairs[e0 + i];
        int l = atomicAdd(&cur[pr & (BWIDTH - 1)], 1);
        int src = (int)(pr >> BSHIFT);
        if (l < CCAP) stage[l] = src;
        else csr[e0 + l] = src;   // overflow fallback
    }
    __syncthreads();
    int lim = ecnt < CCAP ? ecnt : CCAP;
    for (int i = threadIdx.x; i < lim; i += 256) csr[e0 + i] = stage[i];
}

// ======================= attention-coefficient precompute =======================
__global__ void k_prep(const float* __restrict__ W, const float* __restrict__ asrc,
                       const float* __restrict__ adst, float* __restrict__ p_src,
                       float* __restrict__ p_dst, int K) {
    int wid = (blockIdx.x * blockDim.x + threadIdx.x) >> 6;
    int lane = threadIdx.x & 63;
    int total = K * 4 * 2;
    if (wid >= total) return;
    int which = wid / (K * 4);
    int hk = wid % (K * 4);
    int h = hk / K, k = hk % K;
    const float* a = which ? adst : asrc;
    float v = W[(size_t)k * 256 + h * 64 + lane] * a[h * 64 + lane];
    v = wred_sum(v);
    if (lane == 0) (which ? p_dst : p_src)[h * K + k] = v;
}

// W2 -> bf16, transposed: W2bt[c*256 + h*64 + kf] = bf16(W2[kf*256 + h*64 + c])
__global__ void k_w2bt(const float* __restrict__ W2, unsigned short* __restrict__ W2bt) {
    int i = blockIdx.x * 256 + threadIdx.x;
    int c = i >> 8, kh = i & 255;
    int h = kh >> 6, kf = kh & 63;
    W2bt[i] = bf16r(W2[kf * 256 + h * 64 + c]);
}

// es[n,h] = sum_k x[n,k] * ps[h*3+k]  (layer 1)
__global__ void k_esed1(const float* __restrict__ x, const float* __restrict__ ps,
                        const float* __restrict__ pd, float* __restrict__ es,
                        float* __restrict__ ed, int N) {
    int n = blockIdx.x * blockDim.x + threadIdx.x;
    if (n >= N) return;
    float x0 = x[n * 3], x1 = x[n * 3 + 1], x2 = x[n * 3 + 2];
    float4 s, d;
    s.x = x0 * ps[0] + x1 * ps[1] + x2 * ps[2];
    s.y = x0 * ps[3] + x1 * ps[4] + x2 * ps[5];
    s.z = x0 * ps[6] + x1 * ps[7] + x2 * ps[8];
    s.w = x0 * ps[9] + x1 * ps[10] + x2 * ps[11];
    d.x = x0 * pd[0] + x1 * pd[1] + x2 * pd[2];
    d.y = x0 * pd[3] + x1 * pd[4] + x2 * pd[5];
    d.z = x0 * pd[6] + x1 * pd[7] + x2 * pd[8];
    d.w = x0 * pd[9] + x1 * pd[10] + x2 * pd[11];
    ((float4*)es)[n] = s;
    ((float4*)ed)[n] = d;
}

// ======================= layer 1: 16-lane group per node (no-max softmax, 2 passes) =======================
__global__ void k_agg1(const int* __restrict__ off, const int* __restrict__ csr,
                       const float* __restrict__ es, const float* __restrict__ ed,
                       const float* __restrict__ x, const float* __restrict__ W1,
                       const float* __restrict__ b1, const float* __restrict__ qs,
                       const float* __restrict__ qd, unsigned short* __restrict__ houtb,
                       float* __restrict__ es2, float* __restrict__ ed2, int N) {
    int grp = (blockIdx.x * blockDim.x + threadIdx.x) >> 4;
    int l = threadIdx.x & 15;
    int wid = grp;
    bool active = wid < N;
    int o0 = 0, deg = 0;
    float4 edv = make_float4(0.f, 0.f, 0.f, 0.f);
    if (active) {
        o0 = off[wid];
        deg = off[wid + 1] - o0;
        edv = ((const float4*)ed)[wid];
    }

    // pass 1: exp (no max subtraction) + sum; cache first 16 edges in regs
    float t0 = 0.f, t1 = 0.f, t2 = 0.f, t3 = 0.f;
    int s_cache = 0;
    float c0 = 0.f, c1 = 0.f, c2 = 0.f, c3 = 0.f;
    for (int j = l; j < deg; j += 16) {
        int s = csr[o0 + j];
        float4 ev = ((const float4*)es)[s];
        float e0 = __expf(lrelu(ev.x + edv.x));
        float e1 = __expf(lrelu(ev.y + edv.y));
        float e2 = __expf(lrelu(ev.z + edv.z));
        float e3 = __expf(lrelu(ev.w + edv.w));
        if (j < 16) { s_cache = s; c0 = e0; c1 = e1; c2 = e2; c3 = e3; }
        t0 += e0; t1 += e1; t2 += e2; t3 += e3;
    }
    t0 = red16_sum(t0); t1 = red16_sum(t1); t2 = red16_sum(t2); t3 = red16_sum(t3);
    float i0 = t0 > 0.f ? 1.f / t0 : 0.f;
    float i1 = t1 > 0.f ? 1.f / t1 : 0.f;
    float i2 = t2 > 0.f ? 1.f / t2 : 0.f;
    float i3 = t3 > 0.f ? 1.f / t3 : 0.f;

    // pass 2: agg3[h][k] = sum_e exp_eh * x[src,k]  (scaled by inv after reduce)
    float a00 = 0, a01 = 0, a02 = 0, a10 = 0, a11 = 0, a12 = 0;
    float a20 = 0, a21 = 0, a22 = 0, a30 = 0, a31 = 0, a32 = 0;
    for (int j = l; j < deg; j += 16) {
        float e0, e1, e2, e3; int s;
        if (j < 16) { s = s_cache; e0 = c0; e1 = c1; e2 = c2; e3 = c3; }
        else {
            s = csr[o0 + j];
            float4 ev = ((const float4*)es)[s];
            e0 = __expf(lrelu(ev.x + edv.x));
            e1 = __expf(lrelu(ev.y + edv.y));
            e2 = __expf(lrelu(ev.z + edv.z));
            e3 = __expf(lrelu(ev.w + edv.w));
        }
        float xv0 = x[s * 3], xv1 = x[s * 3 + 1], xv2 = x[s * 3 + 2];
        a00 += e0 * xv0; a01 += e0 * xv1; a02 += e0 * xv2;
        a10 += e1 * xv0; a11 += e1 * xv1; a12 += e1 * xv2;
        a20 += e2 * xv0; a21 += e2 * xv1; a22 += e2 * xv2;
        a30 += e3 * xv0; a31 += e3 * xv1; a32 += e3 * xv2;
    }
    a00 = red16_sum(a00) * i0; a01 = red16_sum(a01) * i0; a02 = red16_sum(a02) * i0;
    a10 = red16_sum(a10) * i1; a11 = red16_sum(a11) * i1; a12 = red16_sum(a12) * i1;
    a20 = red16_sum(a20) * i2; a21 = red16_sum(a21) * i2; a22 = red16_sum(a22) * i2;
    a30 = red16_sum(a30) * i3; a31 = red16_sum(a31) * i3; a32 = red16_sum(a32) * i3;

    if (!active) return;

    const float4* W1f = (const float4*)W1;
    float4 r = make_float4(0.f, 0.f, 0.f, 0.f);
    float ah[4][3] = {{a00, a01, a02}, {a10, a11, a12}, {a20, a21, a22}, {a30, a31, a32}};
#pragma unroll
    for (int k = 0; k < 3; k++) {
#pragma unroll
        for (int h = 0; h < 4; h++) {
            float4 wv = W1f[k * 64 + h * 16 + l];
            float a = ah[h][k];
            r.x += a * wv.x; r.y += a * wv.y; r.z += a * wv.z; r.w += a * wv.w;
        }
    }
    float4 bv = ((const float4*)b1)[l];
    float4 hv;
    hv.x = fmaxf(0.25f * r.x + bv.x, 0.f);
    hv.y = fmaxf(0.25f * r.y + bv.y, 0.f);
    hv.z = fmaxf(0.25f * r.z + bv.z, 0.f);
    hv.w = fmaxf(0.25f * r.w + bv.w, 0.f);
    ((ushort4*)houtb)[(size_t)wid * 16 + l] =
        make_ushort4(bf16r(hv.x), bf16r(hv.y), bf16r(hv.z), bf16r(hv.w));

    const float4* qsf = (const float4*)qs;
    const float4* qdf = (const float4*)qd;
    float ps[4], pd[4];
#pragma unroll
    for (int h = 0; h < 4; h++) {
        float4 q = qsf[h * 16 + l];
        ps[h] = red16_sum(hv.x * q.x + hv.y * q.y + hv.z * q.z + hv.w * q.w);
        float4 p = qdf[h * 16 + l];
        pd[h] = red16_sum(hv.x * p.x + hv.y * p.y + hv.z * p.z + hv.w * p.w);
    }
    if (l == 0) {
        ((float4*)es2)[wid] = make_float4(ps[0], ps[1], ps[2], ps[3]);
        ((float4*)ed2)[wid] = make_float4(pd[0], pd[1], pd[2], pd[3]);
    }
}

// ======================= layer 2: single-pass softmax -> LDS, wave gather =======================
#define NS 16
__global__ void k_agg2(const int* __restrict__ off, const int* __restrict__ csr,
                       const float* __restrict__ es, const float* __restrict__ ed,
                       const unsigned short* __restrict__ houtb,
                       unsigned short* __restrict__ aggb, int N) {
    __shared__ float exl[NS * 64 * 4];
    __shared__ int   sl[NS * 64];
    __shared__ float minv[NS * 4];   // inv per head
    __shared__ int   meta[NS * 2];   // o0, deg

    for (int i = threadIdx.x; i < NS * 64; i += 256) {
        ((float4*)exl)[i] = make_float4(0.f, 0.f, 0.f, 0.f);
        sl[i] = 0;
    }
    __syncthreads();

    int l = threadIdx.x & 15;
    int slot = threadIdx.x >> 4;
    int wid = blockIdx.x * NS + slot;
    bool active = wid < N;
    int o0 = 0, deg = 0;
    float4 edv = make_float4(0.f, 0.f, 0.f, 0.f);
    if (active) {
        o0 = off[wid];
        deg = off[wid + 1] - o0;
        edv = ((const float4*)ed)[wid];
    }

    // single pass: exp (no max) -> LDS (first 64 edges) + sum
    float t0 = 0.f, t1 = 0.f, t2 = 0.f, t3 = 0.f;
    for (int j = l; j < deg; j += 16) {
        int s = csr[o0 + j];
        float4 ev = ((const float4*)es)[s];
        float e0 = __expf(lrelu(ev.x + edv.x));
        float e1 = __expf(lrelu(ev.y + edv.y));
        float e2 = __expf(lrelu(ev.z + edv.z));
        float e3 = __expf(lrelu(ev.w + edv.w));
        if (j < 64) {
            ((float4*)exl)[slot * 64 + j] = make_float4(e0, e1, e2, e3);
            sl[slot * 64 + j] = s;
        }
        t0 += e0; t1 += e1; t2 += e2; t3 += e3;
    }
    t0 = red16_sum(t0); t1 = red16_sum(t1); t2 = red16_sum(t2); t3 = red16_sum(t3);
    if (l == 0) {
        minv[slot * 4 + 0] = t0 > 0.f ? 1.f / t0 : 0.f;
        minv[slot * 4 + 1] = t1 > 0.f ? 1.f / t1 : 0.f;
        minv[slot * 4 + 2] = t2 > 0.f ? 1.f / t2 : 0.f;
        minv[slot * 4 + 3] = t3 > 0.f ? 1.f / t3 : 0.f;
        meta[slot * 2 + 0] = o0;
        meta[slot * 2 + 1] = deg;
    }
    __syncthreads();

    int lane = threadIdx.x & 63;
    int w = threadIdx.x >> 6;
    for (int sidx = 0; sidx < 4; sidx++) {
        int slot2 = w * 4 + sidx;
        int nd = blockIdx.x * NS + slot2;
        if (nd >= N) continue;
        int o0b = meta[slot2 * 2 + 0], degb = meta[slot2 * 2 + 1];
        float iv0 = minv[slot2 * 4 + 0], iv1 = minv[slot2 * 4 + 1];
        float iv2 = minv[slot2 * 4 + 2], iv3 = minv[slot2 * 4 + 3];

        float acc0 = 0.f, acc1 = 0.f, acc2 = 0.f, acc3 = 0.f;
        const float4* EX = ((const float4*)exl) + slot2 * 64;
        const int* S = sl + slot2 * 64;
        int dmain = degb < 64 ? degb : 64;
        int d4 = (dmain + 3) & ~3;
        for (int j = 0; j < d4; j += 4) {
            float4 a0 = EX[j], a1 = EX[j + 1], a2 = EX[j + 2], a3 = EX[j + 3];
            int s0 = S[j], s1 = S[j + 1], s2 = S[j + 2], s3 = S[j + 3];
            float v0 = bf2f(houtb[(size_t)s0 * 64 + lane]);
            float v1 = bf2f(houtb[(size_t)s1 * 64 + lane]);
            float v2 = bf2f(houtb[(size_t)s2 * 64 + lane]);
            float v3 = bf2f(houtb[(size_t)s3 * 64 + lane]);
            acc0 += a0.x * v0 + a1.x * v1 + a2.x * v2 + a3.x * v3;
            acc1 += a0.y * v0 + a1.y * v1 + a2.y * v2 + a3.y * v3;
            acc2 += a0.z * v0 + a1.z * v1 + a2.z * v2 + a3.z * v3;
            acc3 += a0.w * v0 + a1.w * v1 + a2.w * v2 + a3.w * v3;
        }
        if (degb > 64) {
            float4 edv2 = ((const float4*)ed)[nd];
            for (int j = 64; j < degb; j++) {
                int s = csr[o0b + j];
                float4 ev = ((const float4*)es)[s];
                float e0 = __expf(lrelu(ev.x + edv2.x));
                float e1 = __expf(lrelu(ev.y + edv2.y));
                float e2 = __expf(lrelu(ev.z + edv2.z));
                float e3 = __expf(lrelu(ev.w + edv2.w));
                float v = bf2f(houtb[(size_t)s * 64 + lane]);
                acc0 += e0 * v; acc1 += e1 * v; acc2 += e2 * v; acc3 += e3 * v;
            }
        }
        size_t b = (size_t)nd * 256;
        aggb[b + lane]        = bf16r(acc0 * iv0);
        aggb[b + 64 + lane]   = bf16r(acc1 * iv1);
        aggb[b + 128 + lane]  = bf16r(acc2 * iv2);
        aggb[b + 192 + lane]  = bf16r(acc3 * iv3);
    }
}

// ======================= layer 2 output transform (MFMA) + fused global-add-pool =======================
__global__ void k_out2(const unsigned short* __restrict__ aggb,
                       const unsigned short* __restrict__ W2bt,
                       const float* __restrict__ b2, const int* __restrict__ batch,
                       float* __restrict__ out, int N) {
    int w = threadIdx.x >> 6, lane = threadIdx.x & 63;
    int nodeBase = blockIdx.x * 64 + w * 16;
    int m = lane & 15;
    int quad = lane >> 4;
    const short* A = (const short*)aggb + (size_t)(nodeBase + m) * 256 + quad * 8;
    const short* B = (const short*)W2bt;

    f32x4 acc0 = {0.f, 0.f, 0.f, 0.f}, acc1 = {0.f, 0.f, 0.f, 0.f};
    f32x4 acc2 = {0.f, 0.f, 0.f, 0.f}, acc3 = {0.f, 0.f, 0.f, 0.f};
#pragma unroll
    for (int kk = 0; kk < 8; kk++) {
        short8 af = *(const short8*)(A + kk * 32);
        short8 b0 = *(const short8*)(B + (size_t)(0 * 16 + m) * 256 + kk * 32 + quad * 8);
        short8 b1v = *(const short8*)(B + (size_t)(1 * 16 + m) * 256 + kk * 32 + quad * 8);
        short8 b2v = *(const short8*)(B + (size_t)(2 * 16 + m) * 256 + kk * 32 + quad * 8);
        short8 b3v = *(const short8*)(B + (size_t)(3 * 16 + m) * 256 + kk * 32 + quad * 8);
        acc0 = __builtin_amdgcn_mfma_f32_16x16x32_bf16(af, b0, acc0, 0, 0, 0);
        acc1 = __builtin_amdgcn_mfma_f32_16x16x32_bf16(af, b1v, acc1, 0, 0, 0);
        acc2 = __builtin_amdgcn_mfma_f32_16x16x32_bf16(af, b2v, acc2, 0, 0, 0);
        acc3 = __builtin_amdgcn_mfma_f32_16x16x32_bf16(af, b3v, acc3, 0, 0, 0);
    }
    f32x4 accs[4] = {acc0, acc1, acc2, acc3};

    float vals[4][4];
#pragma unroll
    for (int cb = 0; cb < 4; cb++) {
        float bv = b2[cb * 16 + m];
#pragma unroll
        for (int r = 0; r < 4; r++)
            vals[cb][r] = fmaxf(0.25f * accs[cb][r] + bv, 0.f);
    }

    bool fast = (nodeBase + 15 < N);
    int g0 = 0;
    if (fast) {
        g0 = batch[nodeBase];
        int g1 = batch[nodeBase + 15];
        fast = (g0 == g1);
    }
    if (fast) {
#pragma unroll
        for (int cb = 0; cb < 4; cb++) {
            float s = vals[cb][0] + vals[cb][1] + vals[cb][2] + vals[cb][3];
            s += __shfl_xor(s, 16);
            s += __shfl_xor(s, 32);
            if (quad == 0) atomicAdd(&out[g0 * 64 + cb * 16 + m], s);
        }
    } else {
#pragma unroll
        for (int r = 0; r < 4; r++) {
            int node = nodeBase + quad * 4 + r;
            if (node < N) {
                int g = batch[node];
#pragma unroll
                for (int cb = 0; cb < 4; cb++)
                    atomicAdd(&out[g * 64 + cb * 16 + m], vals[cb][r]);
            }
        }
    }
}

__global__ void k_pzero(float* __restrict__ out, int total) {
    int i = blockIdx.x * blockDim.x + threadIdx.x;
    if (i < total) out[i] = 0.f;
}

extern "C" void kernel_launch(void* const* d_in, const int* in_sizes, int n_in,
                              void* d_out, int out_size, void* d_ws, size_t ws_size,
                              hipStream_t stream) {
    const float* x   = (const float*)d_in[0];
    const int*   ei  = (const int*)d_in[1];
    const int*   bat = (const int*)d_in[2];
    const float* W1  = (const float*)d_in[3];
    const float* as1 = (const float*)d_in[4];
    const float* ad1 = (const float*)d_in[5];
    const float* b1  = (const float*)d_in[6];
    const float* W2  = (const float*)d_in[7];
    const float* as2 = (const float*)d_in[8];
    const float* ad2 = (const float*)d_in[9];
    const float* b2  = (const float*)d_in[10];
    float* out = (float*)d_out;

    int N = in_sizes[0] / 3;
    int E = in_sizes[1] / 2;
    int G = out_size / 64;
    const int* srcI = ei;
    const int* dstI = ei + E;
    int NBUCK = (N + BWIDTH - 1) >> BSHIFT;

    // ---- workspace layout ----
    float* fw = (float*)d_ws;
    size_t fo = 0;
    unsigned short* aggb = (unsigned short*)fw; fo += (size_t)N * 128;   // N*256 bf16
    unsigned short* houtb = (unsigned short*)(fw + fo); fo += (size_t)N * 32;  // N*64 bf16
    float* esA   = fw + fo; fo += (size_t)N * 4;
    float* edA   = fw + fo; fo += (size_t)N * 4;
    float* esB   = fw + fo; fo += (size_t)N * 4;
    float* edB   = fw + fo; fo += (size_t)N * 4;
    float* p1s   = fw + fo; fo += 64;
    float* p1d   = fw + fo; fo += 64;
    float* qs    = fw + fo; fo += 256;
    float* qd    = fw + fo; fo += 256;
    unsigned short* W2bt = (unsigned short*)(fw + fo); fo += 64 * 256 / 2;
    int* iw = (int*)(fw + fo);
    size_t io = 0;
    unsigned* pairs = (unsigned*)iw; io += E;
    int* csr    = iw + io; io += E;
    int* off    = iw + io; io += N + 1;
    int* bbase  = iw + io; io += 1025;
    int* gcur   = iw + io; io += 1024;
    int* bcnt   = iw + io; io += 1024;

    int nThrBlk = (N + 255) / 256;
    int nGrpBlk = (N + 15) / 16;

    // ---- CSR build: two-level counting sort ----
    k_binit<<<1, 1024, 0, stream>>>(bcnt, NBUCK);
    k_bhist<<<256, 256, 0, stream>>>(dstI, bcnt, E, NBUCK);
    k_bscan<<<1, 1024, 0, stream>>>(bcnt, bbase, gcur, off, NBUCK, N, E);
    k_bdist<<<(E + DCHUNK - 1) / DCHUNK, 1024, 0, stream>>>(srcI, dstI, gcur, pairs, E, NBUCK);
    k_bcsr<<<NBUCK, 256, 0, stream>>>(pairs, bbase, off, csr, N);

    // ---- precompute attention projections + bf16 W2; zero out ----
    k_prep<<<(3 * 8 * 64 + 255) / 256, 256, 0, stream>>>(W1, as1, ad1, p1s, p1d, 3);
    k_prep<<<(64 * 8 * 64 + 255) / 256, 256, 0, stream>>>(W2, as2, ad2, qs, qd, 64);
    k_w2bt<<<64, 256, 0, stream>>>(W2, W2bt);
    k_pzero<<<(G * 64 + 255) / 256, 256, 0, stream>>>(out, G * 64);

    // ---- layer 1 (writes bf16 hout + layer-2 es/ed) ----
    k_esed1<<<nThrBlk, 256, 0, stream>>>(x, p1s, p1d, esA, edA, N);
    k_agg1<<<nGrpBlk, 256, 0, stream>>>(off, csr, esA, edA, x, W1, b1, qs, qd,
                                        houtb, esB, edB, N);

    // ---- layer 2 (aggregate -> bf16 agg -> MFMA transform + fused pool) ----
    k_agg2<<<nGrpBlk, 256, 0, stream>>>(off, csr, esB, edB, houtb, aggb, N);
    k_out2<<<(N + 63) / 64, 256, 0, stream>>>(aggb, W2bt, b2, bat, out, N);
}

// Round 11
// 254.516 us; speedup vs baseline: 9.1287x; 1.0108x over previous
//
#include <hip/hip_runtime.h>
#include <math.h>

#define HEADS 4
#define HID 64
#define BSHIFT 7          // 128 nodes per bucket
#define BWIDTH 128
#define CCAP 4096         // LDS csr-staging capacity (edges/bucket mean ~2047)
#define DCHUNK 8192       // edges per k_bdist block (8 per thread, 1024 threads)

typedef __attribute__((ext_vector_type(8))) short short8;
typedef __attribute__((ext_vector_type(4))) float f32x4;

__device__ __forceinline__ float lrelu(float x) { return x > 0.f ? x : 0.2f * x; }

__device__ __forceinline__ unsigned short bf16r(float f) {
    unsigned u = __float_as_uint(f);
    unsigned r = (u + 0x7FFFu + ((u >> 16) & 1u)) >> 16;
    return (unsigned short)r;
}
__device__ __forceinline__ float bf2f(unsigned short u) {
    return __uint_as_float(((unsigned)u) << 16);
}

__device__ __forceinline__ float wred_sum(float v) {
#pragma unroll
    for (int o = 32; o > 0; o >>= 1) v += __shfl_xor(v, o);
    return v;
}
__device__ __forceinline__ float red16_sum(float v) {
#pragma unroll
    for (int o = 8; o > 0; o >>= 1) v += __shfl_xor(v, o);
    return v;
}

// ======================= CSR build: two-level LDS counting sort =======================
__global__ void k_binit(int* __restrict__ bcnt, int NBUCK) {
    int i = threadIdx.x;
    if (i < NBUCK) bcnt[i] = 0;
}

__global__ void k_bhist(const int* __restrict__ dstI, int* __restrict__ bcnt,
                        int E, int NBUCK) {
    __shared__ int h[1024];
    for (int i = threadIdx.x; i < NBUCK; i += 256) h[i] = 0;
    __syncthreads();
    int stride = gridDim.x * 256;
    for (int e = blockIdx.x * 256 + threadIdx.x; e < E; e += stride)
        atomicAdd(&h[dstI[e] >> BSHIFT], 1);
    __syncthreads();
    for (int i = threadIdx.x; i < NBUCK; i += 256)
        if (h[i]) atomicAdd(&bcnt[i], h[i]);
}

// single block, 1024 threads: exclusive scan of bucket counts
__global__ void k_bscan(const int* __restrict__ bcnt, int* __restrict__ bbase,
                        int* __restrict__ gcur, int* __restrict__ off,
                        int NBUCK, int N, int E) {
    __shared__ int lds[1024];
    int t = threadIdx.x;
    int v = (t < NBUCK) ? bcnt[t] : 0;
    lds[t] = v;
    __syncthreads();
    for (int s = 1; s < 1024; s <<= 1) {
        int u = (t >= s) ? lds[t - s] : 0;
        __syncthreads();
        lds[t] += u;
        __syncthreads();
    }
    if (t < NBUCK) {
        int b = lds[t] - v;
        bbase[t] = b;
        gcur[t] = b;
    }
    if (t == 0) { bbase[NBUCK] = E; off[N] = E; }
}

// distribute edges into bucket regions as packed (src<<BSHIFT | dst&(BWIDTH-1))
__global__ void k_bdist(const int* __restrict__ srcI, const int* __restrict__ dstI,
                        int* __restrict__ gcur, unsigned* __restrict__ pairs,
                        int E, int NBUCK) {
    __shared__ int h[1024];
    __shared__ int cur[1024];
    for (int i = threadIdx.x; i < NBUCK; i += 1024) h[i] = 0;
    __syncthreads();
    int base = blockIdx.x * DCHUNK;
    int sr[8], dr[8];
#pragma unroll
    for (int k = 0; k < 8; k++) {
        int e = base + threadIdx.x + k * 1024;
        if (e < E) {
            sr[k] = srcI[e];
            dr[k] = dstI[e];
            atomicAdd(&h[dr[k] >> BSHIFT], 1);
        } else dr[k] = -1;
    }
    __syncthreads();
    for (int i = threadIdx.x; i < NBUCK; i += 1024)
        cur[i] = h[i] ? atomicAdd(&gcur[i], h[i]) : 0;
    __syncthreads();
#pragma unroll
    for (int k = 0; k < 8; k++) {
        if (dr[k] >= 0) {
            int b = dr[k] >> BSHIFT;
            int p = atomicAdd(&cur[b], 1);
            pairs[p] = ((unsigned)sr[k] << BSHIFT) | ((unsigned)dr[k] & (BWIDTH - 1));
        }
    }
}

// one block per bucket: local degrees -> off[], LDS-cursor distribute -> coalesced csr
__global__ void k_bcsr(const unsigned* __restrict__ pairs, const int* __restrict__ bbase,
                       int* __restrict__ off, int* __restrict__ csr, int N) {
    __shared__ int cnt[BWIDTH];
    __shared__ int scan[BWIDTH];
    __shared__ int cur[BWIDTH];
    __shared__ int stage[CCAP];
    int b = blockIdx.x;
    int nodeBase = b << BSHIFT;
    int nNodes = N - nodeBase;
    if (nNodes > BWIDTH) nNodes = BWIDTH;
    int e0 = bbase[b], e1 = bbase[b + 1];
    int ecnt = e1 - e0;
    if (threadIdx.x < BWIDTH) cnt[threadIdx.x] = 0;
    __syncthreads();
    for (int i = threadIdx.x; i < ecnt; i += 256)
        atomicAdd(&cnt[pairs[e0 + i] & (BWIDTH - 1)], 1);
    __syncthreads();
    if (threadIdx.x < BWIDTH)
        scan[threadIdx.x] = (threadIdx.x < nNodes) ? cnt[threadIdx.x] : 0;
    __syncthreads();
    for (int s = 1; s < BWIDTH; s <<= 1) {
        int u = 0;
        if (threadIdx.x < BWIDTH && threadIdx.x >= s) u = scan[threadIdx.x - s];
        __syncthreads();
        if (threadIdx.x < BWIDTH) scan[threadIdx.x] += u;
        __syncthreads();
    }
    if (threadIdx.x < nNodes) {
        int ex = scan[threadIdx.x] - cnt[threadIdx.x];   // exclusive
        off[nodeBase + threadIdx.x] = e0 + ex;
        cur[threadIdx.x] = ex;
    }
    __syncthreads();
    for (int i = threadIdx.x; i < ecnt; i += 256) {
        unsigned pr = pairs[e0 + i];
        int l = atomicAdd(&cur[pr & (BWIDTH - 1)], 1);
        int src = (int)(pr >> BSHIFT);
        if (l < CCAP) stage[l] = src;
        else csr[e0 + l] = src;   // overflow fallback
    }
    __syncthreads();
    int lim = ecnt < CCAP ? ecnt : CCAP;
    for (int i = threadIdx.x; i < lim; i += 256) csr[e0 + i] = stage[i];
}

// ======================= attention-coefficient precompute =======================
__global__ void k_prep(const float* __restrict__ W, const float* __restrict__ asrc,
                       const float* __restrict__ adst, float* __restrict__ p_src,
                       float* __restrict__ p_dst, int K) {
    int wid = (blockIdx.x * blockDim.x + threadIdx.x) >> 6;
    int lane = threadIdx.x & 63;
    int total = K * 4 * 2;
    if (wid >= total) return;
    int which = wid / (K * 4);
    int hk = wid % (K * 4);
    int h = hk / K, k = hk % K;
    const float* a = which ? adst : asrc;
    float v = W[(size_t)k * 256 + h * 64 + lane] * a[h * 64 + lane];
    v = wred_sum(v);
    if (lane == 0) (which ? p_dst : p_src)[h * K + k] = v;
}

// W2 -> bf16, transposed: W2bt[c*256 + h*64 + kf] = bf16(W2[kf*256 + h*64 + c])
__global__ void k_w2bt(const float* __restrict__ W2, unsigned short* __restrict__ W2bt) {
    int i = blockIdx.x * 256 + threadIdx.x;
    int c = i >> 8, kh = i & 255;
    int h = kh >> 6, kf = kh & 63;
    W2bt[i] = bf16r(W2[kf * 256 + h * 64 + c]);
}

// es[n,h] = sum_k x[n,k] * ps[h*3+k]  (layer 1)
__global__ void k_esed1(const float* __restrict__ x, const float* __restrict__ ps,
                        const float* __restrict__ pd, float* __restrict__ es,
                        float* __restrict__ ed, int N) {
    int n = blockIdx.x * blockDim.x + threadIdx.x;
    if (n >= N) return;
    float x0 = x[n * 3], x1 = x[n * 3 + 1], x2 = x[n * 3 + 2];
    float4 s, d;
    s.x = x0 * ps[0] + x1 * ps[1] + x2 * ps[2];
    s.y = x0 * ps[3] + x1 * ps[4] + x2 * ps[5];
    s.z = x0 * ps[6] + x1 * ps[7] + x2 * ps[8];
    s.w = x0 * ps[9] + x1 * ps[10] + x2 * ps[11];
    d.x = x0 * pd[0] + x1 * pd[1] + x2 * pd[2];
    d.y = x0 * pd[3] + x1 * pd[4] + x2 * pd[5];
    d.z = x0 * pd[6] + x1 * pd[7] + x2 * pd[8];
    d.w = x0 * pd[9] + x1 * pd[10] + x2 * pd[11];
    ((float4*)es)[n] = s;
    ((float4*)ed)[n] = d;
}

// ======================= layer 1: 16-lane group per node, SINGLE pass =======================
// agg[h][k] = (sum_e exp_eh * x[src,k]) / (sum_e exp_eh) — both sums in one loop.
__global__ void k_agg1(const int* __restrict__ off, const int* __restrict__ csr,
                       const float* __restrict__ es, const float* __restrict__ ed,
                       const float* __restrict__ x, const float* __restrict__ W1,
                       const float* __restrict__ b1, const float* __restrict__ qs,
                       const float* __restrict__ qd, unsigned short* __restrict__ houtb,
                       float* __restrict__ es2, float* __restrict__ ed2, int N) {
    int grp = (blockIdx.x * blockDim.x + threadIdx.x) >> 4;
    int l = threadIdx.x & 15;
    int wid = grp;
    bool active = wid < N;
    int o0 = 0, deg = 0;
    float4 edv = make_float4(0.f, 0.f, 0.f, 0.f);
    if (active) {
        o0 = off[wid];
        deg = off[wid + 1] - o0;
        edv = ((const float4*)ed)[wid];
    }

    float t0 = 0.f, t1 = 0.f, t2 = 0.f, t3 = 0.f;
    float a00 = 0, a01 = 0, a02 = 0, a10 = 0, a11 = 0, a12 = 0;
    float a20 = 0, a21 = 0, a22 = 0, a30 = 0, a31 = 0, a32 = 0;
    for (int j = l; j < deg; j += 16) {
        int s = csr[o0 + j];
        float4 ev = ((const float4*)es)[s];
        float e0 = __expf(lrelu(ev.x + edv.x));
        float e1 = __expf(lrelu(ev.y + edv.y));
        float e2 = __expf(lrelu(ev.z + edv.z));
        float e3 = __expf(lrelu(ev.w + edv.w));
        float xv0 = x[s * 3], xv1 = x[s * 3 + 1], xv2 = x[s * 3 + 2];
        t0 += e0; t1 += e1; t2 += e2; t3 += e3;
        a00 += e0 * xv0; a01 += e0 * xv1; a02 += e0 * xv2;
        a10 += e1 * xv0; a11 += e1 * xv1; a12 += e1 * xv2;
        a20 += e2 * xv0; a21 += e2 * xv1; a22 += e2 * xv2;
        a30 += e3 * xv0; a31 += e3 * xv1; a32 += e3 * xv2;
    }
    t0 = red16_sum(t0); t1 = red16_sum(t1); t2 = red16_sum(t2); t3 = red16_sum(t3);
    float i0 = t0 > 0.f ? 1.f / t0 : 0.f;
    float i1 = t1 > 0.f ? 1.f / t1 : 0.f;
    float i2 = t2 > 0.f ? 1.f / t2 : 0.f;
    float i3 = t3 > 0.f ? 1.f / t3 : 0.f;
    a00 = red16_sum(a00) * i0; a01 = red16_sum(a01) * i0; a02 = red16_sum(a02) * i0;
    a10 = red16_sum(a10) * i1; a11 = red16_sum(a11) * i1; a12 = red16_sum(a12) * i1;
    a20 = red16_sum(a20) * i2; a21 = red16_sum(a21) * i2; a22 = red16_sum(a22) * i2;
    a30 = red16_sum(a30) * i3; a31 = red16_sum(a31) * i3; a32 = red16_sum(a32) * i3;

    if (!active) return;

    const float4* W1f = (const float4*)W1;
    float4 r = make_float4(0.f, 0.f, 0.f, 0.f);
    float ah[4][3] = {{a00, a01, a02}, {a10, a11, a12}, {a20, a21, a22}, {a30, a31, a32}};
#pragma unroll
    for (int k = 0; k < 3; k++) {
#pragma unroll
        for (int h = 0; h < 4; h++) {
            float4 wv = W1f[k * 64 + h * 16 + l];
            float a = ah[h][k];
            r.x += a * wv.x; r.y += a * wv.y; r.z += a * wv.z; r.w += a * wv.w;
        }
    }
    float4 bv = ((const float4*)b1)[l];
    float4 hv;
    hv.x = fmaxf(0.25f * r.x + bv.x, 0.f);
    hv.y = fmaxf(0.25f * r.y + bv.y, 0.f);
    hv.z = fmaxf(0.25f * r.z + bv.z, 0.f);
    hv.w = fmaxf(0.25f * r.w + bv.w, 0.f);
    ((ushort4*)houtb)[(size_t)wid * 16 + l] =
        make_ushort4(bf16r(hv.x), bf16r(hv.y), bf16r(hv.z), bf16r(hv.w));

    const float4* qsf = (const float4*)qs;
    const float4* qdf = (const float4*)qd;
    float ps[4], pd[4];
#pragma unroll
    for (int h = 0; h < 4; h++) {
        float4 q = qsf[h * 16 + l];
        ps[h] = red16_sum(hv.x * q.x + hv.y * q.y + hv.z * q.z + hv.w * q.w);
        float4 p = qdf[h * 16 + l];
        pd[h] = red16_sum(hv.x * p.x + hv.y * p.y + hv.z * p.z + hv.w * p.w);
    }
    if (l == 0) {
        ((float4*)es2)[wid] = make_float4(ps[0], ps[1], ps[2], ps[3]);
        ((float4*)ed2)[wid] = make_float4(pd[0], pd[1], pd[2], pd[3]);
    }
}

// ======================= layer 2: single-pass softmax -> LDS, wave gather (unroll 8) =======================
#define NS 16
__global__ void k_agg2(const int* __restrict__ off, const int* __restrict__ csr,
                       const float* __restrict__ es, const float* __restrict__ ed,
                       const unsigned short* __restrict__ houtb,
                       unsigned short* __restrict__ aggb, int N) {
    __shared__ float exl[NS * 64 * 4];
    __shared__ int   sl[NS * 64];
    __shared__ float minv[NS * 4];   // inv per head
    __shared__ int   meta[NS * 2];   // o0, deg

    for (int i = threadIdx.x; i < NS * 64; i += 256) {
        ((float4*)exl)[i] = make_float4(0.f, 0.f, 0.f, 0.f);
        sl[i] = 0;
    }
    __syncthreads();

    int l = threadIdx.x & 15;
    int slot = threadIdx.x >> 4;
    int wid = blockIdx.x * NS + slot;
    bool active = wid < N;
    int o0 = 0, deg = 0;
    float4 edv = make_float4(0.f, 0.f, 0.f, 0.f);
    if (active) {
        o0 = off[wid];
        deg = off[wid + 1] - o0;
        edv = ((const float4*)ed)[wid];
    }

    // single pass: exp (no max) -> LDS (first 64 edges) + sum
    float t0 = 0.f, t1 = 0.f, t2 = 0.f, t3 = 0.f;
    for (int j = l; j < deg; j += 16) {
        int s = csr[o0 + j];
        float4 ev = ((const float4*)es)[s];
        float e0 = __expf(lrelu(ev.x + edv.x));
        float e1 = __expf(lrelu(ev.y + edv.y));
        float e2 = __expf(lrelu(ev.z + edv.z));
        float e3 = __expf(lrelu(ev.w + edv.w));
        if (j < 64) {
            ((float4*)exl)[slot * 64 + j] = make_float4(e0, e1, e2, e3);
            sl[slot * 64 + j] = s;
        }
        t0 += e0; t1 += e1; t2 += e2; t3 += e3;
    }
    t0 = red16_sum(t0); t1 = red16_sum(t1); t2 = red16_sum(t2); t3 = red16_sum(t3);
    if (l == 0) {
        minv[slot * 4 + 0] = t0 > 0.f ? 1.f / t0 : 0.f;
        minv[slot * 4 + 1] = t1 > 0.f ? 1.f / t1 : 0.f;
        minv[slot * 4 + 2] = t2 > 0.f ? 1.f / t2 : 0.f;
        minv[slot * 4 + 3] = t3 > 0.f ? 1.f / t3 : 0.f;
        meta[slot * 2 + 0] = o0;
        meta[slot * 2 + 1] = deg;
    }
    __syncthreads();

    int lane = threadIdx.x & 63;
    int w = threadIdx.x >> 6;
    for (int sidx = 0; sidx < 4; sidx++) {
        int slot2 = w * 4 + sidx;
        int nd = blockIdx.x * NS + slot2;
        if (nd >= N) continue;
        int o0b = meta[slot2 * 2 + 0], degb = meta[slot2 * 2 + 1];
        float iv0 = minv[slot2 * 4 + 0], iv1 = minv[slot2 * 4 + 1];
        float iv2 = minv[slot2 * 4 + 2], iv3 = minv[slot2 * 4 + 3];

        float acc0 = 0.f, acc1 = 0.f, acc2 = 0.f, acc3 = 0.f;
        const float4* EX = ((const float4*)exl) + slot2 * 64;
        const int* S = sl + slot2 * 64;
        int dmain = degb < 64 ? degb : 64;
        int d8 = (dmain + 7) & ~7;   // pad entries have alpha=0, s=0 -> harmless
        for (int j = 0; j < d8; j += 8) {
            float4 a0 = EX[j], a1 = EX[j + 1], a2 = EX[j + 2], a3 = EX[j + 3];
            float4 a4 = EX[j + 4], a5 = EX[j + 5], a6 = EX[j + 6], a7 = EX[j + 7];
            int s0 = S[j], s1 = S[j + 1], s2 = S[j + 2], s3 = S[j + 3];
            int s4 = S[j + 4], s5 = S[j + 5], s6 = S[j + 6], s7 = S[j + 7];
            float v0 = bf2f(houtb[(size_t)s0 * 64 + lane]);
            float v1 = bf2f(houtb[(size_t)s1 * 64 + lane]);
            float v2 = bf2f(houtb[(size_t)s2 * 64 + lane]);
            float v3 = bf2f(houtb[(size_t)s3 * 64 + lane]);
            float v4 = bf2f(houtb[(size_t)s4 * 64 + lane]);
            float v5 = bf2f(houtb[(size_t)s5 * 64 + lane]);
            float v6 = bf2f(houtb[(size_t)s6 * 64 + lane]);
            float v7 = bf2f(houtb[(size_t)s7 * 64 + lane]);
            acc0 += a0.x * v0 + a1.x * v1 + a2.x * v2 + a3.x * v3
                  + a4.x * v4 + a5.x * v5 + a6.x * v6 + a7.x * v7;
            acc1 += a0.y * v0 + a1.y * v1 + a2.y * v2 + a3.y * v3
                  + a4.y * v4 + a5.y * v5 + a6.y * v6 + a7.y * v7;
            acc2 += a0.z * v0 + a1.z * v1 + a2.z * v2 + a3.z * v3
                  + a4.z * v4 + a5.z * v5 + a6.z * v6 + a7.z * v7;
            acc3 += a0.w * v0 + a1.w * v1 + a2.w * v2 + a3.w * v3
                  + a4.w * v4 + a5.w * v5 + a6.w * v6 + a7.w * v7;
        }
        if (degb > 64) {
            float4 edv2 = ((const float4*)ed)[nd];
            for (int j = 64; j < degb; j++) {
                int s = csr[o0b + j];
                float4 ev = ((const float4*)es)[s];
                float e0 = __expf(lrelu(ev.x + edv2.x));
                float e1 = __expf(lrelu(ev.y + edv2.y));
                float e2 = __expf(lrelu(ev.z + edv2.z));
                float e3 = __expf(lrelu(ev.w + edv2.w));
                float v = bf2f(houtb[(size_t)s * 64 + lane]);
                acc0 += e0 * v; acc1 += e1 * v; acc2 += e2 * v; acc3 += e3 * v;
            }
        }
        size_t b = (size_t)nd * 256;
        aggb[b + lane]        = bf16r(acc0 * iv0);
        aggb[b + 64 + lane]   = bf16r(acc1 * iv1);
        aggb[b + 128 + lane]  = bf16r(acc2 * iv2);
        aggb[b + 192 + lane]  = bf16r(acc3 * iv3);
    }
}

// ======================= layer 2 output transform (MFMA) + fused global-add-pool =======================
__global__ void k_out2(const unsigned short* __restrict__ aggb,
                       const unsigned short* __restrict__ W2bt,
                       const float* __restrict__ b2, const int* __restrict__ batch,
                       float* __restrict__ out, int N) {
    int w = threadIdx.x >> 6, lane = threadIdx.x & 63;
    int nodeBase = blockIdx.x * 64 + w * 16;
    int m = lane & 15;
    int quad = lane >> 4;
    const short* A = (const short*)aggb + (size_t)(nodeBase + m) * 256 + quad * 8;
    const short* B = (const short*)W2bt;

    f32x4 acc0 = {0.f, 0.f, 0.f, 0.f}, acc1 = {0.f, 0.f, 0.f, 0.f};
    f32x4 acc2 = {0.f, 0.f, 0.f, 0.f}, acc3 = {0.f, 0.f, 0.f, 0.f};
#pragma unroll
    for (int kk = 0; kk < 8; kk++) {
        short8 af = *(const short8*)(A + kk * 32);
        short8 b0 = *(const short8*)(B + (size_t)(0 * 16 + m) * 256 + kk * 32 + quad * 8);
        short8 b1v = *(const short8*)(B + (size_t)(1 * 16 + m) * 256 + kk * 32 + quad * 8);
        short8 b2v = *(const short8*)(B + (size_t)(2 * 16 + m) * 256 + kk * 32 + quad * 8);
        short8 b3v = *(const short8*)(B + (size_t)(3 * 16 + m) * 256 + kk * 32 + quad * 8);
        acc0 = __builtin_amdgcn_mfma_f32_16x16x32_bf16(af, b0, acc0, 0, 0, 0);
        acc1 = __builtin_amdgcn_mfma_f32_16x16x32_bf16(af, b1v, acc1, 0, 0, 0);
        acc2 = __builtin_amdgcn_mfma_f32_16x16x32_bf16(af, b2v, acc2, 0, 0, 0);
        acc3 = __builtin_amdgcn_mfma_f32_16x16x32_bf16(af, b3v, acc3, 0, 0, 0);
    }
    f32x4 accs[4] = {acc0, acc1, acc2, acc3};

    float vals[4][4];
#pragma unroll
    for (int cb = 0; cb < 4; cb++) {
        float bv = b2[cb * 16 + m];
#pragma unroll
        for (int r = 0; r < 4; r++)
            vals[cb][r] = fmaxf(0.25f * accs[cb][r] + bv, 0.f);
    }

    bool fast = (nodeBase + 15 < N);
    int g0 = 0;
    if (fast) {
        g0 = batch[nodeBase];
        int g1 = batch[nodeBase + 15];
        fast = (g0 == g1);
    }
    if (fast) {
#pragma unroll
        for (int cb = 0; cb < 4; cb++) {
            float s = vals[cb][0] + vals[cb][1] + vals[cb][2] + vals[cb][3];
            s += __shfl_xor(s, 16);
            s += __shfl_xor(s, 32);
            if (quad == 0) atomicAdd(&out[g0 * 64 + cb * 16 + m], s);
        }
    } else {
#pragma unroll
        for (int r = 0; r < 4; r++) {
            int node = nodeBase + quad * 4 + r;
            if (node < N) {
                int g = batch[node];
#pragma unroll
                for (int cb = 0; cb < 4; cb++)
                    atomicAdd(&out[g * 64 + cb * 16 + m], vals[cb][r]);
            }
        }
    }
}

__global__ void k_pzero(float* __restrict__ out, int total) {
    int i = blockIdx.x * blockDim.x + threadIdx.x;
    if (i < total) out[i] = 0.f;
}

extern "C" void kernel_launch(void* const* d_in, const int* in_sizes, int n_in,
                              void* d_out, int out_size, void* d_ws, size_t ws_size,
                              hipStream_t stream) {
    const float* x   = (const float*)d_in[0];
    const int*   ei  = (const int*)d_in[1];
    const int*   bat = (const int*)d_in[2];
    const float* W1  = (const float*)d_in[3];
    const float* as1 = (const float*)d_in[4];
    const float* ad1 = (const float*)d_in[5];
    const float* b1  = (const float*)d_in[6];
    const float* W2  = (const float*)d_in[7];
    const float* as2 = (const float*)d_in[8];
    const float* ad2 = (const float*)d_in[9];
    const float* b2  = (const float*)d_in[10];
    float* out = (float*)d_out;

    int N = in_sizes[0] / 3;
    int E = in_sizes[1] / 2;
    int G = out_size / 64;
    const int* srcI = ei;
    const int* dstI = ei + E;
    int NBUCK = (N + BWIDTH - 1) >> BSHIFT;

    // ---- workspace layout ----
    float* fw = (float*)d_ws;
    size_t fo = 0;
    unsigned short* aggb = (unsigned short*)fw; fo += (size_t)N * 128;   // N*256 bf16
    unsigned short* houtb = (unsigned short*)(fw + fo); fo += (size_t)N * 32;  // N*64 bf16
    float* esA   = fw + fo; fo += (size_t)N * 4;
    float* edA   = fw + fo; fo += (size_t)N * 4;
    float* esB   = fw + fo; fo += (size_t)N * 4;
    float* edB   = fw + fo; fo += (size_t)N * 4;
    float* p1s   = fw + fo; fo += 64;
    float* p1d   = fw + fo; fo += 64;
    float* qs    = fw + fo; fo += 256;
    float* qd    = fw + fo; fo += 256;
    unsigned short* W2bt = (unsigned short*)(fw + fo); fo += 64 * 256 / 2;
    int* iw = (int*)(fw + fo);
    size_t io = 0;
    unsigned* pairs = (unsigned*)iw; io += E;
    int* csr    = iw + io; io += E;
    int* off    = iw + io; io += N + 1;
    int* bbase  = iw + io; io += 1025;
    int* gcur   = iw + io; io += 1024;
    int* bcnt   = iw + io; io += 1024;

    int nThrBlk = (N + 255) / 256;
    int nGrpBlk = (N + 15) / 16;

    // ---- CSR build: two-level counting sort ----
    k_binit<<<1, 1024, 0, stream>>>(bcnt, NBUCK);
    k_bhist<<<256, 256, 0, stream>>>(dstI, bcnt, E, NBUCK);
    k_bscan<<<1, 1024, 0, stream>>>(bcnt, bbase, gcur, off, NBUCK, N, E);
    k_bdist<<<(E + DCHUNK - 1) / DCHUNK, 1024, 0, stream>>>(srcI, dstI, gcur, pairs, E, NBUCK);
    k_bcsr<<<NBUCK, 256, 0, stream>>>(pairs, bbase, off, csr, N);

    // ---- precompute attention projections + bf16 W2; zero out ----
    k_prep<<<(3 * 8 * 64 + 255) / 256, 256, 0, stream>>>(W1, as1, ad1, p1s, p1d, 3);
    k_prep<<<(64 * 8 * 64 + 255) / 256, 256, 0, stream>>>(W2, as2, ad2, qs, qd, 64);
    k_w2bt<<<64, 256, 0, stream>>>(W2, W2bt);
    k_pzero<<<(G * 64 + 255) / 256, 256, 0, stream>>>(out, G * 64);

    // ---- layer 1 (writes bf16 hout + layer-2 es/ed) ----
    k_esed1<<<nThrBlk, 256, 0, stream>>>(x, p1s, p1d, esA, edA, N);
    k_agg1<<<nGrpBlk, 256, 0, stream>>>(off, csr, esA, edA, x, W1, b1, qs, qd,
                                        houtb, esB, edB, N);

    // ---- layer 2 (aggregate -> bf16 agg -> MFMA transform + fused pool) ----
    k_agg2<<<nGrpBlk, 256, 0, stream>>>(off, csr, esB, edB, houtb, aggb, N);
    k_out2<<<(N + 63) / 64, 256, 0, stream>>>(aggb, W2bt, b2, bat, out, N);
}

// Round 12
// 254.156 us; speedup vs baseline: 9.1416x; 1.0014x over previous
//
#include <hip/hip_runtime.h>
#include <math.h>

#define HEADS 4
#define HID 64
#define BSHIFT 7          // 128 nodes per bucket
#define BWIDTH 128
#define CCAP 4096         // LDS csr-staging capacity (edges/bucket mean ~2047)
#define DCHUNK 8192       // edges per k_bdist block (8 per thread, 1024 threads)

typedef __attribute__((ext_vector_type(8))) short short8;
typedef __attribute__((ext_vector_type(4))) float f32x4;

__device__ __forceinline__ float lrelu(float x) { return x > 0.f ? x : 0.2f * x; }

__device__ __forceinline__ unsigned short bf16r(float f) {
    unsigned u = __float_as_uint(f);
    unsigned r = (u + 0x7FFFu + ((u >> 16) & 1u)) >> 16;
    return (unsigned short)r;
}
__device__ __forceinline__ float bf2f(unsigned short u) {
    return __uint_as_float(((unsigned)u) << 16);
}

__device__ __forceinline__ float wred_sum(float v) {
#pragma unroll
    for (int o = 32; o > 0; o >>= 1) v += __shfl_xor(v, o);
    return v;
}
__device__ __forceinline__ float red16_sum(float v) {
#pragma unroll
    for (int o = 8; o > 0; o >>= 1) v += __shfl_xor(v, o);
    return v;
}

// ======================= CSR build: two-level LDS counting sort =======================
__global__ void k_binit(int* __restrict__ bcnt, int NBUCK) {
    int i = threadIdx.x;
    if (i < NBUCK) bcnt[i] = 0;
}

__global__ void k_bhist(const int* __restrict__ dstI, int* __restrict__ bcnt,
                        int E, int NBUCK) {
    __shared__ int h[1024];
    for (int i = threadIdx.x; i < NBUCK; i += 256) h[i] = 0;
    __syncthreads();
    int stride = gridDim.x * 256;
    for (int e = blockIdx.x * 256 + threadIdx.x; e < E; e += stride)
        atomicAdd(&h[dstI[e] >> BSHIFT], 1);
    __syncthreads();
    for (int i = threadIdx.x; i < NBUCK; i += 256)
        if (h[i]) atomicAdd(&bcnt[i], h[i]);
}

__global__ void k_bscan(const int* __restrict__ bcnt, int* __restrict__ bbase,
                        int* __restrict__ gcur, int* __restrict__ off,
                        int NBUCK, int N, int E) {
    __shared__ int lds[1024];
    int t = threadIdx.x;
    int v = (t < NBUCK) ? bcnt[t] : 0;
    lds[t] = v;
    __syncthreads();
    for (int s = 1; s < 1024; s <<= 1) {
        int u = (t >= s) ? lds[t - s] : 0;
        __syncthreads();
        lds[t] += u;
        __syncthreads();
    }
    if (t < NBUCK) {
        int b = lds[t] - v;
        bbase[t] = b;
        gcur[t] = b;
    }
    if (t == 0) { bbase[NBUCK] = E; off[N] = E; }
}

__global__ void k_bdist(const int* __restrict__ srcI, const int* __restrict__ dstI,
                        int* __restrict__ gcur, unsigned* __restrict__ pairs,
                        int E, int NBUCK) {
    __shared__ int h[1024];
    __shared__ int cur[1024];
    for (int i = threadIdx.x; i < NBUCK; i += 1024) h[i] = 0;
    __syncthreads();
    int base = blockIdx.x * DCHUNK;
    int sr[8], dr[8];
#pragma unroll
    for (int k = 0; k < 8; k++) {
        int e = base + threadIdx.x + k * 1024;
        if (e < E) {
            sr[k] = srcI[e];
            dr[k] = dstI[e];
            atomicAdd(&h[dr[k] >> BSHIFT], 1);
        } else dr[k] = -1;
    }
    __syncthreads();
    for (int i = threadIdx.x; i < NBUCK; i += 1024)
        cur[i] = h[i] ? atomicAdd(&gcur[i], h[i]) : 0;
    __syncthreads();
#pragma unroll
    for (int k = 0; k < 8; k++) {
        if (dr[k] >= 0) {
            int b = dr[k] >> BSHIFT;
            int p = atomicAdd(&cur[b], 1);
            pairs[p] = ((unsigned)sr[k] << BSHIFT) | ((unsigned)dr[k] & (BWIDTH - 1));
        }
    }
}

__global__ void k_bcsr(const unsigned* __restrict__ pairs, const int* __restrict__ bbase,
                       int* __restrict__ off, int* __restrict__ csr, int N) {
    __shared__ int cnt[BWIDTH];
    __shared__ int scan[BWIDTH];
    __shared__ int cur[BWIDTH];
    __shared__ int stage[CCAP];
    int b = blockIdx.x;
    int nodeBase = b << BSHIFT;
    int nNodes = N - nodeBase;
    if (nNodes > BWIDTH) nNodes = BWIDTH;
    int e0 = bbase[b], e1 = bbase[b + 1];
    int ecnt = e1 - e0;
    if (threadIdx.x < BWIDTH) cnt[threadIdx.x] = 0;
    __syncthreads();
    for (int i = threadIdx.x; i < ecnt; i += 256)
        atomicAdd(&cnt[pairs[e0 + i] & (BWIDTH - 1)], 1);
    __syncthreads();
    if (threadIdx.x < BWIDTH)
        scan[threadIdx.x] = (threadIdx.x < nNodes) ? cnt[threadIdx.x] : 0;
    __syncthreads();
    for (int s = 1; s < BWIDTH; s <<= 1) {
        int u = 0;
        if (threadIdx.x < BWIDTH && threadIdx.x >= s) u = scan[threadIdx.x - s];
        __syncthreads();
        if (threadIdx.x < BWIDTH) scan[threadIdx.x] += u;
        __syncthreads();
    }
    if (threadIdx.x < nNodes) {
        int ex = scan[threadIdx.x] - cnt[threadIdx.x];
        off[nodeBase + threadIdx.x] = e0 + ex;
        cur[threadIdx.x] = ex;
    }
    __syncthreads();
    for (int i = threadIdx.x; i < ecnt; i += 256) {
        unsigned pr = pairs[e0 + i];
        int l = atomicAdd(&cur[pr & (BWIDTH - 1)], 1);
        int src = (int)(pr >> BSHIFT);
        if (l < CCAP) stage[l] = src;
        else csr[e0 + l] = src;
    }
    __syncthreads();
    int lim = ecnt < CCAP ? ecnt : CCAP;
    for (int i = threadIdx.x; i < lim; i += 256) csr[e0 + i] = stage[i];
}

// ======================= attention-coefficient precompute =======================
__global__ void k_prep(const float* __restrict__ W, const float* __restrict__ asrc,
                       const float* __restrict__ adst, float* __restrict__ p_src,
                       float* __restrict__ p_dst, int K) {
    int wid = (blockIdx.x * blockDim.x + threadIdx.x) >> 6;
    int lane = threadIdx.x & 63;
    int total = K * 4 * 2;
    if (wid >= total) return;
    int which = wid / (K * 4);
    int hk = wid % (K * 4);
    int h = hk / K, k = hk % K;
    const float* a = which ? adst : asrc;
    float v = W[(size_t)k * 256 + h * 64 + lane] * a[h * 64 + lane];
    v = wred_sum(v);
    if (lane == 0) (which ? p_dst : p_src)[h * K + k] = v;
}

// W2 -> bf16 transposed; also zeroes out[] (fused)
__global__ void k_w2bt(const float* __restrict__ W2, unsigned short* __restrict__ W2bt,
                       float* __restrict__ out, int outTotal) {
    int i = blockIdx.x * 256 + threadIdx.x;
    int c = i >> 8, kh = i & 255;
    int h = kh >> 6, kf = kh & 63;
    W2bt[i] = bf16r(W2[kf * 256 + h * 64 + c]);
    if (i < outTotal) out[i] = 0.f;
}

// es[n,h] = sum_k x[n,k] * ps[h*3+k]  (layer 1)
__global__ void k_esed1(const float* __restrict__ x, const float* __restrict__ ps,
                        const float* __restrict__ pd, float* __restrict__ es,
                        float* __restrict__ ed, int N) {
    int n = blockIdx.x * blockDim.x + threadIdx.x;
    if (n >= N) return;
    float x0 = x[n * 3], x1 = x[n * 3 + 1], x2 = x[n * 3 + 2];
    float4 s, d;
    s.x = x0 * ps[0] + x1 * ps[1] + x2 * ps[2];
    s.y = x0 * ps[3] + x1 * ps[4] + x2 * ps[5];
    s.z = x0 * ps[6] + x1 * ps[7] + x2 * ps[8];
    s.w = x0 * ps[9] + x1 * ps[10] + x2 * ps[11];
    d.x = x0 * pd[0] + x1 * pd[1] + x2 * pd[2];
    d.y = x0 * pd[3] + x1 * pd[4] + x2 * pd[5];
    d.z = x0 * pd[6] + x1 * pd[7] + x2 * pd[8];
    d.w = x0 * pd[9] + x1 * pd[10] + x2 * pd[11];
    ((float4*)es)[n] = s;
    ((float4*)ed)[n] = d;
}

// ======================= layer 1: 16-lane group per node, single pass =======================
__global__ void k_agg1(const int* __restrict__ off, const int* __restrict__ csr,
                       const float* __restrict__ es, const float* __restrict__ ed,
                       const float* __restrict__ x, const float* __restrict__ W1,
                       const float* __restrict__ b1, const float* __restrict__ qs,
                       const float* __restrict__ qd, unsigned short* __restrict__ houtb,
                       float* __restrict__ es2, float* __restrict__ ed2, int N) {
    int grp = (blockIdx.x * blockDim.x + threadIdx.x) >> 4;
    int l = threadIdx.x & 15;
    int wid = grp;
    bool active = wid < N;
    int o0 = 0, deg = 0;
    float4 edv = make_float4(0.f, 0.f, 0.f, 0.f);
    if (active) {
        o0 = off[wid];
        deg = off[wid + 1] - o0;
        edv = ((const float4*)ed)[wid];
    }

    float t0 = 0.f, t1 = 0.f, t2 = 0.f, t3 = 0.f;
    float a00 = 0, a01 = 0, a02 = 0, a10 = 0, a11 = 0, a12 = 0;
    float a20 = 0, a21 = 0, a22 = 0, a30 = 0, a31 = 0, a32 = 0;
    for (int j = l; j < deg; j += 16) {
        int s = csr[o0 + j];
        float4 ev = ((const float4*)es)[s];
        float e0 = __expf(lrelu(ev.x + edv.x));
        float e1 = __expf(lrelu(ev.y + edv.y));
        float e2 = __expf(lrelu(ev.z + edv.z));
        float e3 = __expf(lrelu(ev.w + edv.w));
        float xv0 = x[s * 3], xv1 = x[s * 3 + 1], xv2 = x[s * 3 + 2];
        t0 += e0; t1 += e1; t2 += e2; t3 += e3;
        a00 += e0 * xv0; a01 += e0 * xv1; a02 += e0 * xv2;
        a10 += e1 * xv0; a11 += e1 * xv1; a12 += e1 * xv2;
        a20 += e2 * xv0; a21 += e2 * xv1; a22 += e2 * xv2;
        a30 += e3 * xv0; a31 += e3 * xv1; a32 += e3 * xv2;
    }
    t0 = red16_sum(t0); t1 = red16_sum(t1); t2 = red16_sum(t2); t3 = red16_sum(t3);
    float i0 = t0 > 0.f ? 1.f / t0 : 0.f;
    float i1 = t1 > 0.f ? 1.f / t1 : 0.f;
    float i2 = t2 > 0.f ? 1.f / t2 : 0.f;
    float i3 = t3 > 0.f ? 1.f / t3 : 0.f;
    a00 = red16_sum(a00) * i0; a01 = red16_sum(a01) * i0; a02 = red16_sum(a02) * i0;
    a10 = red16_sum(a10) * i1; a11 = red16_sum(a11) * i1; a12 = red16_sum(a12) * i1;
    a20 = red16_sum(a20) * i2; a21 = red16_sum(a21) * i2; a22 = red16_sum(a22) * i2;
    a30 = red16_sum(a30) * i3; a31 = red16_sum(a31) * i3; a32 = red16_sum(a32) * i3;

    if (!active) return;

    const float4* W1f = (const float4*)W1;
    float4 r = make_float4(0.f, 0.f, 0.f, 0.f);
    float ah[4][3] = {{a00, a01, a02}, {a10, a11, a12}, {a20, a21, a22}, {a30, a31, a32}};
#pragma unroll
    for (int k = 0; k < 3; k++) {
#pragma unroll
        for (int h = 0; h < 4; h++) {
            float4 wv = W1f[k * 64 + h * 16 + l];
            float a = ah[h][k];
            r.x += a * wv.x; r.y += a * wv.y; r.z += a * wv.z; r.w += a * wv.w;
        }
    }
    float4 bv = ((const float4*)b1)[l];
    float4 hv;
    hv.x = fmaxf(0.25f * r.x + bv.x, 0.f);
    hv.y = fmaxf(0.25f * r.y + bv.y, 0.f);
    hv.z = fmaxf(0.25f * r.z + bv.z, 0.f);
    hv.w = fmaxf(0.25f * r.w + bv.w, 0.f);
    ((ushort4*)houtb)[(size_t)wid * 16 + l] =
        make_ushort4(bf16r(hv.x), bf16r(hv.y), bf16r(hv.z), bf16r(hv.w));

    const float4* qsf = (const float4*)qs;
    const float4* qdf = (const float4*)qd;
    float ps[4], pd[4];
#pragma unroll
    for (int h = 0; h < 4; h++) {
        float4 q = qsf[h * 16 + l];
        ps[h] = red16_sum(hv.x * q.x + hv.y * q.y + hv.z * q.z + hv.w * q.w);
        float4 p = qdf[h * 16 + l];
        pd[h] = red16_sum(hv.x * p.x + hv.y * p.y + hv.z * p.z + hv.w * p.w);
    }
    if (l == 0) {
        ((float4*)es2)[wid] = make_float4(ps[0], ps[1], ps[2], ps[3]);
        ((float4*)ed2)[wid] = make_float4(pd[0], pd[1], pd[2], pd[3]);
    }
}

// ======================= layer 2: softmax -> LDS; phase-B packed-dword gather =======================
// Phase B: lane = (half, channel-pair); each half-wave processes a different edge;
// one global_load_dword serves 2 bf16 channels. Cross-half shfl_xor(32) combine.
#define NS 16
__global__ void k_agg2(const int* __restrict__ off, const int* __restrict__ csr,
                       const float* __restrict__ es, const float* __restrict__ ed,
                       const unsigned short* __restrict__ houtb,
                       unsigned short* __restrict__ aggb, int N) {
    __shared__ float exl[NS * 64 * 4];
    __shared__ int   sl[NS * 64];
    __shared__ float minv[NS * 4];
    __shared__ int   meta[NS * 2];

    for (int i = threadIdx.x; i < NS * 64; i += 256) {
        ((float4*)exl)[i] = make_float4(0.f, 0.f, 0.f, 0.f);
        sl[i] = 0;
    }
    __syncthreads();

    int l = threadIdx.x & 15;
    int slot = threadIdx.x >> 4;
    int wid = blockIdx.x * NS + slot;
    bool active = wid < N;
    int o0 = 0, deg = 0;
    float4 edv = make_float4(0.f, 0.f, 0.f, 0.f);
    if (active) {
        o0 = off[wid];
        deg = off[wid + 1] - o0;
        edv = ((const float4*)ed)[wid];
    }

    // phase A: exp (no max) -> LDS (first 64 edges) + sum
    float t0 = 0.f, t1 = 0.f, t2 = 0.f, t3 = 0.f;
    for (int j = l; j < deg; j += 16) {
        int s = csr[o0 + j];
        float4 ev = ((const float4*)es)[s];
        float e0 = __expf(lrelu(ev.x + edv.x));
        float e1 = __expf(lrelu(ev.y + edv.y));
        float e2 = __expf(lrelu(ev.z + edv.z));
        float e3 = __expf(lrelu(ev.w + edv.w));
        if (j < 64) {
            ((float4*)exl)[slot * 64 + j] = make_float4(e0, e1, e2, e3);
            sl[slot * 64 + j] = s;
        }
        t0 += e0; t1 += e1; t2 += e2; t3 += e3;
    }
    t0 = red16_sum(t0); t1 = red16_sum(t1); t2 = red16_sum(t2); t3 = red16_sum(t3);
    if (l == 0) {
        minv[slot * 4 + 0] = t0 > 0.f ? 1.f / t0 : 0.f;
        minv[slot * 4 + 1] = t1 > 0.f ? 1.f / t1 : 0.f;
        minv[slot * 4 + 2] = t2 > 0.f ? 1.f / t2 : 0.f;
        minv[slot * 4 + 3] = t3 > 0.f ? 1.f / t3 : 0.f;
        meta[slot * 2 + 0] = o0;
        meta[slot * 2 + 1] = deg;
    }
    __syncthreads();

    int lane = threadIdx.x & 63;
    int w = threadIdx.x >> 6;
    int half = lane >> 5;       // which edge of the pair
    int c2 = lane & 31;         // channel pair: channels 2*c2, 2*c2+1
    for (int sidx = 0; sidx < 4; sidx++) {
        int slot2 = w * 4 + sidx;
        int nd = blockIdx.x * NS + slot2;
        if (nd >= N) continue;
        int o0b = meta[slot2 * 2 + 0], degb = meta[slot2 * 2 + 1];
        float iv0 = minv[slot2 * 4 + 0], iv1 = minv[slot2 * 4 + 1];
        float iv2 = minv[slot2 * 4 + 2], iv3 = minv[slot2 * 4 + 3];

        // acc[head][ch-pair-member]
        float p00 = 0.f, p01 = 0.f, p10 = 0.f, p11 = 0.f;
        float p20 = 0.f, p21 = 0.f, p30 = 0.f, p31 = 0.f;
        const float4* EX = ((const float4*)exl) + slot2 * 64;
        const int* S = sl + slot2 * 64;
        int dmain = degb < 64 ? degb : 64;
        int d8 = (dmain + 7) & ~7;   // pad entries: alpha=0, s=0 -> harmless
        for (int j = 0; j < d8; j += 8) {
            float4 a0 = EX[j + half];
            float4 a1 = EX[j + 2 + half];
            float4 a2 = EX[j + 4 + half];
            float4 a3 = EX[j + 6 + half];
            int s0 = S[j + half], s1 = S[j + 2 + half];
            int s2 = S[j + 4 + half], s3 = S[j + 6 + half];
            unsigned u0 = *(const unsigned*)(houtb + (size_t)s0 * 64 + 2 * c2);
            unsigned u1 = *(const unsigned*)(houtb + (size_t)s1 * 64 + 2 * c2);
            unsigned u2 = *(const unsigned*)(houtb + (size_t)s2 * 64 + 2 * c2);
            unsigned u3 = *(const unsigned*)(houtb + (size_t)s3 * 64 + 2 * c2);
            float v0l = __uint_as_float(u0 << 16), v0h = __uint_as_float(u0 & 0xffff0000u);
            float v1l = __uint_as_float(u1 << 16), v1h = __uint_as_float(u1 & 0xffff0000u);
            float v2l = __uint_as_float(u2 << 16), v2h = __uint_as_float(u2 & 0xffff0000u);
            float v3l = __uint_as_float(u3 << 16), v3h = __uint_as_float(u3 & 0xffff0000u);
            p00 += a0.x * v0l + a1.x * v1l + a2.x * v2l + a3.x * v3l;
            p01 += a0.x * v0h + a1.x * v1h + a2.x * v2h + a3.x * v3h;
            p10 += a0.y * v0l + a1.y * v1l + a2.y * v2l + a3.y * v3l;
            p11 += a0.y * v0h + a1.y * v1h + a2.y * v2h + a3.y * v3h;
            p20 += a0.z * v0l + a1.z * v1l + a2.z * v2l + a3.z * v3l;
            p21 += a0.z * v0h + a1.z * v1h + a2.z * v2h + a3.z * v3h;
            p30 += a0.w * v0l + a1.w * v1l + a2.w * v2l + a3.w * v3l;
            p31 += a0.w * v0h + a1.w * v1h + a2.w * v2h + a3.w * v3h;
        }
        if (degb > 64) {   // rare tail: halves split edges by parity
            float4 edv2 = ((const float4*)ed)[nd];
            for (int j = 64 + half; j < degb; j += 2) {
                int s = csr[o0b + j];
                float4 ev = ((const float4*)es)[s];
                float e0 = __expf(lrelu(ev.x + edv2.x));
                float e1 = __expf(lrelu(ev.y + edv2.y));
                float e2 = __expf(lrelu(ev.z + edv2.z));
                float e3 = __expf(lrelu(ev.w + edv2.w));
                unsigned u = *(const unsigned*)(houtb + (size_t)s * 64 + 2 * c2);
                float vl = __uint_as_float(u << 16), vh = __uint_as_float(u & 0xffff0000u);
                p00 += e0 * vl; p01 += e0 * vh;
                p10 += e1 * vl; p11 += e1 * vh;
                p20 += e2 * vl; p21 += e2 * vh;
                p30 += e3 * vl; p31 += e3 * vh;
            }
        }
        // combine halves
        p00 += __shfl_xor(p00, 32); p01 += __shfl_xor(p01, 32);
        p10 += __shfl_xor(p10, 32); p11 += __shfl_xor(p11, 32);
        p20 += __shfl_xor(p20, 32); p21 += __shfl_xor(p21, 32);
        p30 += __shfl_xor(p30, 32); p31 += __shfl_xor(p31, 32);

        if (half == 0) {
            size_t b = (size_t)nd * 256;
            unsigned w0 = (unsigned)bf16r(p00 * iv0) | ((unsigned)bf16r(p01 * iv0) << 16);
            unsigned w1 = (unsigned)bf16r(p10 * iv1) | ((unsigned)bf16r(p11 * iv1) << 16);
            unsigned w2 = (unsigned)bf16r(p20 * iv2) | ((unsigned)bf16r(p21 * iv2) << 16);
            unsigned w3 = (unsigned)bf16r(p30 * iv3) | ((unsigned)bf16r(p31 * iv3) << 16);
            *(unsigned*)(aggb + b + 2 * c2)        = w0;
            *(unsigned*)(aggb + b + 64 + 2 * c2)   = w1;
            *(unsigned*)(aggb + b + 128 + 2 * c2)  = w2;
            *(unsigned*)(aggb + b + 192 + 2 * c2)  = w3;
        }
    }
}

// ======================= layer 2 output transform (MFMA) + fused global-add-pool =======================
__global__ void k_out2(const unsigned short* __restrict__ aggb,
                       const unsigned short* __restrict__ W2bt,
                       const float* __restrict__ b2, const int* __restrict__ batch,
                       float* __restrict__ out, int N) {
    int w = threadIdx.x >> 6, lane = threadIdx.x & 63;
    int nodeBase = blockIdx.x * 64 + w * 16;
    int m = lane & 15;
    int quad = lane >> 4;
    const short* A = (const short*)aggb + (size_t)(nodeBase + m) * 256 + quad * 8;
    const short* B = (const short*)W2bt;

    f32x4 acc0 = {0.f, 0.f, 0.f, 0.f}, acc1 = {0.f, 0.f, 0.f, 0.f};
    f32x4 acc2 = {0.f, 0.f, 0.f, 0.f}, acc3 = {0.f, 0.f, 0.f, 0.f};
#pragma unroll
    for (int kk = 0; kk < 8; kk++) {
        short8 af = *(const short8*)(A + kk * 32);
        short8 b0 = *(const short8*)(B + (size_t)(0 * 16 + m) * 256 + kk * 32 + quad * 8);
        short8 b1v = *(const short8*)(B + (size_t)(1 * 16 + m) * 256 + kk * 32 + quad * 8);
        short8 b2v = *(const short8*)(B + (size_t)(2 * 16 + m) * 256 + kk * 32 + quad * 8);
        short8 b3v = *(const short8*)(B + (size_t)(3 * 16 + m) * 256 + kk * 32 + quad * 8);
        acc0 = __builtin_amdgcn_mfma_f32_16x16x32_bf16(af, b0, acc0, 0, 0, 0);
        acc1 = __builtin_amdgcn_mfma_f32_16x16x32_bf16(af, b1v, acc1, 0, 0, 0);
        acc2 = __builtin_amdgcn_mfma_f32_16x16x32_bf16(af, b2v, acc2, 0, 0, 0);
        acc3 = __builtin_amdgcn_mfma_f32_16x16x32_bf16(af, b3v, acc3, 0, 0, 0);
    }
    f32x4 accs[4] = {acc0, acc1, acc2, acc3};

    float vals[4][4];
#pragma unroll
    for (int cb = 0; cb < 4; cb++) {
        float bv = b2[cb * 16 + m];
#pragma unroll
        for (int r = 0; r < 4; r++)
            vals[cb][r] = fmaxf(0.25f * accs[cb][r] + bv, 0.f);
    }

    bool fast = (nodeBase + 15 < N);
    int g0 = 0;
    if (fast) {
        g0 = batch[nodeBase];
        int g1 = batch[nodeBase + 15];
        fast = (g0 == g1);
    }
    if (fast) {
#pragma unroll
        for (int cb = 0; cb < 4; cb++) {
            float s = vals[cb][0] + vals[cb][1] + vals[cb][2] + vals[cb][3];
            s += __shfl_xor(s, 16);
            s += __shfl_xor(s, 32);
            if (quad == 0) atomicAdd(&out[g0 * 64 + cb * 16 + m], s);
        }
    } else {
#pragma unroll
        for (int r = 0; r < 4; r++) {
            int node = nodeBase + quad * 4 + r;
            if (node < N) {
                int g = batch[node];
#pragma unroll
                for (int cb = 0; cb < 4; cb++)
                    atomicAdd(&out[g * 64 + cb * 16 + m], vals[cb][r]);
            }
        }
    }
}

extern "C" void kernel_launch(void* const* d_in, const int* in_sizes, int n_in,
                              void* d_out, int out_size, void* d_ws, size_t ws_size,
                              hipStream_t stream) {
    const float* x   = (const float*)d_in[0];
    const int*   ei  = (const int*)d_in[1];
    const int*   bat = (const int*)d_in[2];
    const float* W1  = (const float*)d_in[3];
    const float* as1 = (const float*)d_in[4];
    const float* ad1 = (const float*)d_in[5];
    const float* b1  = (const float*)d_in[6];
    const float* W2  = (const float*)d_in[7];
    const float* as2 = (const float*)d_in[8];
    const float* ad2 = (const float*)d_in[9];
    const float* b2  = (const float*)d_in[10];
    float* out = (float*)d_out;

    int N = in_sizes[0] / 3;
    int E = in_sizes[1] / 2;
    int G = out_size / 64;
    const int* srcI = ei;
    const int* dstI = ei + E;
    int NBUCK = (N + BWIDTH - 1) >> BSHIFT;

    // ---- workspace layout ----
    float* fw = (float*)d_ws;
    size_t fo = 0;
    unsigned short* aggb = (unsigned short*)fw; fo += (size_t)N * 128;
    unsigned short* houtb = (unsigned short*)(fw + fo); fo += (size_t)N * 32;
    float* esA   = fw + fo; fo += (size_t)N * 4;
    float* edA   = fw + fo; fo += (size_t)N * 4;
    float* esB   = fw + fo; fo += (size_t)N * 4;
    float* edB   = fw + fo; fo += (size_t)N * 4;
    float* p1s   = fw + fo; fo += 64;
    float* p1d   = fw + fo; fo += 64;
    float* qs    = fw + fo; fo += 256;
    float* qd    = fw + fo; fo += 256;
    unsigned short* W2bt = (unsigned short*)(fw + fo); fo += 64 * 256 / 2;
    int* iw = (int*)(fw + fo);
    size_t io = 0;
    unsigned* pairs = (unsigned*)iw; io += E;
    int* csr    = iw + io; io += E;
    int* off    = iw + io; io += N + 1;
    int* bbase  = iw + io; io += 1025;
    int* gcur   = iw + io; io += 1024;
    int* bcnt   = iw + io; io += 1024;

    int nThrBlk = (N + 255) / 256;
    int nGrpBlk = (N + 15) / 16;

    // ---- CSR build: two-level counting sort ----
    k_binit<<<1, 1024, 0, stream>>>(bcnt, NBUCK);
    k_bhist<<<256, 256, 0, stream>>>(dstI, bcnt, E, NBUCK);
    k_bscan<<<1, 1024, 0, stream>>>(bcnt, bbase, gcur, off, NBUCK, N, E);
    k_bdist<<<(E + DCHUNK - 1) / DCHUNK, 1024, 0, stream>>>(srcI, dstI, gcur, pairs, E, NBUCK);
    k_bcsr<<<NBUCK, 256, 0, stream>>>(pairs, bbase, off, csr, N);

    // ---- precompute attention projections + bf16 W2 (+ out zero) ----
    k_prep<<<(3 * 8 * 64 + 255) / 256, 256, 0, stream>>>(W1, as1, ad1, p1s, p1d, 3);
    k_prep<<<(64 * 8 * 64 + 255) / 256, 256, 0, stream>>>(W2, as2, ad2, qs, qd, 64);
    k_w2bt<<<64, 256, 0, stream>>>(W2, W2bt, out, G * 64);

    // ---- layer 1 ----
    k_esed1<<<nThrBlk, 256, 0, stream>>>(x, p1s, p1d, esA, edA, N);
    k_agg1<<<nGrpBlk, 256, 0, stream>>>(off, csr, esA, edA, x, W1, b1, qs, qd,
                                        houtb, esB, edB, N);

    // ---- layer 2 ----
    k_agg2<<<nGrpBlk, 256, 0, stream>>>(off, csr, esB, edB, houtb, aggb, N);
    k_out2<<<(N + 63) / 64, 256, 0, stream>>>(aggb, W2bt, b2, bat, out, N);
}

// Round 13
// 247.636 us; speedup vs baseline: 9.3823x; 1.0263x over previous
//
#include <hip/hip_runtime.h>
#include <math.h>

#define HEADS 4
#define HID 64
#define BSHIFT 7          // 128 nodes per bucket
#define BWIDTH 128
#define CCAP 4096         // LDS csr-staging capacity (edges/bucket mean ~2047)
#define DCHUNK 8192       // edges per k_bdist block (8 per thread, 1024 threads)

typedef __attribute__((ext_vector_type(8))) short short8;
typedef __attribute__((ext_vector_type(4))) float f32x4;
typedef __attribute__((ext_vector_type(2))) float f32x2;

__device__ __forceinline__ float lrelu(float x) { return x > 0.f ? x : 0.2f * x; }

__device__ __forceinline__ unsigned short bf16r(float f) {
    unsigned u = __float_as_uint(f);
    unsigned r = (u + 0x7FFFu + ((u >> 16) & 1u)) >> 16;
    return (unsigned short)r;
}
__device__ __forceinline__ f32x2 unpk(unsigned u) {
    f32x2 r;
    r.x = __uint_as_float(u << 16);
    r.y = __uint_as_float(u & 0xffff0000u);
    return r;
}

__device__ __forceinline__ float wred_sum(float v) {
#pragma unroll
    for (int o = 32; o > 0; o >>= 1) v += __shfl_xor(v, o);
    return v;
}
__device__ __forceinline__ float red16_sum(float v) {
#pragma unroll
    for (int o = 8; o > 0; o >>= 1) v += __shfl_xor(v, o);
    return v;
}

// ======================= CSR build: two-level LDS counting sort =======================
__global__ void k_binit(int* __restrict__ bcnt, int NBUCK) {
    int i = threadIdx.x;
    if (i < NBUCK) bcnt[i] = 0;
}

__global__ void k_bhist(const int* __restrict__ dstI, int* __restrict__ bcnt,
                        int E, int NBUCK) {
    __shared__ int h[1024];
    for (int i = threadIdx.x; i < NBUCK; i += 256) h[i] = 0;
    __syncthreads();
    int stride = gridDim.x * 256;
    for (int e = blockIdx.x * 256 + threadIdx.x; e < E; e += stride)
        atomicAdd(&h[dstI[e] >> BSHIFT], 1);
    __syncthreads();
    for (int i = threadIdx.x; i < NBUCK; i += 256)
        if (h[i]) atomicAdd(&bcnt[i], h[i]);
}

__global__ void k_bscan(const int* __restrict__ bcnt, int* __restrict__ bbase,
                        int* __restrict__ gcur, int* __restrict__ off,
                        int NBUCK, int N, int E) {
    __shared__ int lds[1024];
    int t = threadIdx.x;
    int v = (t < NBUCK) ? bcnt[t] : 0;
    lds[t] = v;
    __syncthreads();
    for (int s = 1; s < 1024; s <<= 1) {
        int u = (t >= s) ? lds[t - s] : 0;
        __syncthreads();
        lds[t] += u;
        __syncthreads();
    }
    if (t < NBUCK) {
        int b = lds[t] - v;
        bbase[t] = b;
        gcur[t] = b;
    }
    if (t == 0) { bbase[NBUCK] = E; off[N] = E; }
}

__global__ void k_bdist(const int* __restrict__ srcI, const int* __restrict__ dstI,
                        int* __restrict__ gcur, unsigned* __restrict__ pairs,
                        int E, int NBUCK) {
    __shared__ int h[1024];
    __shared__ int cur[1024];
    for (int i = threadIdx.x; i < NBUCK; i += 1024) h[i] = 0;
    __syncthreads();
    int base = blockIdx.x * DCHUNK;
    int sr[8], dr[8];
#pragma unroll
    for (int k = 0; k < 8; k++) {
        int e = base + threadIdx.x + k * 1024;
        if (e < E) {
            sr[k] = srcI[e];
            dr[k] = dstI[e];
            atomicAdd(&h[dr[k] >> BSHIFT], 1);
        } else dr[k] = -1;
    }
    __syncthreads();
    for (int i = threadIdx.x; i < NBUCK; i += 1024)
        cur[i] = h[i] ? atomicAdd(&gcur[i], h[i]) : 0;
    __syncthreads();
#pragma unroll
    for (int k = 0; k < 8; k++) {
        if (dr[k] >= 0) {
            int b = dr[k] >> BSHIFT;
            int p = atomicAdd(&cur[b], 1);
            pairs[p] = ((unsigned)sr[k] << BSHIFT) | ((unsigned)dr[k] & (BWIDTH - 1));
        }
    }
}

__global__ void k_bcsr(const unsigned* __restrict__ pairs, const int* __restrict__ bbase,
                       int* __restrict__ off, int* __restrict__ csr, int N) {
    __shared__ int cnt[BWIDTH];
    __shared__ int scan[BWIDTH];
    __shared__ int cur[BWIDTH];
    __shared__ int stage[CCAP];
    int b = blockIdx.x;
    int nodeBase = b << BSHIFT;
    int nNodes = N - nodeBase;
    if (nNodes > BWIDTH) nNodes = BWIDTH;
    int e0 = bbase[b], e1 = bbase[b + 1];
    int ecnt = e1 - e0;
    if (threadIdx.x < BWIDTH) cnt[threadIdx.x] = 0;
    __syncthreads();
    for (int i = threadIdx.x; i < ecnt; i += 256)
        atomicAdd(&cnt[pairs[e0 + i] & (BWIDTH - 1)], 1);
    __syncthreads();
    if (threadIdx.x < BWIDTH)
        scan[threadIdx.x] = (threadIdx.x < nNodes) ? cnt[threadIdx.x] : 0;
    __syncthreads();
    for (int s = 1; s < BWIDTH; s <<= 1) {
        int u = 0;
        if (threadIdx.x < BWIDTH && threadIdx.x >= s) u = scan[threadIdx.x - s];
        __syncthreads();
        if (threadIdx.x < BWIDTH) scan[threadIdx.x] += u;
        __syncthreads();
    }
    if (threadIdx.x < nNodes) {
        int ex = scan[threadIdx.x] - cnt[threadIdx.x];
        off[nodeBase + threadIdx.x] = e0 + ex;
        cur[threadIdx.x] = ex;
    }
    __syncthreads();
    for (int i = threadIdx.x; i < ecnt; i += 256) {
        unsigned pr = pairs[e0 + i];
        int l = atomicAdd(&cur[pr & (BWIDTH - 1)], 1);
        int src = (int)(pr >> BSHIFT);
        if (l < CCAP) stage[l] = src;
        else csr[e0 + l] = src;
    }
    __syncthreads();
    int lim = ecnt < CCAP ? ecnt : CCAP;
    for (int i = threadIdx.x; i < lim; i += 256) csr[e0 + i] = stage[i];
}

// ======================= fused prep: W1-proj, W2-proj, W2->bf16, out-zero =======================
__device__ __forceinline__ void prep_body(const float* __restrict__ W,
                                          const float* __restrict__ asrc,
                                          const float* __restrict__ adst,
                                          float* __restrict__ p_src,
                                          float* __restrict__ p_dst, int K, int blk) {
    int wid = blk * 4 + (threadIdx.x >> 6);
    int lane = threadIdx.x & 63;
    int total = K * 4 * 2;
    if (wid >= total) return;
    int which = wid / (K * 4);
    int hk = wid % (K * 4);
    int h = hk / K, k = hk % K;
    const float* a = which ? adst : asrc;
    float v = W[(size_t)k * 256 + h * 64 + lane] * a[h * 64 + lane];
    v = wred_sum(v);
    if (lane == 0) (which ? p_dst : p_src)[h * K + k] = v;
}

// blocks [0,6): W1 proj; [6,134): W2 proj; [134,198): W2->bf16 transpose + out zero
__global__ void k_prep_all(const float* __restrict__ W1, const float* __restrict__ as1,
                           const float* __restrict__ ad1, const float* __restrict__ W2,
                           const float* __restrict__ as2, const float* __restrict__ ad2,
                           float* __restrict__ p1s, float* __restrict__ p1d,
                           float* __restrict__ qs, float* __restrict__ qd,
                           unsigned short* __restrict__ W2bt, float* __restrict__ out,
                           int outTotal) {
    int b = blockIdx.x;
    if (b < 6) {
        prep_body(W1, as1, ad1, p1s, p1d, 3, b);
    } else if (b < 134) {
        prep_body(W2, as2, ad2, qs, qd, 64, b - 6);
    } else {
        int i = (b - 134) * 256 + threadIdx.x;
        int c = i >> 8, kh = i & 255;
        int h = kh >> 6, kf = kh & 63;
        W2bt[i] = bf16r(W2[kf * 256 + h * 64 + c]);
        if (i < outTotal) out[i] = 0.f;
    }
}

// es[n,h] = sum_k x[n,k] * ps[h*3+k]  (layer 1)
__global__ void k_esed1(const float* __restrict__ x, const float* __restrict__ ps,
                        const float* __restrict__ pd, float* __restrict__ es,
                        float* __restrict__ ed, int N) {
    int n = blockIdx.x * blockDim.x + threadIdx.x;
    if (n >= N) return;
    float x0 = x[n * 3], x1 = x[n * 3 + 1], x2 = x[n * 3 + 2];
    float4 s, d;
    s.x = x0 * ps[0] + x1 * ps[1] + x2 * ps[2];
    s.y = x0 * ps[3] + x1 * ps[4] + x2 * ps[5];
    s.z = x0 * ps[6] + x1 * ps[7] + x2 * ps[8];
    s.w = x0 * ps[9] + x1 * ps[10] + x2 * ps[11];
    d.x = x0 * pd[0] + x1 * pd[1] + x2 * pd[2];
    d.y = x0 * pd[3] + x1 * pd[4] + x2 * pd[5];
    d.z = x0 * pd[6] + x1 * pd[7] + x2 * pd[8];
    d.w = x0 * pd[9] + x1 * pd[10] + x2 * pd[11];
    ((float4*)es)[n] = s;
    ((float4*)ed)[n] = d;
}

// ======================= layer 1: 16-lane group per node, single pass =======================
__global__ void k_agg1(const int* __restrict__ off, const int* __restrict__ csr,
                       const float* __restrict__ es, const float* __restrict__ ed,
                       const float* __restrict__ x, const float* __restrict__ W1,
                       const float* __restrict__ b1, const float* __restrict__ qs,
                       const float* __restrict__ qd, unsigned short* __restrict__ houtb,
                       float* __restrict__ es2, float* __restrict__ ed2, int N) {
    int grp = (blockIdx.x * blockDim.x + threadIdx.x) >> 4;
    int l = threadIdx.x & 15;
    int wid = grp;
    bool active = wid < N;
    int o0 = 0, deg = 0;
    float4 edv = make_float4(0.f, 0.f, 0.f, 0.f);
    if (active) {
        o0 = off[wid];
        deg = off[wid + 1] - o0;
        edv = ((const float4*)ed)[wid];
    }

    float t0 = 0.f, t1 = 0.f, t2 = 0.f, t3 = 0.f;
    float a00 = 0, a01 = 0, a02 = 0, a10 = 0, a11 = 0, a12 = 0;
    float a20 = 0, a21 = 0, a22 = 0, a30 = 0, a31 = 0, a32 = 0;
    for (int j = l; j < deg; j += 16) {
        int s = csr[o0 + j];
        float4 ev = ((const float4*)es)[s];
        float e0 = __expf(lrelu(ev.x + edv.x));
        float e1 = __expf(lrelu(ev.y + edv.y));
        float e2 = __expf(lrelu(ev.z + edv.z));
        float e3 = __expf(lrelu(ev.w + edv.w));
        float xv0 = x[s * 3], xv1 = x[s * 3 + 1], xv2 = x[s * 3 + 2];
        t0 += e0; t1 += e1; t2 += e2; t3 += e3;
        a00 += e0 * xv0; a01 += e0 * xv1; a02 += e0 * xv2;
        a10 += e1 * xv0; a11 += e1 * xv1; a12 += e1 * xv2;
        a20 += e2 * xv0; a21 += e2 * xv1; a22 += e2 * xv2;
        a30 += e3 * xv0; a31 += e3 * xv1; a32 += e3 * xv2;
    }
    t0 = red16_sum(t0); t1 = red16_sum(t1); t2 = red16_sum(t2); t3 = red16_sum(t3);
    float i0 = t0 > 0.f ? 1.f / t0 : 0.f;
    float i1 = t1 > 0.f ? 1.f / t1 : 0.f;
    float i2 = t2 > 0.f ? 1.f / t2 : 0.f;
    float i3 = t3 > 0.f ? 1.f / t3 : 0.f;
    a00 = red16_sum(a00) * i0; a01 = red16_sum(a01) * i0; a02 = red16_sum(a02) * i0;
    a10 = red16_sum(a10) * i1; a11 = red16_sum(a11) * i1; a12 = red16_sum(a12) * i1;
    a20 = red16_sum(a20) * i2; a21 = red16_sum(a21) * i2; a22 = red16_sum(a22) * i2;
    a30 = red16_sum(a30) * i3; a31 = red16_sum(a31) * i3; a32 = red16_sum(a32) * i3;

    if (!active) return;

    const float4* W1f = (const float4*)W1;
    float4 r = make_float4(0.f, 0.f, 0.f, 0.f);
    float ah[4][3] = {{a00, a01, a02}, {a10, a11, a12}, {a20, a21, a22}, {a30, a31, a32}};
#pragma unroll
    for (int k = 0; k < 3; k++) {
#pragma unroll
        for (int h = 0; h < 4; h++) {
            float4 wv = W1f[k * 64 + h * 16 + l];
            float a = ah[h][k];
            r.x += a * wv.x; r.y += a * wv.y; r.z += a * wv.z; r.w += a * wv.w;
        }
    }
    float4 bv = ((const float4*)b1)[l];
    float4 hv;
    hv.x = fmaxf(0.25f * r.x + bv.x, 0.f);
    hv.y = fmaxf(0.25f * r.y + bv.y, 0.f);
    hv.z = fmaxf(0.25f * r.z + bv.z, 0.f);
    hv.w = fmaxf(0.25f * r.w + bv.w, 0.f);
    ((ushort4*)houtb)[(size_t)wid * 16 + l] =
        make_ushort4(bf16r(hv.x), bf16r(hv.y), bf16r(hv.z), bf16r(hv.w));

    const float4* qsf = (const float4*)qs;
    const float4* qdf = (const float4*)qd;
    float ps[4], pd[4];
#pragma unroll
    for (int h = 0; h < 4; h++) {
        float4 q = qsf[h * 16 + l];
        ps[h] = red16_sum(hv.x * q.x + hv.y * q.y + hv.z * q.z + hv.w * q.w);
        float4 p = qdf[h * 16 + l];
        pd[h] = red16_sum(hv.x * p.x + hv.y * p.y + hv.z * p.z + hv.w * p.w);
    }
    if (l == 0) {
        ((float4*)es2)[wid] = make_float4(ps[0], ps[1], ps[2], ps[3]);
        ((float4*)ed2)[wid] = make_float4(pd[0], pd[1], pd[2], pd[3]);
    }
}

// ======================= layer 2: softmax -> LDS; phase-B packed f32x2 gather =======================
// Phase A zeros only the pad region [deg, d8) (<=7 entries) instead of all 64 slots.
// Phase B: half-wave per edge, lane-pair per 2 channels, f32x2 accumulation (v_pk_fma_f32).
#define NS 16
__global__ void k_agg2(const int* __restrict__ off, const int* __restrict__ csr,
                       const float* __restrict__ es, const float* __restrict__ ed,
                       const unsigned short* __restrict__ houtb,
                       unsigned short* __restrict__ aggb, int N) {
    __shared__ float exl[NS * 64 * 4];
    __shared__ int   sl[NS * 64];
    __shared__ float minv[NS * 4];
    __shared__ int   meta[NS * 2];

    int l = threadIdx.x & 15;
    int slot = threadIdx.x >> 4;
    int wid = blockIdx.x * NS + slot;
    bool active = wid < N;
    int o0 = 0, deg = 0;
    float4 edv = make_float4(0.f, 0.f, 0.f, 0.f);
    if (active) {
        o0 = off[wid];
        deg = off[wid + 1] - o0;
        edv = ((const float4*)ed)[wid];
    }

    // phase A: exp (no max) -> LDS (first 64 edges) + sum
    float t0 = 0.f, t1 = 0.f, t2 = 0.f, t3 = 0.f;
    for (int j = l; j < deg; j += 16) {
        int s = csr[o0 + j];
        float4 ev = ((const float4*)es)[s];
        float e0 = __expf(lrelu(ev.x + edv.x));
        float e1 = __expf(lrelu(ev.y + edv.y));
        float e2 = __expf(lrelu(ev.z + edv.z));
        float e3 = __expf(lrelu(ev.w + edv.w));
        if (j < 64) {
            ((float4*)exl)[slot * 64 + j] = make_float4(e0, e1, e2, e3);
            sl[slot * 64 + j] = s;
        }
        t0 += e0; t1 += e1; t2 += e2; t3 += e3;
    }
    // zero only the pad region [dmain, d8)
    {
        int dmain = deg < 64 ? deg : 64;
        int d8 = (dmain + 7) & ~7;
        if (dmain + l < d8) {
            ((float4*)exl)[slot * 64 + dmain + l] = make_float4(0.f, 0.f, 0.f, 0.f);
            sl[slot * 64 + dmain + l] = 0;
        }
    }
    t0 = red16_sum(t0); t1 = red16_sum(t1); t2 = red16_sum(t2); t3 = red16_sum(t3);
    if (l == 0) {
        minv[slot * 4 + 0] = t0 > 0.f ? 1.f / t0 : 0.f;
        minv[slot * 4 + 1] = t1 > 0.f ? 1.f / t1 : 0.f;
        minv[slot * 4 + 2] = t2 > 0.f ? 1.f / t2 : 0.f;
        minv[slot * 4 + 3] = t3 > 0.f ? 1.f / t3 : 0.f;
        meta[slot * 2 + 0] = o0;
        meta[slot * 2 + 1] = deg;
    }
    __syncthreads();

    int lane = threadIdx.x & 63;
    int w = threadIdx.x >> 6;
    int half = lane >> 5;       // which edge of the pair
    int c2 = lane & 31;         // channel pair: channels 2*c2, 2*c2+1
    for (int sidx = 0; sidx < 4; sidx++) {
        int slot2 = w * 4 + sidx;
        int nd = blockIdx.x * NS + slot2;
        if (nd >= N) continue;
        int o0b = meta[slot2 * 2 + 0], degb = meta[slot2 * 2 + 1];
        float iv0 = minv[slot2 * 4 + 0], iv1 = minv[slot2 * 4 + 1];
        float iv2 = minv[slot2 * 4 + 2], iv3 = minv[slot2 * 4 + 3];

        f32x2 q0 = {0.f, 0.f}, q1 = {0.f, 0.f}, q2 = {0.f, 0.f}, q3 = {0.f, 0.f};
        const float4* EX = ((const float4*)exl) + slot2 * 64;
        const int* S = sl + slot2 * 64;
        int dmain = degb < 64 ? degb : 64;
        int d8 = (dmain + 7) & ~7;
        for (int j = 0; j < d8; j += 8) {
            float4 a0 = EX[j + half];
            float4 a1 = EX[j + 2 + half];
            float4 a2 = EX[j + 4 + half];
            float4 a3 = EX[j + 6 + half];
            int s0 = S[j + half], s1 = S[j + 2 + half];
            int s2 = S[j + 4 + half], s3 = S[j + 6 + half];
            unsigned u0 = *(const unsigned*)(houtb + (size_t)s0 * 64 + 2 * c2);
            unsigned u1 = *(const unsigned*)(houtb + (size_t)s1 * 64 + 2 * c2);
            unsigned u2 = *(const unsigned*)(houtb + (size_t)s2 * 64 + 2 * c2);
            unsigned u3 = *(const unsigned*)(houtb + (size_t)s3 * 64 + 2 * c2);
            f32x2 v0 = unpk(u0), v1 = unpk(u1), v2 = unpk(u2), v3 = unpk(u3);
            q0 += a0.x * v0; q0 += a1.x * v1; q0 += a2.x * v2; q0 += a3.x * v3;
            q1 += a0.y * v0; q1 += a1.y * v1; q1 += a2.y * v2; q1 += a3.y * v3;
            q2 += a0.z * v0; q2 += a1.z * v1; q2 += a2.z * v2; q2 += a3.z * v3;
            q3 += a0.w * v0; q3 += a1.w * v1; q3 += a2.w * v2; q3 += a3.w * v3;
        }
        if (degb > 64) {   // rare tail: halves split edges by parity
            float4 edv2 = ((const float4*)ed)[nd];
            for (int j = 64 + half; j < degb; j += 2) {
                int s = csr[o0b + j];
                float4 ev = ((const float4*)es)[s];
                float e0 = __expf(lrelu(ev.x + edv2.x));
                float e1 = __expf(lrelu(ev.y + edv2.y));
                float e2 = __expf(lrelu(ev.z + edv2.z));
                float e3 = __expf(lrelu(ev.w + edv2.w));
                unsigned u = *(const unsigned*)(houtb + (size_t)s * 64 + 2 * c2);
                f32x2 v = unpk(u);
                q0 += e0 * v; q1 += e1 * v; q2 += e2 * v; q3 += e3 * v;
            }
        }
        // combine halves
        q0.x += __shfl_xor(q0.x, 32); q0.y += __shfl_xor(q0.y, 32);
        q1.x += __shfl_xor(q1.x, 32); q1.y += __shfl_xor(q1.y, 32);
        q2.x += __shfl_xor(q2.x, 32); q2.y += __shfl_xor(q2.y, 32);
        q3.x += __shfl_xor(q3.x, 32); q3.y += __shfl_xor(q3.y, 32);

        if (half == 0) {
            size_t b = (size_t)nd * 256;
            unsigned w0 = (unsigned)bf16r(q0.x * iv0) | ((unsigned)bf16r(q0.y * iv0) << 16);
            unsigned w1 = (unsigned)bf16r(q1.x * iv1) | ((unsigned)bf16r(q1.y * iv1) << 16);
            unsigned w2 = (unsigned)bf16r(q2.x * iv2) | ((unsigned)bf16r(q2.y * iv2) << 16);
            unsigned w3 = (unsigned)bf16r(q3.x * iv3) | ((unsigned)bf16r(q3.y * iv3) << 16);
            *(unsigned*)(aggb + b + 2 * c2)        = w0;
            *(unsigned*)(aggb + b + 64 + 2 * c2)   = w1;
            *(unsigned*)(aggb + b + 128 + 2 * c2)  = w2;
            *(unsigned*)(aggb + b + 192 + 2 * c2)  = w3;
        }
    }
}

// ======================= layer 2 output transform (MFMA) + fused global-add-pool =======================
__global__ void k_out2(const unsigned short* __restrict__ aggb,
                       const unsigned short* __restrict__ W2bt,
                       const float* __restrict__ b2, const int* __restrict__ batch,
                       float* __restrict__ out, int N) {
    int w = threadIdx.x >> 6, lane = threadIdx.x & 63;
    int nodeBase = blockIdx.x * 64 + w * 16;
    int m = lane & 15;
    int quad = lane >> 4;
    const short* A = (const short*)aggb + (size_t)(nodeBase + m) * 256 + quad * 8;
    const short* B = (const short*)W2bt;

    f32x4 acc0 = {0.f, 0.f, 0.f, 0.f}, acc1 = {0.f, 0.f, 0.f, 0.f};
    f32x4 acc2 = {0.f, 0.f, 0.f, 0.f}, acc3 = {0.f, 0.f, 0.f, 0.f};
#pragma unroll
    for (int kk = 0; kk < 8; kk++) {
        short8 af = *(const short8*)(A + kk * 32);
        short8 b0 = *(const short8*)(B + (size_t)(0 * 16 + m) * 256 + kk * 32 + quad * 8);
        short8 b1v = *(const short8*)(B + (size_t)(1 * 16 + m) * 256 + kk * 32 + quad * 8);
        short8 b2v = *(const short8*)(B + (size_t)(2 * 16 + m) * 256 + kk * 32 + quad * 8);
        short8 b3v = *(const short8*)(B + (size_t)(3 * 16 + m) * 256 + kk * 32 + quad * 8);
        acc0 = __builtin_amdgcn_mfma_f32_16x16x32_bf16(af, b0, acc0, 0, 0, 0);
        acc1 = __builtin_amdgcn_mfma_f32_16x16x32_bf16(af, b1v, acc1, 0, 0, 0);
        acc2 = __builtin_amdgcn_mfma_f32_16x16x32_bf16(af, b2v, acc2, 0, 0, 0);
        acc3 = __builtin_amdgcn_mfma_f32_16x16x32_bf16(af, b3v, acc3, 0, 0, 0);
    }
    f32x4 accs[4] = {acc0, acc1, acc2, acc3};

    float vals[4][4];
#pragma unroll
    for (int cb = 0; cb < 4; cb++) {
        float bv = b2[cb * 16 + m];
#pragma unroll
        for (int r = 0; r < 4; r++)
            vals[cb][r] = fmaxf(0.25f * accs[cb][r] + bv, 0.f);
    }

    bool fast = (nodeBase + 15 < N);
    int g0 = 0;
    if (fast) {
        g0 = batch[nodeBase];
        int g1 = batch[nodeBase + 15];
        fast = (g0 == g1);
    }
    if (fast) {
#pragma unroll
        for (int cb = 0; cb < 4; cb++) {
            float s = vals[cb][0] + vals[cb][1] + vals[cb][2] + vals[cb][3];
            s += __shfl_xor(s, 16);
            s += __shfl_xor(s, 32);
            if (quad == 0) atomicAdd(&out[g0 * 64 + cb * 16 + m], s);
        }
    } else {
#pragma unroll
        for (int r = 0; r < 4; r++) {
            int node = nodeBase + quad * 4 + r;
            if (node < N) {
                int g = batch[node];
#pragma unroll
                for (int cb = 0; cb < 4; cb++)
                    atomicAdd(&out[g * 64 + cb * 16 + m], vals[cb][r]);
            }
        }
    }
}

extern "C" void kernel_launch(void* const* d_in, const int* in_sizes, int n_in,
                              void* d_out, int out_size, void* d_ws, size_t ws_size,
                              hipStream_t stream) {
    const float* x   = (const float*)d_in[0];
    const int*   ei  = (const int*)d_in[1];
    const int*   bat = (const int*)d_in[2];
    const float* W1  = (const float*)d_in[3];
    const float* as1 = (const float*)d_in[4];
    const float* ad1 = (const float*)d_in[5];
    const float* b1  = (const float*)d_in[6];
    const float* W2  = (const float*)d_in[7];
    const float* as2 = (const float*)d_in[8];
    const float* ad2 = (const float*)d_in[9];
    const float* b2  = (const float*)d_in[10];
    float* out = (float*)d_out;

    int N = in_sizes[0] / 3;
    int E = in_sizes[1] / 2;
    int G = out_size / 64;
    const int* srcI = ei;
    const int* dstI = ei + E;
    int NBUCK = (N + BWIDTH - 1) >> BSHIFT;

    // ---- workspace layout ----
    float* fw = (float*)d_ws;
    size_t fo = 0;
    unsigned short* aggb = (unsigned short*)fw; fo += (size_t)N * 128;
    unsigned short* houtb = (unsigned short*)(fw + fo); fo += (size_t)N * 32;
    float* esA   = fw + fo; fo += (size_t)N * 4;
    float* edA   = fw + fo; fo += (size_t)N * 4;
    float* esB   = fw + fo; fo += (size_t)N * 4;
    float* edB   = fw + fo; fo += (size_t)N * 4;
    float* p1s   = fw + fo; fo += 64;
    float* p1d   = fw + fo; fo += 64;
    float* qs    = fw + fo; fo += 256;
    float* qd    = fw + fo; fo += 256;
    unsigned short* W2bt = (unsigned short*)(fw + fo); fo += 64 * 256 / 2;
    int* iw = (int*)(fw + fo);
    size_t io = 0;
    unsigned* pairs = (unsigned*)iw; io += E;
    int* csr    = iw + io; io += E;
    int* off    = iw + io; io += N + 1;
    int* bbase  = iw + io; io += 1025;
    int* gcur   = iw + io; io += 1024;
    int* bcnt   = iw + io; io += 1024;

    int nThrBlk = (N + 255) / 256;
    int nGrpBlk = (N + 15) / 16;

    // ---- CSR build: two-level counting sort ----
    k_binit<<<1, 1024, 0, stream>>>(bcnt, NBUCK);
    k_bhist<<<256, 256, 0, stream>>>(dstI, bcnt, E, NBUCK);
    k_bscan<<<1, 1024, 0, stream>>>(bcnt, bbase, gcur, off, NBUCK, N, E);
    k_bdist<<<(E + DCHUNK - 1) / DCHUNK, 1024, 0, stream>>>(srcI, dstI, gcur, pairs, E, NBUCK);
    k_bcsr<<<NBUCK, 256, 0, stream>>>(pairs, bbase, off, csr, N);

    // ---- fused prep (W1/W2 projections, W2 bf16 transpose, out zero) ----
    k_prep_all<<<198, 256, 0, stream>>>(W1, as1, ad1, W2, as2, ad2,
                                        p1s, p1d, qs, qd, W2bt, out, G * 64);

    // ---- layer 1 ----
    k_esed1<<<nThrBlk, 256, 0, stream>>>(x, p1s, p1d, esA, edA, N);
    k_agg1<<<nGrpBlk, 256, 0, stream>>>(off, csr, esA, edA, x, W1, b1, qs, qd,
                                        houtb, esB, edB, N);

    // ---- layer 2 ----
    k_agg2<<<nGrpBlk, 256, 0, stream>>>(off, csr, esB, edB, houtb, aggb, N);
    k_out2<<<(N + 63) / 64, 256, 0, stream>>>(aggb, W2bt, b2, bat, out, N);
}